// Round 3
// baseline (25810.516 us; speedup 1.0000x reference)
//
#include <hip/hip_runtime.h>
#include <hip/hip_bf16.h>

typedef __hip_bfloat16 bf16;

#define NEDGE 229376
#define NTOT  8192
#define BNCONST 0.9999950000374997f   /* 1/sqrt(1+1e-5) */
#define ISQ96   0.10206207261596575f  /* 1/sqrt(96) */

__constant__ int c_NT[5]     = {2048,2048,2048,1024,1024};
__constant__ int c_OFFS[5]   = {0,2048,4096,6144,7168};
__constant__ int c_ESRC[8]   = {0,1,1,2,0,3,1,4};
__constant__ int c_EDST[8]   = {1,0,2,2,3,1,4,2};
__constant__ int c_EOFF[9]   = {0,32768,65536,98304,131072,147456,180224,196608,229376};
__constant__ int c_RELROW[8] = {0,2048,4096,6144,8192,10240,11264,13312};

static const int h_NT[5]   = {2048,2048,2048,1024,1024};
static const int h_OFFS[5] = {0,2048,4096,6144,7168};

__device__ inline float bf2f(bf16 v){ return __bfloat162float(v); }
__device__ inline float gelu_f(float x){ return 0.5f*x*(1.0f+erff(x*0.70710678118654752f)); }
__device__ inline float sigm(float x){ return 1.0f/(1.0f+expf(-x)); }
__device__ inline float wsum64(float v){
  #pragma unroll
  for (int s=32;s>0;s>>=1) v += __shfl_xor(v, s, 64);
  return v;
}
__device__ inline float wmax64(float v){
  #pragma unroll
  for (int s=32;s>0;s>>=1) v = fmaxf(v, __shfl_xor(v, s, 64));
  return v;
}
__device__ inline unsigned encf(float f){
  unsigned b = __float_as_uint(f);
  return (b & 0x80000000u) ? ~b : (b | 0x80000000u);
}
__device__ inline float decf(unsigned u){
  unsigned b = (u & 0x80000000u) ? (u & 0x7FFFFFFFu) : ~u;
  return __uint_as_float(b);
}
__device__ inline int row_type(int row){
  return (row<2048)?0:((row<4096)?1:((row<6144)?2:((row<7168)?3:4)));
}

/* dual-dtype load: f=1 -> f32, f=0 -> bf16. Explicit branch so the compiler
   cannot speculate the wide load (bf16 buffers are half the f32 footprint). */
__device__ inline float LD(const void* p, size_t i, int f){
  if (f) return ((const float*)p)[i];
  return __bfloat162float(((const bf16*)p)[i]);
}
__device__ inline void STO(void* o, size_t i, float v, int f){
  if (f) ((float*)o)[i] = v;
  else   ((bf16*)o)[i] = __float2bfloat16(v);
}

/* ---------------- dtype detector (one input per launch) ---------------- */
__global__ void k_detect_one(const void* p, int n, int* flag){
  __shared__ int s_f32, s_bf16;
  if (threadIdx.x==0){ s_f32=0; s_bf16=0; }
  __syncthreads();
  int limit = (n >= 8) ? (n >> 1) : n;   // f32 probe stays inside bf16 footprint
  int samples = min(limit, 2048);
  int cf=0, cb=0;
  for (int k = threadIdx.x; k < samples; k += 256){
    float vf = ((const float*)p)[k];
    float a1 = fabsf(vf);
    if (isfinite(vf) && a1 >= 1e-6f && a1 <= 1e4f) cf++;
    float vb = __bfloat162float(((const bf16*)p)[k]);
    float a2 = fabsf(vb);
    if (isfinite(vb) && a2 >= 1e-6f && a2 <= 1e4f) cb++;
  }
  atomicAdd(&s_f32, cf); atomicAdd(&s_bf16, cb);
  __syncthreads();
  if (threadIdx.x==0) *flag = (s_f32 > s_bf16) ? 1 : 0;  // ties -> bf16 (safe for all-zero arrays)
}

/* ---------------- simple utility kernels ---------------- */

__global__ void k_cvt(const void* __restrict__ src, float* __restrict__ dst, int n,
                      const int* __restrict__ FL, int fi){
  int i = blockIdx.x*256 + threadIdx.x;
  int f = FL[fi];
  if (i < n) dst[i] = LD(src, i, f);
}

__global__ void k_gelu(float* __restrict__ x, int n){
  int i = blockIdx.x*256 + threadIdx.x;
  if (i < n) x[i] = gelu_f(x[i]);
}

__global__ void k_mix(const float* __restrict__ a, const float* __restrict__ b,
                      float* __restrict__ c, int n, float fa, float fb){
  int i = blockIdx.x*256 + threadIdx.x;
  if (i < n) c[i] = fa*a[i] + fb*b[i];
}

__global__ void k_comb(const float* __restrict__ ai, const float* __restrict__ user,
                       float* __restrict__ cb){
  int i = blockIdx.x*256 + threadIdx.x;
  if (i >= 2048*768) return;
  int n = i / 768, c = i - n*768;
  cb[i] = (c < 384) ? ai[n*384 + c] : user[n*384 + (c-384)];
}

/* ---------------- edge preprocessing (CSR by destination) ---------------- */

__global__ void k_edge_pre(const int* __restrict__ esrc, const int* __restrict__ edst,
                           int* edg, int* esr, int* erl, int* cnt){
  int e = blockIdx.x*256 + threadIdx.x;
  if (e >= NEDGE) return;
  int r = 0;
  #pragma unroll
  for (int q=1;q<8;q++) if (e >= c_EOFF[q]) r = q;
  int dg = c_OFFS[c_EDST[r]] + edst[e];
  edg[e] = dg;
  esr[e] = c_RELROW[r] + esrc[e];
  erl[e] = r;
  atomicAdd(&cnt[dg], 1);
}

__global__ __launch_bounds__(1024) void k_scan(const int* __restrict__ cnt, int* __restrict__ off){
  __shared__ int sh[1024];
  int tid = threadIdx.x;
  int base = tid*8;
  int loc[8]; int run = 0;
  #pragma unroll
  for (int i=0;i<8;i++){ loc[i] = run; run += cnt[base+i]; }
  sh[tid] = run;
  __syncthreads();
  for (int d=1; d<1024; d<<=1){
    int v = (tid >= d) ? sh[tid-d] : 0;
    __syncthreads();
    sh[tid] += v;
    __syncthreads();
  }
  int pre = (tid==0) ? 0 : sh[tid-1];
  #pragma unroll
  for (int i=0;i<8;i++) off[base+i] = pre + loc[i];
  if (tid==1023) off[8192] = sh[1023];
}

__global__ void k_scatter(const int* __restrict__ edg, const int* __restrict__ off,
                          int* cnt2, int* csr){
  int e = blockIdx.x*256 + threadIdx.x;
  if (e >= NEDGE) return;
  int dg = edg[e];
  int pos = off[dg] + atomicAdd(&cnt2[dg], 1);
  csr[pos] = e;
}

/* ---------------- boring GEMM kernels (thread per output) ---------------- */
// C = act( (A@B + bias) * kmul * cs[col] + csh[col] )
__global__ __launch_bounds__(256) void bg_nn_bf(
    const float* __restrict__ A, int lda,
    const void* __restrict__ B, size_t offB, int ldb,
    const void* __restrict__ bias, size_t offBias,
    const void* __restrict__ cs, size_t offCs,
    const void* __restrict__ csh, size_t offCsh,
    float kmul, float* __restrict__ C, int ldc, int M, int N, int K, int act,
    const int* __restrict__ FL, int iB, int iBias, int iCs, int iCsh)
{
  int n = blockIdx.x*64 + threadIdx.x;
  int m = blockIdx.y*4 + threadIdx.y;
  if (n >= N || m >= M) return;
  int fB = FL[iB];
  const float* a = A + (size_t)m*lda;
  float acc = 0.f;
  for (int k = 0; k < K; k++) acc += a[k] * LD(B, offB + (size_t)k*ldb + n, fB);
  if (bias) acc += LD(bias, offBias + n, FL[iBias]);
  float s = kmul;
  if (cs) s *= LD(cs, offCs + n, FL[iCs]);
  acc *= s;
  if (csh) acc += LD(csh, offCsh + n, FL[iCsh]);
  if (act == 1) acc = fmaxf(acc, 0.f);
  C[(size_t)m*ldc + n] = acc;
}

// C = (A@B)*scale, both f32
__global__ __launch_bounds__(256) void bg_nn_ff(
    const float* __restrict__ A, int lda, const float* __restrict__ B, int ldb,
    float* __restrict__ C, int ldc, int M, int N, int K, float scale)
{
  int n = blockIdx.x*64 + threadIdx.x;
  int m = blockIdx.y*4 + threadIdx.y;
  if (n >= N || m >= M) return;
  const float* a = A + (size_t)m*lda;
  const float* b = B + n;
  float acc = 0.f;
  for (int k = 0; k < K; k++) acc += a[k] * b[(size_t)k*ldb];
  C[(size_t)m*ldc + n] = acc*scale;
}

// C[m,n] = sum_l A[l,m]*B[l,n]
__global__ __launch_bounds__(256) void bg_tn_ff(
    const float* __restrict__ A, int lda, const float* __restrict__ B, int ldb,
    float* __restrict__ C, int ldc, int M, int N, int L)
{
  int n = blockIdx.x*64 + threadIdx.x;
  int m = blockIdx.y*4 + threadIdx.y;
  if (n >= N || m >= M) return;
  float acc = 0.f;
  for (int l = 0; l < L; l++) acc += A[(size_t)l*lda + m] * B[(size_t)l*ldb + n];
  C[(size_t)m*ldc + n] = acc;
}

// KT[c*nkv + n] = MQKV[n*1152 + 384 + c]
__global__ void k_kt(const float* __restrict__ MQ, float* __restrict__ KT, int nkv){
  int idx = blockIdx.x*256 + threadIdx.x;
  if (idx >= 384*nkv) return;
  int c = idx / nkv, n = idx - c*nkv;
  KT[idx] = MQ[(size_t)n*1152 + 384 + c];
}

/* ---------------- HGT relation projection ---------------- */
__global__ void k_relproj_b(const float* __restrict__ KQV_, const void* __restrict__ rel,
                            size_t offR, float* __restrict__ OUT, int which,
                            const int* __restrict__ FL, int iR)
{
  int idx = blockIdx.x*256 + threadIdx.x;
  if (idx >= 14336*384) return;
  int fR = FL[iR];
  int row = idx / 384, c = idx - row*384;
  int h = c / 96, f = c - h*96;
  int r = 0;
  #pragma unroll
  for (int q=1;q<8;q++) if (row >= c_RELROW[q]) r = q;
  int s = c_ESRC[r];
  int nr = row - c_RELROW[r];
  const float* a = KQV_ + (size_t)(c_OFFS[s] + nr)*1152 + (which ? 768 : 0) + h*96;
  size_t wb = offR + (size_t)(r*4 + h)*9216 + f;
  float acc = 0.f;
  #pragma unroll 4
  for (int d = 0; d < 96; d++) acc += a[d] * LD(rel, wb + (size_t)d*96, fR);
  OUT[idx] = acc;
}

/* ---------------- edge attention ---------------- */

__global__ __launch_bounds__(256) void k_escore(
    const float* __restrict__ KQV_, const float* __restrict__ KE_,
    const int* __restrict__ edg, const int* __restrict__ esr, const int* __restrict__ erl,
    const void* __restrict__ prel, size_t offP, float* __restrict__ EA,
    const int* __restrict__ FL, int iP)
{
  int e = blockIdx.x*4 + (threadIdx.x>>6);
  if (e >= NEDGE) return;
  int lane = threadIdx.x & 63;
  int h = lane >> 4, j = lane & 15;
  int dg = edg[e], sr = esr[e], r = erl[e];
  const float* q  = KQV_ + (size_t)dg*1152 + 384 + h*96;
  const float* ke = KE_  + (size_t)sr*384 + h*96;
  float p = 0.f;
  #pragma unroll
  for (int t=0;t<6;t++){ int d = j + t*16; p += q[d]*ke[d]; }
  p += __shfl_xor(p, 1, 64);
  p += __shfl_xor(p, 2, 64);
  p += __shfl_xor(p, 4, 64);
  p += __shfl_xor(p, 8, 64);
  if (j == 0) EA[(size_t)e*4 + h] = p * LD(prel, offP + r*4 + h, FL[iP]) * ISQ96;
}

__global__ void k_segmax(const float* __restrict__ EA, const int* __restrict__ edg,
                         unsigned* __restrict__ EMX){
  int i = blockIdx.x*256 + threadIdx.x;
  if (i >= NEDGE*4) return;
  int e = i >> 2, h = i & 3;
  atomicMax(&EMX[edg[e]*4 + h], encf(EA[i]));
}

__global__ void k_expsum(float* __restrict__ EA, const int* __restrict__ edg,
                         const unsigned* __restrict__ EMX, float* __restrict__ EDEN){
  int i = blockIdx.x*256 + threadIdx.x;
  if (i >= NEDGE*4) return;
  int e = i >> 2, h = i & 3;
  int dg = edg[e];
  float m = decf(EMX[dg*4 + h]);
  float ex = expf(EA[i] - m);
  EA[i] = ex;
  atomicAdd(&EDEN[dg*4 + h], ex);
}

__global__ __launch_bounds__(128) void k_agg(
    const float* __restrict__ EA, const float* __restrict__ VE_,
    const float* __restrict__ EDEN, const int* __restrict__ csr,
    const int* __restrict__ off, const int* __restrict__ esr, float* __restrict__ AGG)
{
  int node = blockIdx.x, tid = threadIdx.x;
  int b = off[node], e1 = off[node+1];
  int d0 = tid, d1 = tid+128, d2 = tid+256;
  int h0 = d0/96, h1 = d1/96, h2 = d2/96;
  float a0=0.f, a1=0.f, a2=0.f;
  if (e1 > b){
    float i0 = 1.0f/EDEN[node*4+h0];
    float i1 = 1.0f/EDEN[node*4+h1];
    float i2 = 1.0f/EDEN[node*4+h2];
    for (int p=b; p<e1; p++){
      int e = csr[p];
      const float* ve = VE_ + (size_t)esr[e]*384;
      const float* ea = EA + (size_t)e*4;
      a0 += ea[h0]*i0*ve[d0];
      a1 += ea[h1]*i1*ve[d1];
      a2 += ea[h2]*i2*ve[d2];
    }
  }
  AGG[(size_t)node*384 + d0] = a0;
  AGG[(size_t)node*384 + d1] = a1;
  AGG[(size_t)node*384 + d2] = a2;
}

/* ---------------- row-wise norm kernels ---------------- */

__global__ __launch_bounds__(128) void k_gateln(
    const float* __restrict__ O, float* __restrict__ X,
    const void* __restrict__ skp, size_t offS,
    const void* __restrict__ lng, const void* __restrict__ lnb,
    const int* __restrict__ FL, int iS, int iG, int iB)
{
  __shared__ float red[2];
  int row = blockIdx.x, tid = threadIdx.x;
  int t = row_type(row);
  float gt = sigm(LD(skp, offS + t, FL[iS]));
  const float* o = O + (size_t)row*384;
  float* x = X + (size_t)row*384;
  float v0 = gelu_f(gt*o[tid]     + (1.f-gt)*x[tid]);
  float v1 = gelu_f(gt*o[tid+128] + (1.f-gt)*x[tid+128]);
  float v2 = gelu_f(gt*o[tid+256] + (1.f-gt)*x[tid+256]);
  int lane = tid & 63, wid = tid >> 6;
  float s = wsum64(v0+v1+v2);
  if (lane==0) red[wid] = s;
  __syncthreads();
  float mean = (red[0]+red[1]) * (1.0f/384.0f);
  __syncthreads();
  float d0=v0-mean, d1=v1-mean, d2=v2-mean;
  float q = wsum64(d0*d0+d1*d1+d2*d2);
  if (lane==0) red[wid] = q;
  __syncthreads();
  float var = (red[0]+red[1]) * (1.0f/384.0f);
  float rs = 1.0f/sqrtf(var + 1e-5f);
  int fG = FL[iG], fB = FL[iB];
  size_t gb = (size_t)t*384;
  x[tid]     = d0*rs*LD(lng, gb+tid,     fG) + LD(lnb, gb+tid,     fB);
  x[tid+128] = d1*rs*LD(lng, gb+tid+128, fG) + LD(lnb, gb+tid+128, fB);
  x[tid+256] = d2*rs*LD(lng, gb+tid+256, fG) + LD(lnb, gb+tid+256, fB);
}

__global__ __launch_bounds__(128) void k_lnrow(
    const float* __restrict__ X, float* __restrict__ Y,
    const void* __restrict__ g, const void* __restrict__ b, int act,
    const int* __restrict__ FL, int iG, int iB)
{
  __shared__ float red[2];
  int row = blockIdx.x, tid = threadIdx.x;
  const float* x = X + (size_t)row*384;
  float* y = Y + (size_t)row*384;
  float v0 = x[tid], v1 = x[tid+128], v2 = x[tid+256];
  int lane = tid & 63, wid = tid >> 6;
  float s = wsum64(v0+v1+v2);
  if (lane==0) red[wid] = s;
  __syncthreads();
  float mean = (red[0]+red[1]) * (1.0f/384.0f);
  __syncthreads();
  float d0=v0-mean, d1=v1-mean, d2=v2-mean;
  float q = wsum64(d0*d0+d1*d1+d2*d2);
  if (lane==0) red[wid] = q;
  __syncthreads();
  float var = (red[0]+red[1]) * (1.0f/384.0f);
  float rs = 1.0f/sqrtf(var + 1e-5f);
  int fG = FL[iG], fB = FL[iB];
  float u0 = d0*rs*LD(g, tid,     fG) + LD(b, tid,     fB);
  float u1 = d1*rs*LD(g, tid+128, fG) + LD(b, tid+128, fB);
  float u2 = d2*rs*LD(g, tid+256, fG) + LD(b, tid+256, fB);
  if (act==1){ u0=fmaxf(u0,0.f); u1=fmaxf(u1,0.f); u2=fmaxf(u2,0.f); }
  else       { u0=gelu_f(u0); u1=gelu_f(u1); u2=gelu_f(u2); }
  y[tid] = u0; y[tid+128] = u1; y[tid+256] = u2;
}

/* ---------------- softmax / reductions / misc ---------------- */

__global__ __launch_bounds__(256) void k_softmax(float* __restrict__ S, int L){
  __shared__ float red[4];
  int row = blockIdx.x, tid = threadIdx.x;
  float* p = S + (size_t)row*L;
  float m = -3.0e38f;
  for (int c=tid;c<L;c+=256) m = fmaxf(m, p[c]);
  m = wmax64(m);
  int lane = tid & 63, wid = tid >> 6;
  if (lane==0) red[wid] = m;
  __syncthreads();
  m = fmaxf(fmaxf(red[0],red[1]), fmaxf(red[2],red[3]));
  __syncthreads();
  float s = 0.f;
  for (int c=tid;c<L;c+=256){ float e = expf(p[c]-m); p[c]=e; s += e; }
  s = wsum64(s);
  if (lane==0) red[wid] = s;
  __syncthreads();
  float inv = 1.0f/(red[0]+red[1]+red[2]+red[3]);
  for (int c=tid;c<L;c+=256) p[c] *= inv;
}

__global__ __launch_bounds__(256) void k_sumsq(const float* __restrict__ x, int n, float* out){
  __shared__ float red[4];
  float s = 0.f;
  for (int i = blockIdx.x*256 + threadIdx.x; i < n; i += gridDim.x*256){ float v=x[i]; s += v*v; }
  s = wsum64(s);
  int lane = threadIdx.x & 63, wid = threadIdx.x >> 6;
  if (lane==0) red[wid] = s;
  __syncthreads();
  if (threadIdx.x==0) atomicAdd(out, red[0]+red[1]+red[2]+red[3]);
}

__global__ void k_colsum(const float* __restrict__ A, int R, int C, float scale,
                         float* __restrict__ out){
  int col = blockIdx.x*256 + threadIdx.x;
  if (col >= C) return;
  int nchunk = gridDim.y;
  int chunk = (R + nchunk - 1)/nchunk;
  int r0 = blockIdx.y*chunk, r1 = min(R, r0+chunk);
  float s = 0.f;
  for (int r=r0; r<r1; r++) s += A[(size_t)r*C + col];
  atomicAdd(&out[col], s*scale);
}

__global__ __launch_bounds__(256) void k_dnm(const float* __restrict__ QB,
    const float* __restrict__ KSUM, const float* __restrict__ sqsk, float* __restrict__ DNM){
  int wv = blockIdx.x*4 + (threadIdx.x>>6);
  int n = wv >> 2, h = wv & 3;
  int lane = threadIdx.x & 63;
  const float* q = QB + (size_t)n*1536 + h*384;
  const float* ks = KSUM + h*384;
  float p = 0.f;
  #pragma unroll
  for (int d=lane; d<384; d+=64) p += q[d]*ks[d];
  p = wsum64(p);
  if (lane==0) DNM[n*4+h] = p * (1.0f/sqrtf(sqsk[0]*sqsk[1])) + 2048.0f;
}

__global__ void k_zcomb(const float* __restrict__ ZN, const float* __restrict__ VB_,
                        const float* __restrict__ DNM_, const float* __restrict__ sqsk,
                        float* __restrict__ XG_,
                        const void* __restrict__ bng, const void* __restrict__ bnb, size_t offBN,
                        const int* __restrict__ FL, int iG, int iB){
  int i = blockIdx.x*256 + threadIdx.x;
  if (i >= 2048*384) return;
  int n = i / 384, c = i - n*384;
  float inv_s = 1.0f/sqrtf(sqsk[0]*sqsk[1]);
  float zm = 0.f;
  #pragma unroll
  for (int h=0;h<4;h++){
    float num = ZN[(size_t)n*1536 + h*384 + c]*inv_s + 2048.0f*VB_[(size_t)n*1536 + h*384 + c];
    zm += num / DNM_[n*4+h];
  }
  zm *= 0.25f;
  float y = 0.5f*zm + 0.5f*XG_[i];
  y = y * (LD(bng, offBN + c, FL[iG]) * BNCONST) + LD(bnb, offBN + c, FL[iB]);
  XG_[i] = fmaxf(y, 0.f);
}

/* ---------------- conv1d (kernel 3, pad 1) ---------------- */
__global__ __launch_bounds__(256) void k_conv3(
    const float* __restrict__ in, const void* __restrict__ W, const void* __restrict__ bias,
    float* __restrict__ out, int IC, int OC,
    const int* __restrict__ FL, int iW, int iB)
{
  __shared__ float xs[34][384];
  int tid = threadIdx.x;
  int p0 = blockIdx.x*32, oc0 = blockIdx.y*64;
  for (int idx = tid; idx < 34*IC; idx += 256){
    int rr = idx / IC, c = idx - rr*IC;
    int gp = p0 - 1 + rr;
    xs[rr][c] = (gp >= 0 && gp < 2048) ? in[(size_t)gp*IC + c] : 0.f;
  }
  __syncthreads();
  int fW = FL[iW];
  int oc = oc0 + (tid & 63);
  int py = tid >> 6;
  float acc[8] = {0,0,0,0,0,0,0,0};
  size_t wb = (size_t)oc*IC*3;
  for (int c=0;c<IC;c++){
    float w0 = LD(W, wb + c*3+0, fW);
    float w1 = LD(W, wb + c*3+1, fW);
    float w2 = LD(W, wb + c*3+2, fW);
    #pragma unroll
    for (int u=0;u<8;u++){
      int pl = py + u*4;
      acc[u] += w0*xs[pl][c] + w1*xs[pl+1][c] + w2*xs[pl+2][c];
    }
  }
  float b = LD(bias, oc, FL[iB]);
  #pragma unroll
  for (int u=0;u<8;u++){
    int pl = py + u*4;
    out[(size_t)(p0+pl)*OC + oc] = gelu_f(acc[u] + b);
  }
}

/* ---------------- small dense kernels ---------------- */

__global__ __launch_bounds__(256) void k_gemv1(const float* __restrict__ in, int K,
    const void* __restrict__ W, int ldw, const void* __restrict__ b,
    float* __restrict__ out, int N, int act,
    const int* __restrict__ FL, int iW, int iB){
  __shared__ float x[1344];
  int tid = threadIdx.x;
  for (int i = tid; i < K; i += 256) x[i] = in[i];
  __syncthreads();
  int fW = FL[iW], fB = FL[iB];
  for (int c = tid; c < N; c += 256){
    float acc = 0.f;
    for (int k = 0; k < K; k++) acc += x[k]*LD(W, (size_t)k*ldw + c, fW);
    acc += LD(b, c, fB);
    if (act==1) acc = fmaxf(acc, 0.f);
    out[c] = acc;
  }
}

// out[offO + r] = sigmoid(A[r,:K] . w + b)
__global__ __launch_bounds__(256) void k_rowdot(const float* __restrict__ A, int lda, int K,
    const void* __restrict__ w, const void* __restrict__ b, void* __restrict__ out,
    size_t offO, int M, const int* __restrict__ FL, int iW, int iB, int iOut){
  int r = blockIdx.x*4 + (threadIdx.x>>6);
  if (r >= M) return;
  int lane = threadIdx.x & 63;
  int fW = FL[iW];
  const float* a = A + (size_t)r*lda;
  float p = 0.f;
  for (int k = lane; k < K; k += 64) p += a[k]*LD(w, k, fW);
  p = wsum64(p);
  if (lane==0) STO(out, offO + r, sigm(p + LD(b, 0, FL[iB])), FL[iOut]);
}

__global__ __launch_bounds__(64) void k_final(const float* __restrict__ z2,
    const void* __restrict__ w, const void* __restrict__ b, void* __restrict__ out,
    const int* __restrict__ FL, int iW, int iB, int iOut){
  int lane = threadIdx.x;
  float p = 0.f;
  int fW = FL[iW];
  for (int k = lane; k < 192; k += 64) p += z2[k]*LD(w, k, fW);
  p = wsum64(p);
  if (lane==0){
    float l = p + LD(b, 0, FL[iB]);
    int fo = FL[iOut];
    STO(out, 0, l, fo);
    STO(out, 1, sigm(l), fo);
  }
}

/* ================================================================ */

extern "C" void kernel_launch(void* const* d_in, const int* in_sizes, int n_in,
                              void* d_out, int out_size, void* d_ws, size_t ws_size,
                              hipStream_t stream)
{
  const void* xin[5] = {d_in[0], d_in[1], d_in[2], d_in[3], d_in[4]};
  const void* Wkqv=d_in[5];  const void* bkqv=d_in[6];
  const void* Wout=d_in[7];  const void* bout=d_in[8];
  const void* krel=d_in[9];  const void* vrel=d_in[10];
  const void* prel=d_in[11]; const void* skp =d_in[12];
  const void* lng =d_in[13]; const void* lnb =d_in[14];
  const void* sp_W=d_in[15]; const void* sp_b=d_in[16];
  const void* sp_lng=d_in[17]; const void* sp_lnb=d_in[18];
  const void* fc0_W=d_in[19]; const void* fc0_b=d_in[20];
  const void* bn_g=d_in[21]; const void* bn_b=d_in[22];
  const void* tq_W=d_in[23]; const void* tq_b=d_in[24];
  const void* tk_W=d_in[25]; const void* tk_b=d_in[26];
  const void* tv_W=d_in[27]; const void* tv_b=d_in[28];
  const void* mWqkv=d_in[29]; const void* mbqkv=d_in[30];
  const void* mWo=d_in[31];  const void* mbo=d_in[32];
  const void* c1W=d_in[33];  const void* c1b=d_in[34];
  const void* c2W=d_in[35];  const void* c2b=d_in[36];
  const void* opW=d_in[37];  const void* opb=d_in[38];
  const void* as1W=d_in[39]; const void* as1b=d_in[40];
  const void* as2W=d_in[41]; const void* as2b=d_in[42];
  const void* sc1W=d_in[43]; const void* sc1b=d_in[44];
  const void* sc2W=d_in[45]; const void* sc2b=d_in[46];
  const void* cl1W=d_in[47]; const void* cl1b=d_in[48];
  const void* cllng=d_in[49]; const void* cllnb=d_in[50];
  const void* cl2W=d_in[51]; const void* cl2b=d_in[52];
  const void* cl3W=d_in[53]; const void* cl3b=d_in[54];
  const void* tpW=d_in[55];  const void* tpb=d_in[56];
  const int* e_src=(const int*)d_in[57];  const int* e_dst=(const int*)d_in[58];

  /* workspace arena */
  char* ws = (char*)d_ws;
  size_t off_b = 0;
  auto alloc = [&](size_t bytes)->char*{
    char* r = ws + off_b;
    off_b = (off_b + bytes + 255) & ~(size_t)255;
    return r;
  };
  float* X    = (float*)alloc((size_t)8192*384*4);
  float* KQV  = (float*)alloc((size_t)8192*1152*4);
  float* KE   = (float*)alloc((size_t)14336*384*4);
  float* VE   = (float*)alloc((size_t)14336*384*4);
  float* AGG  = (float*)alloc((size_t)8192*384*4);
  float* EA   = (float*)alloc((size_t)NEDGE*4*4);
  int* edg    = (int*)alloc((size_t)NEDGE*4);
  int* esr    = (int*)alloc((size_t)NEDGE*4);
  int* erl    = (int*)alloc((size_t)NEDGE*4);
  int* csr    = (int*)alloc((size_t)NEDGE*4);
  int* cnt    = (int*)alloc(8192*4);
  int* cnt2   = (int*)alloc(8192*4);
  int* coff   = (int*)alloc(8193*4);
  unsigned* EMX = (unsigned*)alloc(8192*4*4);
  float* EDEN = (float*)alloc(8192*4*4);
  float* SM   = (float*)alloc(65536);
  int* FLG    = (int*)alloc(64*4);
  if (off_b > ws_size) return;

  float* SQSK = SM;
  float* TRAJSUM = SM + 8;
  float* DECAYSUM = SM + 392;
  float* TEMB = SM + 600;
  float* AIPOOL = SM + 984;
  float* BCTXV = SM + 1368;
  float* SDELT = SM + 1752;
  float* SDIN = SM + 2048;
  float* T1   = SM + 2816;
  float* Z1   = SM + 3200;
  float* Zb   = SM + 3584;
  float* Z2   = SM + 3968;
  float* KSUM = SM + 4224;
  float* DNM  = SM + 6144;

  float* QB = KQV;
  float* KB = KQV + (size_t)2048*1536;
  float* VB = KQV + (size_t)2*2048*1536;
  float* MQKV = KQV;
  float* AO = KQV + (size_t)2*2048*1536;
  float* SSC = KE;
  float* KT  = KE + (size_t)2048*2048;
  float* ZNUM = KE;
  float* OWT = KE;
  float* HS = VE;
  float* XG = VE + (size_t)2048*384;
  float* HM = VE + (size_t)2*2048*384;
  float* C1O = VE + (size_t)3*2048*384;
  float* TRAJ = VE + (size_t)4*2048*384;
  float* AICTX = VE + (size_t)5*2048*384;
  float* C2O = VE + (size_t)6*2048*384;
  float* TMPA = AGG;
  float* CB = AGG;
  float* PT = AGG + (size_t)2048*768;
  float* KVS = AGG + (size_t)2048*1152;

  dim3 B256(256);
  dim3 BG(64,4);

  /* ---- dtype detection for all 57 float inputs ---- */
  for (int i = 0; i < 57; i++)
    k_detect_one<<<dim3(1), B256, 0, stream>>>(d_in[i], in_sizes[i], FLG + i);

  auto bgemm = [&](const float* A, int lda, const void* Bw, size_t offB, int ldb, int iB,
                   const void* bias, size_t offBias, int iBias,
                   const void* cs, size_t offCs, int iCs,
                   const void* csh, size_t offCsh, int iCsh, float kmul,
                   float* C, int ldc, int M, int N, int K, int act){
    dim3 g((N+63)/64, (M+3)/4);
    bg_nn_bf<<<g, BG, 0, stream>>>(A, lda, Bw, offB, ldb, bias, offBias, cs, offCs,
                                   csh, offCsh, kmul, C, ldc, M, N, K, act,
                                   FLG, iB, iBias, iCs, iCsh);
  };
  auto bgemm_ff = [&](const float* A, int lda, const float* B, int ldb, float* C, int ldc,
                      int M, int N, int K, float scale){
    dim3 g((N+63)/64, (M+3)/4);
    bg_nn_ff<<<g, BG, 0, stream>>>(A, lda, B, ldb, C, ldc, M, N, K, scale);
  };
  auto bgemm_tn = [&](const float* A, int lda, const float* B, int ldb, float* C, int ldc,
                      int M, int N, int L){
    dim3 g((N+63)/64, (M+3)/4);
    bg_tn_ff<<<g, BG, 0, stream>>>(A, lda, B, ldb, C, ldc, M, N, L);
  };

  /* ---- edge CSR ---- */
  hipMemsetAsync(cnt, 0, 8192*4, stream);
  hipMemsetAsync(cnt2, 0, 8192*4, stream);
  k_edge_pre<<<dim3(NEDGE/256), B256, 0, stream>>>(e_src, e_dst, edg, esr, erl, cnt);
  k_scan<<<dim3(1), dim3(1024), 0, stream>>>(cnt, coff);
  k_scatter<<<dim3(NEDGE/256), B256, 0, stream>>>(edg, coff, cnt2, csr);

  /* ---- inputs -> X ---- */
  for (int t=0;t<5;t++)
    k_cvt<<<dim3((h_NT[t]*384+255)/256), B256, 0, stream>>>(xin[t], X + (size_t)h_OFFS[t]*384,
                                                            h_NT[t]*384, FLG, t);

  /* ---- HGT layers ---- */
  for (int l=0;l<2;l++){
    for (int t=0;t<5;t++)
      bgemm(X + (size_t)h_OFFS[t]*384, 384,
            Wkqv, (size_t)(l*5+t)*442368, 1152, 5,
            bkqv, (size_t)(l*5+t)*1152, 6,
            nullptr,0,6, nullptr,0,6, 1.f,
            KQV + (size_t)h_OFFS[t]*1152, 1152, h_NT[t], 1152, 384, 0);
    k_relproj_b<<<dim3(21504), B256, 0, stream>>>(KQV, krel, (size_t)l*294912, KE, 0, FLG, 9);
    k_relproj_b<<<dim3(21504), B256, 0, stream>>>(KQV, vrel, (size_t)l*294912, VE, 1, FLG, 10);
    k_escore<<<dim3(NEDGE/4), B256, 0, stream>>>(KQV, KE, edg, esr, erl, prel, (size_t)l*32, EA, FLG, 11);
    hipMemsetAsync(EMX, 0, 8192*4*4, stream);
    hipMemsetAsync(EDEN, 0, 8192*4*4, stream);
    k_segmax<<<dim3(NEDGE*4/256), B256, 0, stream>>>(EA, edg, EMX);
    k_expsum<<<dim3(NEDGE*4/256), B256, 0, stream>>>(EA, edg, EMX, EDEN);
    k_agg<<<dim3(NTOT), dim3(128), 0, stream>>>(EA, VE, EDEN, csr, coff, esr, AGG);
    k_gelu<<<dim3(12288), B256, 0, stream>>>(AGG, 8192*384);
    for (int t=0;t<5;t++)
      bgemm(AGG + (size_t)h_OFFS[t]*384, 384,
            Wout, (size_t)(l*5+t)*147456, 384, 7,
            bout, (size_t)(l*5+t)*384, 8,
            nullptr,0,8, nullptr,0,8, 1.f,
            OWT + (size_t)h_OFFS[t]*384, 384, h_NT[t], 384, 384, 0);
    k_gateln<<<dim3(NTOT), dim3(128), 0, stream>>>(OWT, X, skp, (size_t)l*5, lng, lnb, FLG, 12, 13, 14);
  }

  const float* user_h   = X;
  const float* ai_h     = X + (size_t)2048*384;
  const float* stance_h = X + (size_t)4096*384;
  const float* belief_h = X + (size_t)7168*384;

  /* ---- hs, xg ---- */
  bgemm(stance_h, 384, sp_W, 0, 384, 15, sp_b, 0, 16, nullptr,0,16, nullptr,0,16, 1.f,
        TMPA, 384, 2048, 384, 384, 0);
  k_lnrow<<<dim3(2048), dim3(128), 0, stream>>>(TMPA, HS, sp_lng, sp_lnb, 0, FLG, 17, 18);
  bgemm(HS, 384, fc0_W, 0, 384, 19, fc0_b, 0, 20, bn_g, 0, 21, bn_b, 0, 22, BNCONST,
        XG, 384, 2048, 384, 384, 1);

  /* ---- linear-attention blocks ---- */
  for (int i=0;i<2;i++){
    bgemm(XG, 384, tq_W, (size_t)i*589824, 1536, 23, tq_b, (size_t)i*1536, 24,
          nullptr,0,24, nullptr,0,24, 1.f, QB, 1536, 2048, 1536, 384, 0);
    bgemm(XG, 384, tk_W, (size_t)i*589824, 1536, 25, tk_b, (size_t)i*1536, 26,
          nullptr,0,26, nullptr,0,26, 1.f, KB, 1536, 2048, 1536, 384, 0);
    bgemm(XG, 384, tv_W, (size_t)i*589824, 1536, 27, tv_b, (size_t)i*1536, 28,
          nullptr,0,28, nullptr,0,28, 1.f, VB, 1536, 2048, 1536, 384, 0);
    hipMemsetAsync(SQSK, 0, 8, stream);
    k_sumsq<<<dim3(512), B256, 0, stream>>>(QB, 2048*1536, SQSK);
    k_sumsq<<<dim3(512), B256, 0, stream>>>(KB, 2048*1536, SQSK+1);
    hipMemsetAsync(KSUM, 0, 1536*4, stream);
    k_colsum<<<dim3(6,8), B256, 0, stream>>>(KB, 2048, 1536, 1.0f, KSUM);
    k_dnm<<<dim3(2048), B256, 0, stream>>>(QB, KSUM, SQSK, DNM);
    for (int h=0;h<4;h++)
      bgemm_tn(KB + h*384, 1536, VB + h*384, 1536, KVS + (size_t)h*147456, 384, 384, 384, 2048);
    for (int h=0;h<4;h++)
      bgemm_ff(QB + h*384, 1536, KVS + (size_t)h*147456, 384, ZNUM + h*384, 1536,
               2048, 384, 384, 1.0f);
    k_zcomb<<<dim3(3072), B256, 0, stream>>>(ZNUM, VB, DNM, SQSK, XG,
        bn_g, bn_b, (size_t)(i+1)*384, FLG, 21, 22);
  }

  /* ---- h_mixed ---- */
  k_mix<<<dim3(3072), B256, 0, stream>>>(HS, XG, HM, 2048*384, 0.7f, 0.3f);

  /* ---- MHA helper ---- */
  auto run_mha = [&](const float* qin, int nq, const float* kvin, int nkv, int mi, float* OUT){
    bgemm(qin, 384, mWqkv, (size_t)mi*442368, 1152, 29, mbqkv, (size_t)mi*1152, 30,
          nullptr,0,30, nullptr,0,30, 1.f, MQKV, 1152, nq, 384, 384, 0);
    bgemm(kvin, 384, mWqkv, (size_t)mi*442368 + 384, 1152, 29, mbqkv, (size_t)mi*1152 + 384, 30,
          nullptr,0,30, nullptr,0,30, 1.f, MQKV + 384, 1152, nkv, 768, 384, 0);
    k_kt<<<dim3((384*nkv)/256), B256, 0, stream>>>(MQKV, KT, nkv);
    for (int h=0;h<4;h++){
      bgemm_ff(MQKV + h*96, 1152, KT + (size_t)h*96*nkv, nkv, SSC, nkv, nq, nkv, 96, ISQ96);
      k_softmax<<<dim3(nq), B256, 0, stream>>>(SSC, nkv);
      bgemm_ff(SSC, nkv, MQKV + 768 + h*96, 1152, AO + h*96, 384, nq, 96, nkv, 1.0f);
    }
    bgemm(AO, 384, mWo, (size_t)mi*147456, 384, 31, mbo, (size_t)mi*384, 32,
          nullptr,0,32, nullptr,0,32, 1.f, OUT, 384, nq, 384, 384, 0);
  };

  /* ---- traj ---- */
  run_mha(HM, 2048, HM, 2048, 1, TRAJ);
  hipMemsetAsync(TRAJSUM, 0, 576*4, stream);
  k_colsum<<<dim3(2,8), B256, 0, stream>>>(TRAJ, 2048, 384, 1.0f/2048.0f, TRAJSUM);

  /* ---- conv path ---- */
  k_conv3<<<dim3(64,6), B256, 0, stream>>>(HM, c1W, c1b, C1O, 384, 384, FLG, 33, 34);
  k_conv3<<<dim3(64,3), B256, 0, stream>>>(C1O, c2W, c2b, C2O, 384, 192, FLG, 35, 36);
  k_colsum<<<dim3(1,8), B256, 0, stream>>>(C2O, 2048, 192, 1.0f/2048.0f, DECAYSUM);

  /* ---- traj_emb ---- */
  k_gemv1<<<dim3(1), B256, 0, stream>>>(TRAJSUM, 576, opW, 384, opb, TEMB, 384, 0, FLG, 37, 38);

  /* ---- ai_ctx ---- */
  run_mha(ai_h, 2048, user_h, 2048, 0, AICTX);
  hipMemsetAsync(AIPOOL, 0, 384*4, stream);
  k_colsum<<<dim3(2,8), B256, 0, stream>>>(AICTX, 2048, 384, 1.0f/2048.0f, AIPOOL);

  /* ---- pscores ---- */
  k_comb<<<dim3(6144), B256, 0, stream>>>(ai_h, user_h, CB);
  bgemm(CB, 768, as1W, 0, 384, 39, as1b, 0, 40, nullptr,0,40, nullptr,0,40, 1.f,
        PT, 384, 2048, 384, 768, 1);
  k_rowdot<<<dim3(512), B256, 0, stream>>>(PT, 384, 384, as2W, as2b, d_out, 2050, 2048, FLG, 41, 42, 0);

  /* ---- bctx ---- */
  run_mha(ai_h, 2048, belief_h, 1024, 2, TRAJ);
  hipMemsetAsync(BCTXV, 0, 384*4, stream);
  k_colsum<<<dim3(2,8), B256, 0, stream>>>(TRAJ, 2048, 384, 1.0f/2048.0f, BCTXV);

  /* ---- stance delta ---- */
  hipMemcpyAsync(SDIN, stance_h, 384*4, hipMemcpyDeviceToDevice, stream);
  hipMemcpyAsync(SDIN + 384, stance_h + (size_t)2047*384, 384*4, hipMemcpyDeviceToDevice, stream);
  k_gemv1<<<dim3(1), B256, 0, stream>>>(SDIN, 768, sc1W, 384, sc1b, T1, 384, 1, FLG, 43, 44);
  k_gemv1<<<dim3(1), B256, 0, stream>>>(T1, 384, sc2W, 192, sc2b, SDELT, 192, 0, FLG, 45, 46);

  /* ---- classifier ---- */
  k_gemv1<<<dim3(1), B256, 0, stream>>>(TEMB, 1344, cl1W, 384, cl1b, Z1, 384, 0, FLG, 47, 48);
  k_lnrow<<<dim3(1), dim3(128), 0, stream>>>(Z1, Zb, cllng, cllnb, 1, FLG, 49, 50);
  k_gemv1<<<dim3(1), B256, 0, stream>>>(Zb, 384, cl2W, 192, cl2b, Z2, 192, 1, FLG, 51, 52);
  k_final<<<dim3(1), dim3(64), 0, stream>>>(Z2, cl3W, cl3b, d_out, FLG, 53, 54, 0);

  /* ---- per_turn ---- */
  k_rowdot<<<dim3(512), B256, 0, stream>>>(AICTX, 384, 384, tpW, tpb, d_out, 2, 2048, FLG, 55, 56, 0);
}

// Round 4
// 12880.070 us; speedup vs baseline: 2.0039x; 2.0039x over previous
//
#include <hip/hip_runtime.h>
#include <hip/hip_bf16.h>

#define NEDGE 229376
#define NTOT  8192
#define BNCONST 0.9999950000374997f   /* 1/sqrt(1+1e-5) */
#define ISQ96   0.10206207261596575f  /* 1/sqrt(96) */

__constant__ int c_NT[5]     = {2048,2048,2048,1024,1024};
__constant__ int c_OFFS[5]   = {0,2048,4096,6144,7168};
__constant__ int c_ESRC[8]   = {0,1,1,2,0,3,1,4};
__constant__ int c_EDST[8]   = {1,0,2,2,3,1,4,2};
__constant__ int c_EOFF[9]   = {0,32768,65536,98304,131072,147456,180224,196608,229376};
__constant__ int c_RELROW[8] = {0,2048,4096,6144,8192,10240,11264,13312};

static const int h_NT[5]   = {2048,2048,2048,1024,1024};
static const int h_OFFS[5] = {0,2048,4096,6144,7168};

__device__ inline float gelu_f(float x){ return 0.5f*x*(1.0f+erff(x*0.70710678118654752f)); }
__device__ inline float sigm(float x){ return 1.0f/(1.0f+expf(-x)); }
__device__ inline float wsum64(float v){
  #pragma unroll
  for (int s=32;s>0;s>>=1) v += __shfl_xor(v, s, 64);
  return v;
}
__device__ inline float wmax64(float v){
  #pragma unroll
  for (int s=32;s>0;s>>=1) v = fmaxf(v, __shfl_xor(v, s, 64));
  return v;
}
__device__ inline unsigned encf(float f){
  unsigned b = __float_as_uint(f);
  return (b & 0x80000000u) ? ~b : (b | 0x80000000u);
}
__device__ inline float decf(unsigned u){
  unsigned b = (u & 0x80000000u) ? (u & 0x7FFFFFFFu) : ~u;
  return __uint_as_float(b);
}
__device__ inline int row_type(int row){
  return (row<2048)?0:((row<4096)?1:((row<6144)?2:((row<7168)?3:4)));
}

/* ---------------- simple utility kernels ---------------- */

__global__ void k_mix(const float* __restrict__ a, const float* __restrict__ b,
                      float* __restrict__ c, int n, float fa, float fb){
  int i = blockIdx.x*256 + threadIdx.x;
  if (i < n) c[i] = fa*a[i] + fb*b[i];
}

__global__ void k_comb(const float* __restrict__ ai, const float* __restrict__ user,
                       float* __restrict__ cb){
  int i = blockIdx.x*256 + threadIdx.x;
  if (i >= 2048*768) return;
  int n = i / 768, c = i - n*768;
  cb[i] = (c < 384) ? ai[n*384 + c] : user[n*384 + (c-384)];
}

/* ---------------- edge preprocessing (CSR by destination) ---------------- */

__global__ void k_edge_pre(const int* __restrict__ esrc, const int* __restrict__ edst,
                           int* edg, int* esr, int* erl, int* cnt){
  int e = blockIdx.x*256 + threadIdx.x;
  if (e >= NEDGE) return;
  int r = 0;
  #pragma unroll
  for (int q=1;q<8;q++) if (e >= c_EOFF[q]) r = q;
  int dg = c_OFFS[c_EDST[r]] + edst[e];
  edg[e] = dg;
  esr[e] = c_RELROW[r] + esrc[e];
  erl[e] = r;
  atomicAdd(&cnt[dg], 1);
}

__global__ __launch_bounds__(1024) void k_scan(const int* __restrict__ cnt, int* __restrict__ off){
  __shared__ int sh[1024];
  int tid = threadIdx.x;
  int base = tid*8;
  int loc[8]; int run = 0;
  #pragma unroll
  for (int i=0;i<8;i++){ loc[i] = run; run += cnt[base+i]; }
  sh[tid] = run;
  __syncthreads();
  for (int d=1; d<1024; d<<=1){
    int v = (tid >= d) ? sh[tid-d] : 0;
    __syncthreads();
    sh[tid] += v;
    __syncthreads();
  }
  int pre = (tid==0) ? 0 : sh[tid-1];
  #pragma unroll
  for (int i=0;i<8;i++) off[base+i] = pre + loc[i];
  if (tid==1023) off[8192] = sh[1023];
}

__global__ void k_scatter(const int* __restrict__ edg, const int* __restrict__ off,
                          int* cnt2, int* csr){
  int e = blockIdx.x*256 + threadIdx.x;
  if (e >= NEDGE) return;
  int dg = edg[e];
  int pos = off[dg] + atomicAdd(&cnt2[dg], 1);
  csr[pos] = e;
}

/* ---------------- tiled GEMM kernels (64x64 tile, 4x4 microtile) ---------------- */

// C = act( (gelu?(A)@B + bias) * kmul * cs[col] + csh[col] );  A (M,K) lda, B (K,N) ldb
__global__ __launch_bounds__(256) void gemm_f(
    const float* __restrict__ A, int lda, const float* __restrict__ B, int ldb,
    const float* __restrict__ bias, const float* __restrict__ cs, const float* __restrict__ csh,
    float kmul, float* __restrict__ C, int ldc, int M, int N, int K, int act, int agelu)
{
  __shared__ float As[16][65];
  __shared__ float Bs[16][65];
  int tid = threadIdx.x;
  int tx = tid & 15, ty = tid >> 4;
  int m0 = blockIdx.y * 64, n0 = blockIdx.x * 64;
  float acc[4][4] = {};
  for (int kk = 0; kk < K; kk += 16) {
    #pragma unroll
    for (int i = 0; i < 4; i++) {
      int e = tid + i*256;
      int m = e >> 4, k = e & 15;
      int gm = m0 + m;
      float v = 0.f;
      if (gm < M && kk + k < K) v = A[(size_t)gm*lda + kk + k];
      if (agelu) v = gelu_f(v);
      As[k][m] = v;
    }
    #pragma unroll
    for (int i = 0; i < 4; i++) {
      int e = tid + i*256;
      int k = e >> 6, n = e & 63;
      int gn = n0 + n;
      Bs[k][n] = (gn < N && kk + k < K) ? B[(size_t)(kk + k)*ldb + gn] : 0.f;
    }
    __syncthreads();
    #pragma unroll
    for (int k = 0; k < 16; k++) {
      float a[4], b[4];
      #pragma unroll
      for (int i=0;i<4;i++) a[i] = As[k][ty + 16*i];
      #pragma unroll
      for (int j=0;j<4;j++) b[j] = Bs[k][tx + 16*j];
      #pragma unroll
      for (int i=0;i<4;i++)
        #pragma unroll
        for (int j=0;j<4;j++) acc[i][j] += a[i]*b[j];
    }
    __syncthreads();
  }
  #pragma unroll
  for (int i=0;i<4;i++){
    int gm = m0 + ty + 16*i; if (gm >= M) continue;
    #pragma unroll
    for (int j=0;j<4;j++){
      int gn = n0 + tx + 16*j; if (gn >= N) continue;
      float v = acc[i][j];
      if (bias) v += bias[gn];
      float s = kmul;
      if (cs) s *= cs[gn];
      v *= s;
      if (csh) v += csh[gn];
      if (act==1) v = fmaxf(v, 0.f);
      C[(size_t)gm*ldc + gn] = v;
    }
  }
}

// C[m,n] = scale * sum_k A[m,k]*B[n,k]   (Q @ K^T)
__global__ __launch_bounds__(256) void gemm_abt_f(
    const float* __restrict__ A, int lda, const float* __restrict__ B, int ldb,
    float* __restrict__ C, int ldc, int M, int N, int K, float scale)
{
  __shared__ float As[16][65];
  __shared__ float Bs[16][65];
  int tid = threadIdx.x;
  int tx = tid & 15, ty = tid >> 4;
  int m0 = blockIdx.y * 64, n0 = blockIdx.x * 64;
  float acc[4][4] = {};
  for (int kk = 0; kk < K; kk += 16) {
    #pragma unroll
    for (int i = 0; i < 4; i++) {
      int e = tid + i*256;
      int m = e >> 4, k = e & 15;
      int gm = m0 + m;
      As[k][m] = (gm < M && kk + k < K) ? A[(size_t)gm*lda + kk + k] : 0.f;
    }
    #pragma unroll
    for (int i = 0; i < 4; i++) {
      int e = tid + i*256;
      int n = e >> 4, k = e & 15;
      int gn = n0 + n;
      Bs[k][n] = (gn < N && kk + k < K) ? B[(size_t)gn*ldb + kk + k] : 0.f;
    }
    __syncthreads();
    #pragma unroll
    for (int k = 0; k < 16; k++) {
      float a[4], b[4];
      #pragma unroll
      for (int i=0;i<4;i++) a[i] = As[k][ty + 16*i];
      #pragma unroll
      for (int j=0;j<4;j++) b[j] = Bs[k][tx + 16*j];
      #pragma unroll
      for (int i=0;i<4;i++)
        #pragma unroll
        for (int j=0;j<4;j++) acc[i][j] += a[i]*b[j];
    }
    __syncthreads();
  }
  #pragma unroll
  for (int i=0;i<4;i++){
    int gm = m0 + ty + 16*i; if (gm >= M) continue;
    #pragma unroll
    for (int j=0;j<4;j++){
      int gn = n0 + tx + 16*j; if (gn >= N) continue;
      C[(size_t)gm*ldc + gn] = acc[i][j]*scale;
    }
  }
}

// C[m,n] = sum_l A[l,m]*B[l,n]   (K^T @ V)
__global__ __launch_bounds__(256) void gemm_atb_f(
    const float* __restrict__ A, int lda, const float* __restrict__ B, int ldb,
    float* __restrict__ C, int ldc, int M, int N, int L)
{
  __shared__ float As[16][65];
  __shared__ float Bs[16][65];
  int tid = threadIdx.x;
  int tx = tid & 15, ty = tid >> 4;
  int m0 = blockIdx.y * 64, n0 = blockIdx.x * 64;
  float acc[4][4] = {};
  for (int ll = 0; ll < L; ll += 16) {
    #pragma unroll
    for (int i = 0; i < 4; i++) {
      int e = tid + i*256;
      int l = e >> 6, m = e & 63;
      int gm = m0 + m;
      As[l][m] = (gm < M && ll + l < L) ? A[(size_t)(ll + l)*lda + gm] : 0.f;
    }
    #pragma unroll
    for (int i = 0; i < 4; i++) {
      int e = tid + i*256;
      int l = e >> 6, n = e & 63;
      int gn = n0 + n;
      Bs[l][n] = (gn < N && ll + l < L) ? B[(size_t)(ll + l)*ldb + gn] : 0.f;
    }
    __syncthreads();
    #pragma unroll
    for (int l = 0; l < 16; l++) {
      float a[4], b[4];
      #pragma unroll
      for (int i=0;i<4;i++) a[i] = As[l][ty + 16*i];
      #pragma unroll
      for (int j=0;j<4;j++) b[j] = Bs[l][tx + 16*j];
      #pragma unroll
      for (int i=0;i<4;i++)
        #pragma unroll
        for (int j=0;j<4;j++) acc[i][j] += a[i]*b[j];
    }
    __syncthreads();
  }
  #pragma unroll
  for (int i=0;i<4;i++){
    int gm = m0 + ty + 16*i; if (gm >= M) continue;
    #pragma unroll
    for (int j=0;j<4;j++){
      int gn = n0 + tx + 16*j; if (gn >= N) continue;
      C[(size_t)gm*ldc + gn] = acc[i][j];
    }
  }
}

/* ---------------- HGT relation projection: KE/VE = K_s @ rel (per head) ---------------- */
// grid (128, 4, 16)  z = r*2 + which(0=k,1=v), block (96,2)
__global__ __launch_bounds__(192) void k_relproj(
    const float* __restrict__ KQV_, const float* __restrict__ krel_l,
    const float* __restrict__ vrel_l, float* __restrict__ KE_, float* __restrict__ VE_)
{
  int r = blockIdx.z >> 1, w = blockIdx.z & 1, h = blockIdx.y;
  int s = c_ESRC[r];
  int Ns = c_NT[s];
  int row0 = blockIdx.x * 16;
  if (row0 >= Ns) return;
  __shared__ float Wl[96*96];
  __shared__ float Ar[2][96];
  const float* Wp = (w ? vrel_l : krel_l) + (size_t)(r*4 + h)*9216;
  int tid = threadIdx.y*96 + threadIdx.x;
  for (int idx = tid; idx < 9216; idx += 192) Wl[idx] = Wp[idx];
  __syncthreads();
  int colbase = (w ? 768 : 0) + h*96;
  float* OUT = (w ? VE_ : KE_);
  for (int it = 0; it < 8; it++){
    int rr = row0 + it*2 + threadIdx.y;
    const float* a = KQV_ + (size_t)(c_OFFS[s] + rr)*1152 + colbase;
    Ar[threadIdx.y][threadIdx.x] = a[threadIdx.x];
    __syncthreads();
    float acc = 0.f;
    #pragma unroll 8
    for (int d = 0; d < 96; d++) acc += Ar[threadIdx.y][d] * Wl[d*96 + threadIdx.x];
    OUT[(size_t)(c_RELROW[r] + rr)*384 + h*96 + threadIdx.x] = acc;
    __syncthreads();
  }
}

/* ---------------- edge attention ---------------- */

__global__ __launch_bounds__(256) void k_escore(
    const float* __restrict__ KQV_, const float* __restrict__ KE_,
    const int* __restrict__ edg, const int* __restrict__ esr, const int* __restrict__ erl,
    const float* __restrict__ prel_l, float* __restrict__ EA)
{
  int e = blockIdx.x*4 + (threadIdx.x>>6);
  if (e >= NEDGE) return;
  int lane = threadIdx.x & 63;
  int h = lane >> 4, j = lane & 15;
  int dg = edg[e], sr = esr[e], r = erl[e];
  const float* q  = KQV_ + (size_t)dg*1152 + 384 + h*96;
  const float* ke = KE_  + (size_t)sr*384 + h*96;
  float p = 0.f;
  #pragma unroll
  for (int t=0;t<6;t++){ int d = j + t*16; p += q[d]*ke[d]; }
  p += __shfl_xor(p, 1, 64);
  p += __shfl_xor(p, 2, 64);
  p += __shfl_xor(p, 4, 64);
  p += __shfl_xor(p, 8, 64);
  if (j == 0) EA[(size_t)e*4 + h] = p * prel_l[r*4+h] * ISQ96;
}

__global__ void k_segmax(const float* __restrict__ EA, const int* __restrict__ edg,
                         unsigned* __restrict__ EMX){
  int i = blockIdx.x*256 + threadIdx.x;
  if (i >= NEDGE*4) return;
  int e = i >> 2, h = i & 3;
  atomicMax(&EMX[edg[e]*4 + h], encf(EA[i]));
}

__global__ void k_expsum(float* __restrict__ EA, const int* __restrict__ edg,
                         const unsigned* __restrict__ EMX, float* __restrict__ EDEN){
  int i = blockIdx.x*256 + threadIdx.x;
  if (i >= NEDGE*4) return;
  int e = i >> 2, h = i & 3;
  int dg = edg[e];
  float m = decf(EMX[dg*4 + h]);
  float ex = expf(EA[i] - m);
  EA[i] = ex;
  atomicAdd(&EDEN[dg*4 + h], ex);
}

__global__ __launch_bounds__(128) void k_agg(
    const float* __restrict__ EA, const float* __restrict__ VE_,
    const float* __restrict__ EDEN, const int* __restrict__ csr,
    const int* __restrict__ off, const int* __restrict__ esr, float* __restrict__ AGG)
{
  int node = blockIdx.x, tid = threadIdx.x;
  int b = off[node], e1 = off[node+1];
  int d0 = tid, d1 = tid+128, d2 = tid+256;
  int h0 = d0/96, h1 = d1/96, h2 = d2/96;
  float a0=0.f, a1=0.f, a2=0.f;
  if (e1 > b){
    float i0 = 1.0f/EDEN[node*4+h0];
    float i1 = 1.0f/EDEN[node*4+h1];
    float i2 = 1.0f/EDEN[node*4+h2];
    for (int p=b; p<e1; p++){
      int e = csr[p];
      const float* ve = VE_ + (size_t)esr[e]*384;
      const float* ea = EA + (size_t)e*4;
      a0 += ea[h0]*i0*ve[d0];
      a1 += ea[h1]*i1*ve[d1];
      a2 += ea[h2]*i2*ve[d2];
    }
  }
  AGG[(size_t)node*384 + d0] = a0;
  AGG[(size_t)node*384 + d1] = a1;
  AGG[(size_t)node*384 + d2] = a2;
}

/* ---------------- row-wise norm kernels ---------------- */

__global__ __launch_bounds__(128) void k_gateln(
    const float* __restrict__ O, float* __restrict__ X,
    const float* __restrict__ skip_l, const float* __restrict__ lng, const float* __restrict__ lnb)
{
  __shared__ float red[2];
  int row = blockIdx.x, tid = threadIdx.x;
  int t = row_type(row);
  float gt = sigm(skip_l[t]);
  const float* o = O + (size_t)row*384;
  float* x = X + (size_t)row*384;
  float v0 = gelu_f(gt*o[tid]     + (1.f-gt)*x[tid]);
  float v1 = gelu_f(gt*o[tid+128] + (1.f-gt)*x[tid+128]);
  float v2 = gelu_f(gt*o[tid+256] + (1.f-gt)*x[tid+256]);
  int lane = tid & 63, wid = tid >> 6;
  float s = wsum64(v0+v1+v2);
  if (lane==0) red[wid] = s;
  __syncthreads();
  float mean = (red[0]+red[1]) * (1.0f/384.0f);
  __syncthreads();
  float d0=v0-mean, d1=v1-mean, d2=v2-mean;
  float q = wsum64(d0*d0+d1*d1+d2*d2);
  if (lane==0) red[wid] = q;
  __syncthreads();
  float var = (red[0]+red[1]) * (1.0f/384.0f);
  float rs = 1.0f/sqrtf(var + 1e-5f);
  const float* g = lng + (size_t)t*384;
  const float* b = lnb + (size_t)t*384;
  x[tid]     = d0*rs*g[tid]     + b[tid];
  x[tid+128] = d1*rs*g[tid+128] + b[tid+128];
  x[tid+256] = d2*rs*g[tid+256] + b[tid+256];
}

__global__ __launch_bounds__(128) void k_lnrow(
    const float* __restrict__ X, float* __restrict__ Y,
    const float* __restrict__ g, const float* __restrict__ b, int act)
{
  __shared__ float red[2];
  int row = blockIdx.x, tid = threadIdx.x;
  const float* x = X + (size_t)row*384;
  float* y = Y + (size_t)row*384;
  float v0 = x[tid], v1 = x[tid+128], v2 = x[tid+256];
  int lane = tid & 63, wid = tid >> 6;
  float s = wsum64(v0+v1+v2);
  if (lane==0) red[wid] = s;
  __syncthreads();
  float mean = (red[0]+red[1]) * (1.0f/384.0f);
  __syncthreads();
  float d0=v0-mean, d1=v1-mean, d2=v2-mean;
  float q = wsum64(d0*d0+d1*d1+d2*d2);
  if (lane==0) red[wid] = q;
  __syncthreads();
  float var = (red[0]+red[1]) * (1.0f/384.0f);
  float rs = 1.0f/sqrtf(var + 1e-5f);
  float u0 = d0*rs*g[tid]     + b[tid];
  float u1 = d1*rs*g[tid+128] + b[tid+128];
  float u2 = d2*rs*g[tid+256] + b[tid+256];
  if (act==1){ u0=fmaxf(u0,0.f); u1=fmaxf(u1,0.f); u2=fmaxf(u2,0.f); }
  else       { u0=gelu_f(u0); u1=gelu_f(u1); u2=gelu_f(u2); }
  y[tid] = u0; y[tid+128] = u1; y[tid+256] = u2;
}

/* ---------------- softmax / reductions / misc ---------------- */

__global__ __launch_bounds__(256) void k_softmax(float* __restrict__ S, int L){
  __shared__ float red[4];
  int row = blockIdx.x, tid = threadIdx.x;
  float* p = S + (size_t)row*L;
  float m = -3.0e38f;
  for (int c=tid;c<L;c+=256) m = fmaxf(m, p[c]);
  m = wmax64(m);
  int lane = tid & 63, wid = tid >> 6;
  if (lane==0) red[wid] = m;
  __syncthreads();
  m = fmaxf(fmaxf(red[0],red[1]), fmaxf(red[2],red[3]));
  __syncthreads();
  float s = 0.f;
  for (int c=tid;c<L;c+=256){ float e = expf(p[c]-m); p[c]=e; s += e; }
  s = wsum64(s);
  if (lane==0) red[wid] = s;
  __syncthreads();
  float inv = 1.0f/(red[0]+red[1]+red[2]+red[3]);
  for (int c=tid;c<L;c+=256) p[c] *= inv;
}

__global__ __launch_bounds__(256) void k_sumsq(const float* __restrict__ x, int n, float* out){
  __shared__ float red[4];
  float s = 0.f;
  for (int i = blockIdx.x*256 + threadIdx.x; i < n; i += gridDim.x*256){ float v=x[i]; s += v*v; }
  s = wsum64(s);
  int lane = threadIdx.x & 63, wid = threadIdx.x >> 6;
  if (lane==0) red[wid] = s;
  __syncthreads();
  if (threadIdx.x==0) atomicAdd(out, red[0]+red[1]+red[2]+red[3]);
}

__global__ void k_colsum(const float* __restrict__ A, int R, int C, float scale,
                         float* __restrict__ out){
  int col = blockIdx.x*256 + threadIdx.x;
  if (col >= C) return;
  int nchunk = gridDim.y;
  int chunk = (R + nchunk - 1)/nchunk;
  int r0 = blockIdx.y*chunk, r1 = min(R, r0+chunk);
  float s = 0.f;
  for (int r=r0; r<r1; r++) s += A[(size_t)r*C + col];
  atomicAdd(&out[col], s*scale);
}

__global__ __launch_bounds__(256) void k_dnm(const float* __restrict__ QB,
    const float* __restrict__ KSUM, const float* __restrict__ sqsk, float* __restrict__ DNM){
  int wv = blockIdx.x*4 + (threadIdx.x>>6);
  int n = wv >> 2, h = wv & 3;
  int lane = threadIdx.x & 63;
  const float* q = QB + (size_t)n*1536 + h*384;
  const float* ks = KSUM + h*384;
  float p = 0.f;
  #pragma unroll
  for (int d=lane; d<384; d+=64) p += q[d]*ks[d];
  p = wsum64(p);
  if (lane==0) DNM[n*4+h] = p * (1.0f/sqrtf(sqsk[0]*sqsk[1])) + 2048.0f;
}

__global__ void k_zcomb(const float* __restrict__ ZN, const float* __restrict__ VB_,
                        const float* __restrict__ DNM_, const float* __restrict__ sqsk,
                        float* __restrict__ XG_,
                        const float* __restrict__ bng, const float* __restrict__ bnb){
  int i = blockIdx.x*256 + threadIdx.x;
  if (i >= 2048*384) return;
  int n = i / 384, c = i - n*384;
  float inv_s = 1.0f/sqrtf(sqsk[0]*sqsk[1]);
  float zm = 0.f;
  #pragma unroll
  for (int h=0;h<4;h++){
    float num = ZN[(size_t)n*1536 + h*384 + c]*inv_s + 2048.0f*VB_[(size_t)n*1536 + h*384 + c];
    zm += num / DNM_[n*4+h];
  }
  zm *= 0.25f;
  float y = 0.5f*zm + 0.5f*XG_[i];
  y = y * (bng[c] * BNCONST) + bnb[c];
  XG_[i] = fmaxf(y, 0.f);
}

/* ---------------- conv1d (kernel 3, pad 1), in/out (pos, ch), gelu ---------------- */
__global__ __launch_bounds__(256) void k_conv3(
    const float* __restrict__ in, const float* __restrict__ W, const float* __restrict__ bias,
    float* __restrict__ out, int IC, int OC)
{
  __shared__ float xs[34][384];
  int tid = threadIdx.x;
  int p0 = blockIdx.x*32, oc0 = blockIdx.y*64;
  for (int idx = tid; idx < 34*IC; idx += 256){
    int rr = idx / IC, c = idx - rr*IC;
    int gp = p0 - 1 + rr;
    xs[rr][c] = (gp >= 0 && gp < 2048) ? in[(size_t)gp*IC + c] : 0.f;
  }
  __syncthreads();
  int oc = oc0 + (tid & 63);
  int py = tid >> 6;
  float acc[8] = {0,0,0,0,0,0,0,0};
  const float* Wp = W + (size_t)oc*IC*3;
  for (int c=0;c<IC;c++){
    float w0 = Wp[c*3+0], w1 = Wp[c*3+1], w2 = Wp[c*3+2];
    #pragma unroll
    for (int u=0;u<8;u++){
      int pl = py + u*4;
      acc[u] += w0*xs[pl][c] + w1*xs[pl+1][c] + w2*xs[pl+2][c];
    }
  }
  float b = bias[oc];
  #pragma unroll
  for (int u=0;u<8;u++){
    int pl = py + u*4;
    out[(size_t)(p0+pl)*OC + oc] = gelu_f(acc[u] + b);
  }
}

/* ---------------- small dense kernels ---------------- */

__global__ __launch_bounds__(256) void k_gemv1(const float* __restrict__ in, int K,
    const float* __restrict__ W, int ldw, const float* __restrict__ b,
    float* __restrict__ out, int N, int act){
  __shared__ float x[1344];
  int tid = threadIdx.x;
  for (int i = tid; i < K; i += 256) x[i] = in[i];
  __syncthreads();
  for (int c = tid; c < N; c += 256){
    float acc = 0.f;
    for (int k = 0; k < K; k++) acc += x[k]*W[(size_t)k*ldw + c];
    acc += b[c];
    if (act==1) acc = fmaxf(acc, 0.f);
    out[c] = acc;
  }
}

// out[r] = sigmoid(A[r,:K] . w + b)  -> f32
__global__ __launch_bounds__(256) void k_rowdot(const float* __restrict__ A, int lda, int K,
    const float* __restrict__ w, const float* __restrict__ b, float* __restrict__ out, int M){
  int r = blockIdx.x*4 + (threadIdx.x>>6);
  if (r >= M) return;
  int lane = threadIdx.x & 63;
  const float* a = A + (size_t)r*lda;
  float p = 0.f;
  for (int k = lane; k < K; k += 64) p += a[k]*w[k];
  p = wsum64(p);
  if (lane==0) out[r] = sigm(p + b[0]);
}

__global__ __launch_bounds__(64) void k_final(const float* __restrict__ z2,
    const float* __restrict__ w, const float* __restrict__ b, float* __restrict__ out){
  int lane = threadIdx.x;
  float p = 0.f;
  for (int k = lane; k < 192; k += 64) p += z2[k]*w[k];
  p = wsum64(p);
  if (lane==0){
    float l = p + b[0];
    out[0] = l;
    out[1] = sigm(l);
  }
}

/* ================================================================ */

extern "C" void kernel_launch(void* const* d_in, const int* in_sizes, int n_in,
                              void* d_out, int out_size, void* d_ws, size_t ws_size,
                              hipStream_t stream)
{
  const float* xin[5] = {(const float*)d_in[0], (const float*)d_in[1], (const float*)d_in[2],
                         (const float*)d_in[3], (const float*)d_in[4]};
  const float* Wkqv=(const float*)d_in[5];  const float* bkqv=(const float*)d_in[6];
  const float* Wout=(const float*)d_in[7];  const float* bout=(const float*)d_in[8];
  const float* krel=(const float*)d_in[9];  const float* vrel=(const float*)d_in[10];
  const float* prel=(const float*)d_in[11]; const float* skp =(const float*)d_in[12];
  const float* lng =(const float*)d_in[13]; const float* lnb =(const float*)d_in[14];
  const float* sp_W=(const float*)d_in[15]; const float* sp_b=(const float*)d_in[16];
  const float* sp_lng=(const float*)d_in[17]; const float* sp_lnb=(const float*)d_in[18];
  const float* fc0_W=(const float*)d_in[19]; const float* fc0_b=(const float*)d_in[20];
  const float* bn_g=(const float*)d_in[21]; const float* bn_b=(const float*)d_in[22];
  const float* tq_W=(const float*)d_in[23]; const float* tq_b=(const float*)d_in[24];
  const float* tk_W=(const float*)d_in[25]; const float* tk_b=(const float*)d_in[26];
  const float* tv_W=(const float*)d_in[27]; const float* tv_b=(const float*)d_in[28];
  const float* mWqkv=(const float*)d_in[29]; const float* mbqkv=(const float*)d_in[30];
  const float* mWo=(const float*)d_in[31];  const float* mbo=(const float*)d_in[32];
  const float* c1W=(const float*)d_in[33];  const float* c1b=(const float*)d_in[34];
  const float* c2W=(const float*)d_in[35];  const float* c2b=(const float*)d_in[36];
  const float* opW=(const float*)d_in[37];  const float* opb=(const float*)d_in[38];
  const float* as1W=(const float*)d_in[39]; const float* as1b=(const float*)d_in[40];
  const float* as2W=(const float*)d_in[41]; const float* as2b=(const float*)d_in[42];
  const float* sc1W=(const float*)d_in[43]; const float* sc1b=(const float*)d_in[44];
  const float* sc2W=(const float*)d_in[45]; const float* sc2b=(const float*)d_in[46];
  const float* cl1W=(const float*)d_in[47]; const float* cl1b=(const float*)d_in[48];
  const float* cllng=(const float*)d_in[49]; const float* cllnb=(const float*)d_in[50];
  const float* cl2W=(const float*)d_in[51]; const float* cl2b=(const float*)d_in[52];
  const float* cl3W=(const float*)d_in[53]; const float* cl3b=(const float*)d_in[54];
  const float* tpW=(const float*)d_in[55];  const float* tpb=(const float*)d_in[56];
  const int* e_src=(const int*)d_in[57];  const int* e_dst=(const int*)d_in[58];
  float* out = (float*)d_out;

  /* workspace arena */
  char* ws = (char*)d_ws;
  size_t off_b = 0;
  auto alloc = [&](size_t bytes)->char*{
    char* r = ws + off_b;
    off_b = (off_b + bytes + 255) & ~(size_t)255;
    return r;
  };
  float* X    = (float*)alloc((size_t)8192*384*4);
  float* KQV  = (float*)alloc((size_t)8192*1152*4);
  float* KE   = (float*)alloc((size_t)14336*384*4);
  float* VE   = (float*)alloc((size_t)14336*384*4);
  float* AGG  = (float*)alloc((size_t)8192*384*4);
  float* EA   = (float*)alloc((size_t)NEDGE*4*4);
  int* edg    = (int*)alloc((size_t)NEDGE*4);
  int* esr    = (int*)alloc((size_t)NEDGE*4);
  int* erl    = (int*)alloc((size_t)NEDGE*4);
  int* csr    = (int*)alloc((size_t)NEDGE*4);
  int* cnt    = (int*)alloc(8192*4);
  int* cnt2   = (int*)alloc(8192*4);
  int* coff   = (int*)alloc(8193*4);
  unsigned* EMX = (unsigned*)alloc(8192*4*4);
  float* EDEN = (float*)alloc(8192*4*4);
  float* SM   = (float*)alloc(65536);
  if (off_b > ws_size) return;

  float* SQSK = SM;
  float* TRAJSUM = SM + 8;
  float* DECAYSUM = SM + 392;
  float* TEMB = SM + 600;
  float* AIPOOL = SM + 984;
  float* BCTXV = SM + 1368;
  float* SDELT = SM + 1752;
  float* SDIN = SM + 2048;
  float* T1   = SM + 2816;
  float* Z1   = SM + 3200;
  float* Zb   = SM + 3584;
  float* Z2   = SM + 3968;
  float* KSUM = SM + 4224;
  float* DNM  = SM + 6144;

  float* QB = KQV;
  float* KB = KQV + (size_t)2048*1536;
  float* VB = KQV + (size_t)2*2048*1536;
  float* MQKV = KQV;
  float* AO = KQV + (size_t)2*2048*1536;
  float* SSC = KE;
  float* ZNUM = KE;
  float* OWT = KE;
  float* HS = VE;
  float* XG = VE + (size_t)2048*384;
  float* HM = VE + (size_t)2*2048*384;
  float* C1O = VE + (size_t)3*2048*384;
  float* TRAJ = VE + (size_t)4*2048*384;
  float* AICTX = VE + (size_t)5*2048*384;
  float* C2O = VE + (size_t)6*2048*384;
  float* TMPA = AGG;
  float* CB = AGG;
  float* PT = AGG + (size_t)2048*768;
  float* KVS = AGG + (size_t)2048*1152;

  dim3 B256(256);
  auto gemm = [&](const float* A, int lda, const float* Bw, int ldb, const float* bias,
                  const float* cs, const float* csh, float kmul,
                  float* C, int ldc, int M, int N, int K, int act, int agelu){
    dim3 g((N+63)/64, (M+63)/64);
    gemm_f<<<g, B256, 0, stream>>>(A, lda, Bw, ldb, bias, cs, csh, kmul, C, ldc, M, N, K, act, agelu);
  };
  auto gemm_abt = [&](const float* A, int lda, const float* B, int ldb, float* C, int ldc,
                      int M, int N, int K, float scale){
    dim3 g((N+63)/64, (M+63)/64);
    gemm_abt_f<<<g, B256, 0, stream>>>(A, lda, B, ldb, C, ldc, M, N, K, scale);
  };
  auto gemm_atb = [&](const float* A, int lda, const float* B, int ldb, float* C, int ldc,
                      int M, int N, int L){
    dim3 g((N+63)/64, (M+63)/64);
    gemm_atb_f<<<g, B256, 0, stream>>>(A, lda, B, ldb, C, ldc, M, N, L);
  };

  /* ---- edge CSR ---- */
  hipMemsetAsync(cnt, 0, 8192*4, stream);
  hipMemsetAsync(cnt2, 0, 8192*4, stream);
  k_edge_pre<<<dim3(NEDGE/256), B256, 0, stream>>>(e_src, e_dst, edg, esr, erl, cnt);
  k_scan<<<dim3(1), dim3(1024), 0, stream>>>(cnt, coff);
  k_scatter<<<dim3(NEDGE/256), B256, 0, stream>>>(edg, coff, cnt2, csr);

  /* ---- inputs -> X (d2d copy; f32 contiguous by type) ---- */
  for (int t=0;t<5;t++)
    hipMemcpyAsync(X + (size_t)h_OFFS[t]*384, xin[t], (size_t)h_NT[t]*384*4,
                   hipMemcpyDeviceToDevice, stream);

  /* ---- HGT layers ---- */
  for (int l=0;l<2;l++){
    for (int t=0;t<5;t++)
      gemm(X + (size_t)h_OFFS[t]*384, 384, Wkqv + (size_t)(l*5+t)*442368, 1152,
           bkqv + (size_t)(l*5+t)*1152, nullptr, nullptr, 1.f,
           KQV + (size_t)h_OFFS[t]*1152, 1152, h_NT[t], 1152, 384, 0, 0);
    k_relproj<<<dim3(128,4,16), dim3(96,2), 0, stream>>>(
        KQV, krel + (size_t)l*294912, vrel + (size_t)l*294912, KE, VE);
    k_escore<<<dim3(NEDGE/4), B256, 0, stream>>>(KQV, KE, edg, esr, erl, prel + (size_t)l*32, EA);
    hipMemsetAsync(EMX, 0, 8192*4*4, stream);
    hipMemsetAsync(EDEN, 0, 8192*4*4, stream);
    k_segmax<<<dim3(NEDGE*4/256), B256, 0, stream>>>(EA, edg, EMX);
    k_expsum<<<dim3(NEDGE*4/256), B256, 0, stream>>>(EA, edg, EMX, EDEN);
    k_agg<<<dim3(NTOT), dim3(128), 0, stream>>>(EA, VE, EDEN, csr, coff, esr, AGG);
    for (int t=0;t<5;t++)
      gemm(AGG + (size_t)h_OFFS[t]*384, 384, Wout + (size_t)(l*5+t)*147456, 384,
           bout + (size_t)(l*5+t)*384, nullptr, nullptr, 1.f,
           OWT + (size_t)h_OFFS[t]*384, 384, h_NT[t], 384, 384, 0, 1 /*gelu on A*/);
    k_gateln<<<dim3(NTOT), dim3(128), 0, stream>>>(OWT, X, skp + l*5, lng, lnb);
  }

  const float* user_h   = X;
  const float* ai_h     = X + (size_t)2048*384;
  const float* stance_h = X + (size_t)4096*384;
  const float* belief_h = X + (size_t)7168*384;

  /* ---- hs, xg ---- */
  gemm(stance_h, 384, sp_W, 384, sp_b, nullptr, nullptr, 1.f, TMPA, 384, 2048, 384, 384, 0, 0);
  k_lnrow<<<dim3(2048), dim3(128), 0, stream>>>(TMPA, HS, sp_lng, sp_lnb, 0 /*gelu*/);
  gemm(HS, 384, fc0_W, 384, fc0_b, bn_g, bn_b, BNCONST, XG, 384, 2048, 384, 384, 1 /*relu*/, 0);

  /* ---- linear-attention blocks ---- */
  for (int i=0;i<2;i++){
    gemm(XG, 384, tq_W + (size_t)i*589824, 1536, tq_b + (size_t)i*1536, nullptr, nullptr, 1.f,
         QB, 1536, 2048, 1536, 384, 0, 0);
    gemm(XG, 384, tk_W + (size_t)i*589824, 1536, tk_b + (size_t)i*1536, nullptr, nullptr, 1.f,
         KB, 1536, 2048, 1536, 384, 0, 0);
    gemm(XG, 384, tv_W + (size_t)i*589824, 1536, tv_b + (size_t)i*1536, nullptr, nullptr, 1.f,
         VB, 1536, 2048, 1536, 384, 0, 0);
    hipMemsetAsync(SQSK, 0, 8, stream);
    k_sumsq<<<dim3(512), B256, 0, stream>>>(QB, 2048*1536, SQSK);
    k_sumsq<<<dim3(512), B256, 0, stream>>>(KB, 2048*1536, SQSK+1);
    hipMemsetAsync(KSUM, 0, 1536*4, stream);
    k_colsum<<<dim3(6,8), B256, 0, stream>>>(KB, 2048, 1536, 1.0f, KSUM);
    k_dnm<<<dim3(2048), B256, 0, stream>>>(QB, KSUM, SQSK, DNM);
    for (int h=0;h<4;h++)
      gemm_atb(KB + h*384, 1536, VB + h*384, 1536, KVS + (size_t)h*147456, 384, 384, 384, 2048);
    for (int h=0;h<4;h++)
      gemm(QB + h*384, 1536, KVS + (size_t)h*147456, 384, nullptr, nullptr, nullptr, 1.f,
           ZNUM + h*384, 1536, 2048, 384, 384, 0, 0);
    k_zcomb<<<dim3(3072), B256, 0, stream>>>(ZNUM, VB, DNM, SQSK, XG,
        bn_g + (size_t)(i+1)*384, bn_b + (size_t)(i+1)*384);
  }

  /* ---- h_mixed ---- */
  k_mix<<<dim3(3072), B256, 0, stream>>>(HS, XG, HM, 2048*384, 0.7f, 0.3f);

  /* ---- MHA helper ---- */
  auto run_mha = [&](const float* qin, int nq, const float* kvin, int nkv, int mi, float* OUT){
    const float* Wq = mWqkv + (size_t)mi*442368;
    const float* bq = mbqkv + (size_t)mi*1152;
    gemm(qin, 384, Wq, 1152, bq, nullptr, nullptr, 1.f, MQKV, 1152, nq, 384, 384, 0, 0);
    gemm(kvin, 384, Wq + 384, 1152, bq + 384, nullptr, nullptr, 1.f, MQKV + 384, 1152, nkv, 768, 384, 0, 0);
    for (int h=0;h<4;h++){
      gemm_abt(MQKV + h*96, 1152, MQKV + 384 + h*96, 1152, SSC, nkv, nq, nkv, 96, ISQ96);
      k_softmax<<<dim3(nq), B256, 0, stream>>>(SSC, nkv);
      gemm(SSC, nkv, MQKV + 768 + h*96, 1152, nullptr, nullptr, nullptr, 1.f,
           AO + h*96, 384, nq, 96, nkv, 0, 0);
    }
    gemm(AO, 384, mWo + (size_t)mi*147456, 384, mbo + (size_t)mi*384,
         nullptr, nullptr, 1.f, OUT, 384, nq, 384, 384, 0, 0);
  };

  /* ---- traj ---- */
  run_mha(HM, 2048, HM, 2048, 1, TRAJ);
  hipMemsetAsync(TRAJSUM, 0, 576*4, stream);
  k_colsum<<<dim3(2,8), B256, 0, stream>>>(TRAJ, 2048, 384, 1.0f/2048.0f, TRAJSUM);

  /* ---- conv path ---- */
  k_conv3<<<dim3(64,6), B256, 0, stream>>>(HM, c1W, c1b, C1O, 384, 384);
  k_conv3<<<dim3(64,3), B256, 0, stream>>>(C1O, c2W, c2b, C2O, 384, 192);
  k_colsum<<<dim3(1,8), B256, 0, stream>>>(C2O, 2048, 192, 1.0f/2048.0f, DECAYSUM);

  /* ---- traj_emb ---- */
  k_gemv1<<<dim3(1), B256, 0, stream>>>(TRAJSUM, 576, opW, 384, opb, TEMB, 384, 0);

  /* ---- ai_ctx ---- */
  run_mha(ai_h, 2048, user_h, 2048, 0, AICTX);
  hipMemsetAsync(AIPOOL, 0, 384*4, stream);
  k_colsum<<<dim3(2,8), B256, 0, stream>>>(AICTX, 2048, 384, 1.0f/2048.0f, AIPOOL);

  /* ---- pscores ---- */
  k_comb<<<dim3(6144), B256, 0, stream>>>(ai_h, user_h, CB);
  gemm(CB, 768, as1W, 384, as1b, nullptr, nullptr, 1.f, PT, 384, 2048, 384, 768, 1, 0);
  k_rowdot<<<dim3(512), B256, 0, stream>>>(PT, 384, 384, as2W, as2b, out + 2 + 2048, 2048);

  /* ---- bctx ---- */
  run_mha(ai_h, 2048, belief_h, 1024, 2, TRAJ);
  hipMemsetAsync(BCTXV, 0, 384*4, stream);
  k_colsum<<<dim3(2,8), B256, 0, stream>>>(TRAJ, 2048, 384, 1.0f/2048.0f, BCTXV);

  /* ---- stance delta ---- */
  hipMemcpyAsync(SDIN, stance_h, 384*4, hipMemcpyDeviceToDevice, stream);
  hipMemcpyAsync(SDIN + 384, stance_h + (size_t)2047*384, 384*4, hipMemcpyDeviceToDevice, stream);
  k_gemv1<<<dim3(1), B256, 0, stream>>>(SDIN, 768, sc1W, 384, sc1b, T1, 384, 1);
  k_gemv1<<<dim3(1), B256, 0, stream>>>(T1, 384, sc2W, 192, sc2b, SDELT, 192, 0);

  /* ---- classifier ---- */
  k_gemv1<<<dim3(1), B256, 0, stream>>>(TEMB, 1344, cl1W, 384, cl1b, Z1, 384, 0);
  k_lnrow<<<dim3(1), dim3(128), 0, stream>>>(Z1, Zb, cllng, cllnb, 1 /*relu*/);
  k_gemv1<<<dim3(1), B256, 0, stream>>>(Zb, 384, cl2W, 192, cl2b, Z2, 192, 1);
  k_final<<<dim3(1), dim3(64), 0, stream>>>(Z2, cl3W, cl3b, out);

  /* ---- per_turn ---- */
  k_rowdot<<<dim3(512), B256, 0, stream>>>(AICTX, 384, 384, tpW, tpb, out + 2, 2048);
}

// Round 5
// 6917.280 us; speedup vs baseline: 3.7313x; 1.8620x over previous
//
#include <hip/hip_runtime.h>
#include <hip/hip_bf16.h>

#define NEDGE 229376
#define NTOT  8192
#define BNCONST 0.9999950000374997f   /* 1/sqrt(1+1e-5) */
#define ISQ96   0.10206207261596575f  /* 1/sqrt(96) */

__constant__ int c_NT[5]     = {2048,2048,2048,1024,1024};
__constant__ int c_OFFS[5]   = {0,2048,4096,6144,7168};
__constant__ int c_ESRC[8]   = {0,1,1,2,0,3,1,4};
__constant__ int c_EDST[8]   = {1,0,2,2,3,1,4,2};
__constant__ int c_EOFF[9]   = {0,32768,65536,98304,131072,147456,180224,196608,229376};
__constant__ int c_RELROW[8] = {0,2048,4096,6144,8192,10240,11264,13312};

static const int h_NT[5]   = {2048,2048,2048,1024,1024};
static const int h_OFFS[5] = {0,2048,4096,6144,7168};

__device__ inline float gelu_f(float x){ return 0.5f*x*(1.0f+erff(x*0.70710678118654752f)); }
__device__ inline float sigm(float x){ return 1.0f/(1.0f+expf(-x)); }
__device__ inline float wsum64(float v){
  #pragma unroll
  for (int s=32;s>0;s>>=1) v += __shfl_xor(v, s, 64);
  return v;
}
__device__ inline float wmax64(float v){
  #pragma unroll
  for (int s=32;s>0;s>>=1) v = fmaxf(v, __shfl_xor(v, s, 64));
  return v;
}
__device__ inline unsigned encf(float f){
  unsigned b = __float_as_uint(f);
  return (b & 0x80000000u) ? ~b : (b | 0x80000000u);
}
__device__ inline float decf(unsigned u){
  unsigned b = (u & 0x80000000u) ? (u & 0x7FFFFFFFu) : ~u;
  return __uint_as_float(b);
}
__device__ inline int row_type(int row){
  return (row<2048)?0:((row<4096)?1:((row<6144)?2:((row<7168)?3:4)));
}

/* ---------------- simple utility kernels ---------------- */

__global__ void k_mix(const float* __restrict__ a, const float* __restrict__ b,
                      float* __restrict__ c, int n, float fa, float fb){
  int i = blockIdx.x*256 + threadIdx.x;
  if (i < n) c[i] = fa*a[i] + fb*b[i];
}

__global__ void k_comb(const float* __restrict__ ai, const float* __restrict__ user,
                       float* __restrict__ cb){
  int i = blockIdx.x*256 + threadIdx.x;
  if (i >= 2048*768) return;
  int n = i / 768, c = i - n*768;
  cb[i] = (c < 384) ? ai[n*384 + c] : user[n*384 + (c-384)];
}

/* ---------------- edge preprocessing (CSR by destination) ---------------- */

__global__ void k_edge_pre(const int* __restrict__ esrc, const int* __restrict__ edst,
                           int* edg, int* esr, int* erl, int* cnt){
  int e = blockIdx.x*256 + threadIdx.x;
  if (e >= NEDGE) return;
  int r = 0;
  #pragma unroll
  for (int q=1;q<8;q++) if (e >= c_EOFF[q]) r = q;
  int dg = c_OFFS[c_EDST[r]] + edst[e];
  edg[e] = dg;
  esr[e] = c_RELROW[r] + esrc[e];
  erl[e] = r;
  atomicAdd(&cnt[dg], 1);
}

__global__ __launch_bounds__(1024) void k_scan(const int* __restrict__ cnt, int* __restrict__ off){
  __shared__ int sh[1024];
  int tid = threadIdx.x;
  int base = tid*8;
  int loc[8]; int run = 0;
  #pragma unroll
  for (int i=0;i<8;i++){ loc[i] = run; run += cnt[base+i]; }
  sh[tid] = run;
  __syncthreads();
  for (int d=1; d<1024; d<<=1){
    int v = (tid >= d) ? sh[tid-d] : 0;
    __syncthreads();
    sh[tid] += v;
    __syncthreads();
  }
  int pre = (tid==0) ? 0 : sh[tid-1];
  #pragma unroll
  for (int i=0;i<8;i++) off[base+i] = pre + loc[i];
  if (tid==1023) off[8192] = sh[1023];
}

__global__ void k_scatter(const int* __restrict__ edg, const int* __restrict__ off,
                          int* cnt2, int* csr){
  int e = blockIdx.x*256 + threadIdx.x;
  if (e >= NEDGE) return;
  int dg = edg[e];
  int pos = off[dg] + atomicAdd(&cnt2[dg], 1);
  csr[pos] = e;
}

/* ------- tiled GEMMs: 64x64 tile, contiguous 4x4 microtile, b128 LDS reads ------- */
/* LDS rows padded to 68 floats (272B) so &As[k][ty*4] stays 16B-aligned. */

// C = act( (gelu?(A)@B + bias) * kmul * cs[col] + csh[col] );  A (M,K) lda, B (K,N) ldb
__global__ __launch_bounds__(256) void gemm_f(
    const float* __restrict__ A, int lda, const float* __restrict__ B, int ldb,
    const float* __restrict__ bias, const float* __restrict__ cs, const float* __restrict__ csh,
    float kmul, float* __restrict__ C, int ldc, int M, int N, int K, int act, int agelu)
{
  __shared__ float As[16][68];
  __shared__ float Bs[16][68];
  int tid = threadIdx.x;
  int tx = tid & 15, ty = tid >> 4;
  int m0 = blockIdx.y * 64, n0 = blockIdx.x * 64;
  float acc[4][4] = {};
  for (int kk = 0; kk < K; kk += 16) {
    #pragma unroll
    for (int i = 0; i < 4; i++) {
      int e = tid + i*256;
      int m = e >> 4, k = e & 15;
      int gm = m0 + m;
      float v = 0.f;
      if (gm < M && kk + k < K) v = A[(size_t)gm*lda + kk + k];
      if (agelu) v = gelu_f(v);
      As[k][m] = v;
    }
    #pragma unroll
    for (int i = 0; i < 4; i++) {
      int e = tid + i*256;
      int k = e >> 6, n = e & 63;
      int gn = n0 + n;
      Bs[k][n] = (gn < N && kk + k < K) ? B[(size_t)(kk + k)*ldb + gn] : 0.f;
    }
    __syncthreads();
    #pragma unroll
    for (int k = 0; k < 16; k++) {
      float4 a4 = *reinterpret_cast<const float4*>(&As[k][ty*4]);
      float4 b4 = *reinterpret_cast<const float4*>(&Bs[k][tx*4]);
      float a[4] = {a4.x, a4.y, a4.z, a4.w};
      float b[4] = {b4.x, b4.y, b4.z, b4.w};
      #pragma unroll
      for (int i=0;i<4;i++)
        #pragma unroll
        for (int j=0;j<4;j++) acc[i][j] += a[i]*b[j];
    }
    __syncthreads();
  }
  #pragma unroll
  for (int i=0;i<4;i++){
    int gm = m0 + ty*4 + i; if (gm >= M) continue;
    #pragma unroll
    for (int j=0;j<4;j++){
      int gn = n0 + tx*4 + j; if (gn >= N) continue;
      float v = acc[i][j];
      if (bias) v += bias[gn];
      float s = kmul;
      if (cs) s *= cs[gn];
      v *= s;
      if (csh) v += csh[gn];
      if (act==1) v = fmaxf(v, 0.f);
      C[(size_t)gm*ldc + gn] = v;
    }
  }
}

// C[m,n] = scale * sum_k A[m,k]*B[n,k]   (Q @ K^T)
__global__ __launch_bounds__(256) void gemm_abt_f(
    const float* __restrict__ A, int lda, const float* __restrict__ B, int ldb,
    float* __restrict__ C, int ldc, int M, int N, int K, float scale)
{
  __shared__ float As[16][68];
  __shared__ float Bs[16][68];
  int tid = threadIdx.x;
  int tx = tid & 15, ty = tid >> 4;
  int m0 = blockIdx.y * 64, n0 = blockIdx.x * 64;
  float acc[4][4] = {};
  for (int kk = 0; kk < K; kk += 16) {
    #pragma unroll
    for (int i = 0; i < 4; i++) {
      int e = tid + i*256;
      int m = e >> 4, k = e & 15;
      int gm = m0 + m;
      As[k][m] = (gm < M && kk + k < K) ? A[(size_t)gm*lda + kk + k] : 0.f;
    }
    #pragma unroll
    for (int i = 0; i < 4; i++) {
      int e = tid + i*256;
      int n = e >> 4, k = e & 15;
      int gn = n0 + n;
      Bs[k][n] = (gn < N && kk + k < K) ? B[(size_t)gn*ldb + kk + k] : 0.f;
    }
    __syncthreads();
    #pragma unroll
    for (int k = 0; k < 16; k++) {
      float4 a4 = *reinterpret_cast<const float4*>(&As[k][ty*4]);
      float4 b4 = *reinterpret_cast<const float4*>(&Bs[k][tx*4]);
      float a[4] = {a4.x, a4.y, a4.z, a4.w};
      float b[4] = {b4.x, b4.y, b4.z, b4.w};
      #pragma unroll
      for (int i=0;i<4;i++)
        #pragma unroll
        for (int j=0;j<4;j++) acc[i][j] += a[i]*b[j];
    }
    __syncthreads();
  }
  #pragma unroll
  for (int i=0;i<4;i++){
    int gm = m0 + ty*4 + i; if (gm >= M) continue;
    #pragma unroll
    for (int j=0;j<4;j++){
      int gn = n0 + tx*4 + j; if (gn >= N) continue;
      C[(size_t)gm*ldc + gn] = acc[i][j]*scale;
    }
  }
}

// C[m,n] += sum_l A[l,m]*B[l,n], head-batched + L-split (atomic accumulate).
// grid.z = head*nch + chunk; chunk covers L range [chunk*256, +256)
__global__ __launch_bounds__(256) void gemm_atb_ks(
    const float* __restrict__ A0, int lda, const float* __restrict__ B0, int ldb,
    float* __restrict__ C0, int ldc, int M, int N, int L,
    int hsA, int hsB, int hsC, int nch)
{
  __shared__ float As[16][68];
  __shared__ float Bs[16][68];
  int h = blockIdx.z / nch, c = blockIdx.z % nch;
  const float* A = A0 + (size_t)h*hsA;
  const float* B = B0 + (size_t)h*hsB;
  float* C = C0 + (size_t)h*hsC;
  int l0 = c*256, l1 = min(L, l0+256);
  int tid = threadIdx.x;
  int tx = tid & 15, ty = tid >> 4;
  int m0 = blockIdx.y * 64, n0 = blockIdx.x * 64;
  float acc[4][4] = {};
  for (int ll = l0; ll < l1; ll += 16) {
    #pragma unroll
    for (int i = 0; i < 4; i++) {
      int e = tid + i*256;
      int l = e >> 6, m = e & 63;
      int gm = m0 + m;
      As[l][m] = (gm < M && ll + l < l1) ? A[(size_t)(ll + l)*lda + gm] : 0.f;
    }
    #pragma unroll
    for (int i = 0; i < 4; i++) {
      int e = tid + i*256;
      int l = e >> 6, n = e & 63;
      int gn = n0 + n;
      Bs[l][n] = (gn < N && ll + l < l1) ? B[(size_t)(ll + l)*ldb + gn] : 0.f;
    }
    __syncthreads();
    #pragma unroll
    for (int l = 0; l < 16; l++) {
      float4 a4 = *reinterpret_cast<const float4*>(&As[l][ty*4]);
      float4 b4 = *reinterpret_cast<const float4*>(&Bs[l][tx*4]);
      float a[4] = {a4.x, a4.y, a4.z, a4.w};
      float b[4] = {b4.x, b4.y, b4.z, b4.w};
      #pragma unroll
      for (int i=0;i<4;i++)
        #pragma unroll
        for (int j=0;j<4;j++) acc[i][j] += a[i]*b[j];
    }
    __syncthreads();
  }
  #pragma unroll
  for (int i=0;i<4;i++){
    int gm = m0 + ty*4 + i; if (gm >= M) continue;
    #pragma unroll
    for (int j=0;j<4;j++){
      int gn = n0 + tx*4 + j; if (gn >= N) continue;
      atomicAdd(&C[(size_t)gm*ldc + gn], acc[i][j]);
    }
  }
}

// C += (A@B)*scale over K-chunk (grid.z = chunk of 256); atomic accumulate.
__global__ __launch_bounds__(256) void gemm_nn_ks(
    const float* __restrict__ A, int lda, const float* __restrict__ B, int ldb,
    float* __restrict__ C, int ldc, int M, int N, int K, float scale)
{
  __shared__ float As[16][68];
  __shared__ float Bs[16][68];
  int k0 = blockIdx.z*256, k1 = min(K, k0+256);
  int tid = threadIdx.x;
  int tx = tid & 15, ty = tid >> 4;
  int m0 = blockIdx.y * 64, n0 = blockIdx.x * 64;
  float acc[4][4] = {};
  for (int kk = k0; kk < k1; kk += 16) {
    #pragma unroll
    for (int i = 0; i < 4; i++) {
      int e = tid + i*256;
      int m = e >> 4, k = e & 15;
      int gm = m0 + m;
      As[k][m] = (gm < M && kk + k < k1) ? A[(size_t)gm*lda + kk + k] : 0.f;
    }
    #pragma unroll
    for (int i = 0; i < 4; i++) {
      int e = tid + i*256;
      int k = e >> 6, n = e & 63;
      int gn = n0 + n;
      Bs[k][n] = (gn < N && kk + k < k1) ? B[(size_t)(kk + k)*ldb + gn] : 0.f;
    }
    __syncthreads();
    #pragma unroll
    for (int k = 0; k < 16; k++) {
      float4 a4 = *reinterpret_cast<const float4*>(&As[k][ty*4]);
      float4 b4 = *reinterpret_cast<const float4*>(&Bs[k][tx*4]);
      float a[4] = {a4.x, a4.y, a4.z, a4.w};
      float b[4] = {b4.x, b4.y, b4.z, b4.w};
      #pragma unroll
      for (int i=0;i<4;i++)
        #pragma unroll
        for (int j=0;j<4;j++) acc[i][j] += a[i]*b[j];
    }
    __syncthreads();
  }
  #pragma unroll
  for (int i=0;i<4;i++){
    int gm = m0 + ty*4 + i; if (gm >= M) continue;
    #pragma unroll
    for (int j=0;j<4;j++){
      int gn = n0 + tx*4 + j; if (gn >= N) continue;
      atomicAdd(&C[(size_t)gm*ldc + gn], acc[i][j]*scale);
    }
  }
}

/* ---------------- HGT relation projection: KE/VE = K_s @ rel (per head) ---------------- */
// grid (128, 4, 16)  z = r*2 + which(0=k,1=v), block (96,2)
__global__ __launch_bounds__(192) void k_relproj(
    const float* __restrict__ KQV_, const float* __restrict__ krel_l,
    const float* __restrict__ vrel_l, float* __restrict__ KE_, float* __restrict__ VE_)
{
  int r = blockIdx.z >> 1, w = blockIdx.z & 1, h = blockIdx.y;
  int s = c_ESRC[r];
  int Ns = c_NT[s];
  int row0 = blockIdx.x * 16;
  if (row0 >= Ns) return;
  __shared__ float Wl[96*96];
  __shared__ float Ar[2][96];
  const float* Wp = (w ? vrel_l : krel_l) + (size_t)(r*4 + h)*9216;
  int tid = threadIdx.y*96 + threadIdx.x;
  for (int idx = tid; idx < 9216; idx += 192) Wl[idx] = Wp[idx];
  __syncthreads();
  int colbase = (w ? 768 : 0) + h*96;
  float* OUT = (w ? VE_ : KE_);
  for (int it = 0; it < 8; it++){
    int rr = row0 + it*2 + threadIdx.y;
    const float* a = KQV_ + (size_t)(c_OFFS[s] + rr)*1152 + colbase;
    Ar[threadIdx.y][threadIdx.x] = a[threadIdx.x];
    __syncthreads();
    float acc = 0.f;
    #pragma unroll 8
    for (int d = 0; d < 96; d++) acc += Ar[threadIdx.y][d] * Wl[d*96 + threadIdx.x];
    OUT[(size_t)(c_RELROW[r] + rr)*384 + h*96 + threadIdx.x] = acc;
    __syncthreads();
  }
}

/* ---------------- edge attention ---------------- */

__global__ __launch_bounds__(256) void k_escore(
    const float* __restrict__ KQV_, const float* __restrict__ KE_,
    const int* __restrict__ edg, const int* __restrict__ esr, const int* __restrict__ erl,
    const float* __restrict__ prel_l, float* __restrict__ EA)
{
  int e = blockIdx.x*4 + (threadIdx.x>>6);
  if (e >= NEDGE) return;
  int lane = threadIdx.x & 63;
  int h = lane >> 4, j = lane & 15;
  int dg = edg[e], sr = esr[e], r = erl[e];
  const float* q  = KQV_ + (size_t)dg*1152 + 384 + h*96;
  const float* ke = KE_  + (size_t)sr*384 + h*96;
  float p = 0.f;
  #pragma unroll
  for (int t=0;t<6;t++){ int d = j + t*16; p += q[d]*ke[d]; }
  p += __shfl_xor(p, 1, 64);
  p += __shfl_xor(p, 2, 64);
  p += __shfl_xor(p, 4, 64);
  p += __shfl_xor(p, 8, 64);
  if (j == 0) EA[(size_t)e*4 + h] = p * prel_l[r*4+h] * ISQ96;
}

__global__ void k_segmax(const float* __restrict__ EA, const int* __restrict__ edg,
                         unsigned* __restrict__ EMX){
  int i = blockIdx.x*256 + threadIdx.x;
  if (i >= NEDGE*4) return;
  int e = i >> 2, h = i & 3;
  atomicMax(&EMX[edg[e]*4 + h], encf(EA[i]));
}

__global__ void k_expsum(float* __restrict__ EA, const int* __restrict__ edg,
                         const unsigned* __restrict__ EMX, float* __restrict__ EDEN){
  int i = blockIdx.x*256 + threadIdx.x;
  if (i >= NEDGE*4) return;
  int e = i >> 2, h = i & 3;
  int dg = edg[e];
  float m = decf(EMX[dg*4 + h]);
  float ex = expf(EA[i] - m);
  EA[i] = ex;
  atomicAdd(&EDEN[dg*4 + h], ex);
}

__global__ __launch_bounds__(128) void k_agg(
    const float* __restrict__ EA, const float* __restrict__ VE_,
    const float* __restrict__ EDEN, const int* __restrict__ csr,
    const int* __restrict__ off, const int* __restrict__ esr, float* __restrict__ AGG)
{
  int node = blockIdx.x, tid = threadIdx.x;
  int b = off[node], e1 = off[node+1];
  int d0 = tid, d1 = tid+128, d2 = tid+256;
  int h0 = d0/96, h1 = d1/96, h2 = d2/96;
  float a0=0.f, a1=0.f, a2=0.f;
  if (e1 > b){
    float i0 = 1.0f/EDEN[node*4+h0];
    float i1 = 1.0f/EDEN[node*4+h1];
    float i2 = 1.0f/EDEN[node*4+h2];
    for (int p=b; p<e1; p++){
      int e = csr[p];
      const float* ve = VE_ + (size_t)esr[e]*384;
      const float* ea = EA + (size_t)e*4;
      a0 += ea[h0]*i0*ve[d0];
      a1 += ea[h1]*i1*ve[d1];
      a2 += ea[h2]*i2*ve[d2];
    }
  }
  AGG[(size_t)node*384 + d0] = a0;
  AGG[(size_t)node*384 + d1] = a1;
  AGG[(size_t)node*384 + d2] = a2;
}

/* ---------------- row-wise norm kernels ---------------- */

__global__ __launch_bounds__(128) void k_gateln(
    const float* __restrict__ O, float* __restrict__ X,
    const float* __restrict__ skip_l, const float* __restrict__ lng, const float* __restrict__ lnb)
{
  __shared__ float red[2];
  int row = blockIdx.x, tid = threadIdx.x;
  int t = row_type(row);
  float gt = sigm(skip_l[t]);
  const float* o = O + (size_t)row*384;
  float* x = X + (size_t)row*384;
  float v0 = gelu_f(gt*o[tid]     + (1.f-gt)*x[tid]);
  float v1 = gelu_f(gt*o[tid+128] + (1.f-gt)*x[tid+128]);
  float v2 = gelu_f(gt*o[tid+256] + (1.f-gt)*x[tid+256]);
  int lane = tid & 63, wid = tid >> 6;
  float s = wsum64(v0+v1+v2);
  if (lane==0) red[wid] = s;
  __syncthreads();
  float mean = (red[0]+red[1]) * (1.0f/384.0f);
  __syncthreads();
  float d0=v0-mean, d1=v1-mean, d2=v2-mean;
  float q = wsum64(d0*d0+d1*d1+d2*d2);
  if (lane==0) red[wid] = q;
  __syncthreads();
  float var = (red[0]+red[1]) * (1.0f/384.0f);
  float rs = 1.0f/sqrtf(var + 1e-5f);
  const float* g = lng + (size_t)t*384;
  const float* b = lnb + (size_t)t*384;
  x[tid]     = d0*rs*g[tid]     + b[tid];
  x[tid+128] = d1*rs*g[tid+128] + b[tid+128];
  x[tid+256] = d2*rs*g[tid+256] + b[tid+256];
}

__global__ __launch_bounds__(128) void k_lnrow(
    const float* __restrict__ X, float* __restrict__ Y,
    const float* __restrict__ g, const float* __restrict__ b, int act)
{
  __shared__ float red[2];
  int row = blockIdx.x, tid = threadIdx.x;
  const float* x = X + (size_t)row*384;
  float* y = Y + (size_t)row*384;
  float v0 = x[tid], v1 = x[tid+128], v2 = x[tid+256];
  int lane = tid & 63, wid = tid >> 6;
  float s = wsum64(v0+v1+v2);
  if (lane==0) red[wid] = s;
  __syncthreads();
  float mean = (red[0]+red[1]) * (1.0f/384.0f);
  __syncthreads();
  float d0=v0-mean, d1=v1-mean, d2=v2-mean;
  float q = wsum64(d0*d0+d1*d1+d2*d2);
  if (lane==0) red[wid] = q;
  __syncthreads();
  float var = (red[0]+red[1]) * (1.0f/384.0f);
  float rs = 1.0f/sqrtf(var + 1e-5f);
  float u0 = d0*rs*g[tid]     + b[tid];
  float u1 = d1*rs*g[tid+128] + b[tid+128];
  float u2 = d2*rs*g[tid+256] + b[tid+256];
  if (act==1){ u0=fmaxf(u0,0.f); u1=fmaxf(u1,0.f); u2=fmaxf(u2,0.f); }
  else       { u0=gelu_f(u0); u1=gelu_f(u1); u2=gelu_f(u2); }
  y[tid] = u0; y[tid+128] = u1; y[tid+256] = u2;
}

/* ---------------- softmax / reductions / misc ---------------- */

__global__ __launch_bounds__(256) void k_softmax(float* __restrict__ S, int L){
  __shared__ float red[4];
  int row = blockIdx.x, tid = threadIdx.x;
  float* p = S + (size_t)row*L;
  float m = -3.0e38f;
  for (int c=tid;c<L;c+=256) m = fmaxf(m, p[c]);
  m = wmax64(m);
  int lane = tid & 63, wid = tid >> 6;
  if (lane==0) red[wid] = m;
  __syncthreads();
  m = fmaxf(fmaxf(red[0],red[1]), fmaxf(red[2],red[3]));
  __syncthreads();
  float s = 0.f;
  for (int c=tid;c<L;c+=256){ float e = expf(p[c]-m); p[c]=e; s += e; }
  s = wsum64(s);
  if (lane==0) red[wid] = s;
  __syncthreads();
  float inv = 1.0f/(red[0]+red[1]+red[2]+red[3]);
  for (int c=tid;c<L;c+=256) p[c] *= inv;
}

__global__ __launch_bounds__(256) void k_sumsq(const float* __restrict__ x, int n, float* out){
  __shared__ float red[4];
  float s = 0.f;
  for (int i = blockIdx.x*256 + threadIdx.x; i < n; i += gridDim.x*256){ float v=x[i]; s += v*v; }
  s = wsum64(s);
  int lane = threadIdx.x & 63, wid = threadIdx.x >> 6;
  if (lane==0) red[wid] = s;
  __syncthreads();
  if (threadIdx.x==0) atomicAdd(out, red[0]+red[1]+red[2]+red[3]);
}

__global__ void k_colsum(const float* __restrict__ A, int R, int C, float scale,
                         float* __restrict__ out){
  int col = blockIdx.x*256 + threadIdx.x;
  if (col >= C) return;
  int nchunk = gridDim.y;
  int chunk = (R + nchunk - 1)/nchunk;
  int r0 = blockIdx.y*chunk, r1 = min(R, r0+chunk);
  float s = 0.f;
  for (int r=r0; r<r1; r++) s += A[(size_t)r*C + col];
  atomicAdd(&out[col], s*scale);
}

__global__ __launch_bounds__(256) void k_dnm(const float* __restrict__ QB,
    const float* __restrict__ KSUM, const float* __restrict__ sqsk, float* __restrict__ DNM){
  int wv = blockIdx.x*4 + (threadIdx.x>>6);
  int n = wv >> 2, h = wv & 3;
  int lane = threadIdx.x & 63;
  const float* q = QB + (size_t)n*1536 + h*384;
  const float* ks = KSUM + h*384;
  float p = 0.f;
  #pragma unroll
  for (int d=lane; d<384; d+=64) p += q[d]*ks[d];
  p = wsum64(p);
  if (lane==0) DNM[n*4+h] = p * (1.0f/sqrtf(sqsk[0]*sqsk[1])) + 2048.0f;
}

__global__ void k_zcomb(const float* __restrict__ ZN, const float* __restrict__ VB_,
                        const float* __restrict__ DNM_, const float* __restrict__ sqsk,
                        float* __restrict__ XG_,
                        const float* __restrict__ bng, const float* __restrict__ bnb){
  int i = blockIdx.x*256 + threadIdx.x;
  if (i >= 2048*384) return;
  int n = i / 384, c = i - n*384;
  float inv_s = 1.0f/sqrtf(sqsk[0]*sqsk[1]);
  float zm = 0.f;
  #pragma unroll
  for (int h=0;h<4;h++){
    float num = ZN[(size_t)n*1536 + h*384 + c]*inv_s + 2048.0f*VB_[(size_t)n*1536 + h*384 + c];
    zm += num / DNM_[n*4+h];
  }
  zm *= 0.25f;
  float y = 0.5f*zm + 0.5f*XG_[i];
  y = y * (bng[c] * BNCONST) + bnb[c];
  XG_[i] = fmaxf(y, 0.f);
}

/* ---------------- conv1d (kernel 3, pad 1), in/out (pos, ch), gelu ---------------- */
__global__ __launch_bounds__(256) void k_conv3(
    const float* __restrict__ in, const float* __restrict__ W, const float* __restrict__ bias,
    float* __restrict__ out, int IC, int OC)
{
  __shared__ float xs[34][384];
  int tid = threadIdx.x;
  int p0 = blockIdx.x*32, oc0 = blockIdx.y*64;
  for (int idx = tid; idx < 34*IC; idx += 256){
    int rr = idx / IC, c = idx - rr*IC;
    int gp = p0 - 1 + rr;
    xs[rr][c] = (gp >= 0 && gp < 2048) ? in[(size_t)gp*IC + c] : 0.f;
  }
  __syncthreads();
  int oc = oc0 + (tid & 63);
  int py = tid >> 6;
  float acc[8] = {0,0,0,0,0,0,0,0};
  const float* Wp = W + (size_t)oc*IC*3;
  for (int c=0;c<IC;c++){
    float w0 = Wp[c*3+0], w1 = Wp[c*3+1], w2 = Wp[c*3+2];
    #pragma unroll
    for (int u=0;u<8;u++){
      int pl = py + u*4;
      acc[u] += w0*xs[pl][c] + w1*xs[pl+1][c] + w2*xs[pl+2][c];
    }
  }
  float b = bias[oc];
  #pragma unroll
  for (int u=0;u<8;u++){
    int pl = py + u*4;
    out[(size_t)(p0+pl)*OC + oc] = gelu_f(acc[u] + b);
  }
}

/* ---------------- small dense kernels ---------------- */

__global__ __launch_bounds__(256) void k_gemv1(const float* __restrict__ in, int K,
    const float* __restrict__ W, int ldw, const float* __restrict__ b,
    float* __restrict__ out, int N, int act){
  __shared__ float x[1344];
  int tid = threadIdx.x;
  for (int i = tid; i < K; i += 256) x[i] = in[i];
  __syncthreads();
  for (int c = tid; c < N; c += 256){
    float acc = 0.f;
    for (int k = 0; k < K; k++) acc += x[k]*W[(size_t)k*ldw + c];
    acc += b[c];
    if (act==1) acc = fmaxf(acc, 0.f);
    out[c] = acc;
  }
}

__global__ __launch_bounds__(256) void k_rowdot(const float* __restrict__ A, int lda, int K,
    const float* __restrict__ w, const float* __restrict__ b, float* __restrict__ out, int M){
  int r = blockIdx.x*4 + (threadIdx.x>>6);
  if (r >= M) return;
  int lane = threadIdx.x & 63;
  const float* a = A + (size_t)r*lda;
  float p = 0.f;
  for (int k = lane; k < K; k += 64) p += a[k]*w[k];
  p = wsum64(p);
  if (lane==0) out[r] = sigm(p + b[0]);
}

__global__ __launch_bounds__(64) void k_final(const float* __restrict__ z2,
    const float* __restrict__ w, const float* __restrict__ b, float* __restrict__ out){
  int lane = threadIdx.x;
  float p = 0.f;
  for (int k = lane; k < 192; k += 64) p += z2[k]*w[k];
  p = wsum64(p);
  if (lane==0){
    float l = p + b[0];
    out[0] = l;
    out[1] = sigm(l);
  }
}

/* ================================================================ */

extern "C" void kernel_launch(void* const* d_in, const int* in_sizes, int n_in,
                              void* d_out, int out_size, void* d_ws, size_t ws_size,
                              hipStream_t stream)
{
  const float* xin[5] = {(const float*)d_in[0], (const float*)d_in[1], (const float*)d_in[2],
                         (const float*)d_in[3], (const float*)d_in[4]};
  const float* Wkqv=(const float*)d_in[5];  const float* bkqv=(const float*)d_in[6];
  const float* Wout=(const float*)d_in[7];  const float* bout=(const float*)d_in[8];
  const float* krel=(const float*)d_in[9];  const float* vrel=(const float*)d_in[10];
  const float* prel=(const float*)d_in[11]; const float* skp =(const float*)d_in[12];
  const float* lng =(const float*)d_in[13]; const float* lnb =(const float*)d_in[14];
  const float* sp_W=(const float*)d_in[15]; const float* sp_b=(const float*)d_in[16];
  const float* sp_lng=(const float*)d_in[17]; const float* sp_lnb=(const float*)d_in[18];
  const float* fc0_W=(const float*)d_in[19]; const float* fc0_b=(const float*)d_in[20];
  const float* bn_g=(const float*)d_in[21]; const float* bn_b=(const float*)d_in[22];
  const float* tq_W=(const float*)d_in[23]; const float* tq_b=(const float*)d_in[24];
  const float* tk_W=(const float*)d_in[25]; const float* tk_b=(const float*)d_in[26];
  const float* tv_W=(const float*)d_in[27]; const float* tv_b=(const float*)d_in[28];
  const float* mWqkv=(const float*)d_in[29]; const float* mbqkv=(const float*)d_in[30];
  const float* mWo=(const float*)d_in[31];  const float* mbo=(const float*)d_in[32];
  const float* c1W=(const float*)d_in[33];  const float* c1b=(const float*)d_in[34];
  const float* c2W=(const float*)d_in[35];  const float* c2b=(const float*)d_in[36];
  const float* opW=(const float*)d_in[37];  const float* opb=(const float*)d_in[38];
  const float* as1W=(const float*)d_in[39]; const float* as1b=(const float*)d_in[40];
  const float* as2W=(const float*)d_in[41]; const float* as2b=(const float*)d_in[42];
  const float* sc1W=(const float*)d_in[43]; const float* sc1b=(const float*)d_in[44];
  const float* sc2W=(const float*)d_in[45]; const float* sc2b=(const float*)d_in[46];
  const float* cl1W=(const float*)d_in[47]; const float* cl1b=(const float*)d_in[48];
  const float* cllng=(const float*)d_in[49]; const float* cllnb=(const float*)d_in[50];
  const float* cl2W=(const float*)d_in[51]; const float* cl2b=(const float*)d_in[52];
  const float* cl3W=(const float*)d_in[53]; const float* cl3b=(const float*)d_in[54];
  const float* tpW=(const float*)d_in[55];  const float* tpb=(const float*)d_in[56];
  const int* e_src=(const int*)d_in[57];  const int* e_dst=(const int*)d_in[58];
  float* out = (float*)d_out;

  /* workspace arena */
  char* ws = (char*)d_ws;
  size_t off_b = 0;
  auto alloc = [&](size_t bytes)->char*{
    char* r = ws + off_b;
    off_b = (off_b + bytes + 255) & ~(size_t)255;
    return r;
  };
  float* X    = (float*)alloc((size_t)8192*384*4);
  float* KQV  = (float*)alloc((size_t)8192*1152*4);
  float* KE   = (float*)alloc((size_t)14336*384*4);
  float* VE   = (float*)alloc((size_t)14336*384*4);
  float* AGG  = (float*)alloc((size_t)8192*384*4);
  float* EA   = (float*)alloc((size_t)NEDGE*4*4);
  int* edg    = (int*)alloc((size_t)NEDGE*4);
  int* esr    = (int*)alloc((size_t)NEDGE*4);
  int* erl    = (int*)alloc((size_t)NEDGE*4);
  int* csr    = (int*)alloc((size_t)NEDGE*4);
  int* cnt    = (int*)alloc(8192*4);
  int* cnt2   = (int*)alloc(8192*4);
  int* coff   = (int*)alloc(8193*4);
  unsigned* EMX = (unsigned*)alloc(8192*4*4);
  float* EDEN = (float*)alloc(8192*4*4);
  float* SM   = (float*)alloc(65536);
  if (off_b > ws_size) return;

  float* SQSK = SM;
  float* TRAJSUM = SM + 8;
  float* DECAYSUM = SM + 392;
  float* TEMB = SM + 600;
  float* AIPOOL = SM + 984;
  float* BCTXV = SM + 1368;
  float* SDELT = SM + 1752;
  float* SDIN = SM + 2048;
  float* T1   = SM + 2816;
  float* Z1   = SM + 3200;
  float* Zb   = SM + 3584;
  float* Z2   = SM + 3968;
  float* KSUM = SM + 4224;
  float* DNM  = SM + 6144;

  float* QB = KQV;
  float* KB = KQV + (size_t)2048*1536;
  float* VB = KQV + (size_t)2*2048*1536;
  float* MQKV = KQV;
  float* AO = KQV + (size_t)2*2048*1536;
  float* SSC = KE;
  float* ZNUM = KE;
  float* OWT = KE;
  float* HS = VE;
  float* XG = VE + (size_t)2048*384;
  float* HM = VE + (size_t)2*2048*384;
  float* C1O = VE + (size_t)3*2048*384;
  float* TRAJ = VE + (size_t)4*2048*384;
  float* AICTX = VE + (size_t)5*2048*384;
  float* C2O = VE + (size_t)6*2048*384;
  float* TMPA = AGG;
  float* CB = AGG;
  float* PT = AGG + (size_t)2048*768;
  float* KVS = AGG + (size_t)2048*1152;

  dim3 B256(256);
  auto gemm = [&](const float* A, int lda, const float* Bw, int ldb, const float* bias,
                  const float* cs, const float* csh, float kmul,
                  float* C, int ldc, int M, int N, int K, int act, int agelu){
    dim3 g((N+63)/64, (M+63)/64);
    gemm_f<<<g, B256, 0, stream>>>(A, lda, Bw, ldb, bias, cs, csh, kmul, C, ldc, M, N, K, act, agelu);
  };
  auto gemm_abt = [&](const float* A, int lda, const float* B, int ldb, float* C, int ldc,
                      int M, int N, int K, float scale){
    dim3 g((N+63)/64, (M+63)/64);
    gemm_abt_f<<<g, B256, 0, stream>>>(A, lda, B, ldb, C, ldc, M, N, K, scale);
  };

  /* ---- edge CSR ---- */
  hipMemsetAsync(cnt, 0, 8192*4, stream);
  hipMemsetAsync(cnt2, 0, 8192*4, stream);
  k_edge_pre<<<dim3(NEDGE/256), B256, 0, stream>>>(e_src, e_dst, edg, esr, erl, cnt);
  k_scan<<<dim3(1), dim3(1024), 0, stream>>>(cnt, coff);
  k_scatter<<<dim3(NEDGE/256), B256, 0, stream>>>(edg, coff, cnt2, csr);

  /* ---- inputs -> X ---- */
  for (int t=0;t<5;t++)
    hipMemcpyAsync(X + (size_t)h_OFFS[t]*384, xin[t], (size_t)h_NT[t]*384*4,
                   hipMemcpyDeviceToDevice, stream);

  /* ---- HGT layers ---- */
  for (int l=0;l<2;l++){
    for (int t=0;t<5;t++)
      gemm(X + (size_t)h_OFFS[t]*384, 384, Wkqv + (size_t)(l*5+t)*442368, 1152,
           bkqv + (size_t)(l*5+t)*1152, nullptr, nullptr, 1.f,
           KQV + (size_t)h_OFFS[t]*1152, 1152, h_NT[t], 1152, 384, 0, 0);
    k_relproj<<<dim3(128,4,16), dim3(96,2), 0, stream>>>(
        KQV, krel + (size_t)l*294912, vrel + (size_t)l*294912, KE, VE);
    k_escore<<<dim3(NEDGE/4), B256, 0, stream>>>(KQV, KE, edg, esr, erl, prel + (size_t)l*32, EA);
    hipMemsetAsync(EMX, 0, 8192*4*4, stream);
    hipMemsetAsync(EDEN, 0, 8192*4*4, stream);
    k_segmax<<<dim3(NEDGE*4/256), B256, 0, stream>>>(EA, edg, EMX);
    k_expsum<<<dim3(NEDGE*4/256), B256, 0, stream>>>(EA, edg, EMX, EDEN);
    k_agg<<<dim3(NTOT), dim3(128), 0, stream>>>(EA, VE, EDEN, csr, coff, esr, AGG);
    for (int t=0;t<5;t++)
      gemm(AGG + (size_t)h_OFFS[t]*384, 384, Wout + (size_t)(l*5+t)*147456, 384,
           bout + (size_t)(l*5+t)*384, nullptr, nullptr, 1.f,
           OWT + (size_t)h_OFFS[t]*384, 384, h_NT[t], 384, 384, 0, 1 /*gelu on A*/);
    k_gateln<<<dim3(NTOT), dim3(128), 0, stream>>>(OWT, X, skp + l*5, lng, lnb);
  }

  const float* user_h   = X;
  const float* ai_h     = X + (size_t)2048*384;
  const float* stance_h = X + (size_t)4096*384;
  const float* belief_h = X + (size_t)7168*384;

  /* ---- hs, xg ---- */
  gemm(stance_h, 384, sp_W, 384, sp_b, nullptr, nullptr, 1.f, TMPA, 384, 2048, 384, 384, 0, 0);
  k_lnrow<<<dim3(2048), dim3(128), 0, stream>>>(TMPA, HS, sp_lng, sp_lnb, 0 /*gelu*/);
  gemm(HS, 384, fc0_W, 384, fc0_b, bn_g, bn_b, BNCONST, XG, 384, 2048, 384, 384, 1 /*relu*/, 0);

  /* ---- linear-attention blocks ---- */
  for (int i=0;i<2;i++){
    gemm(XG, 384, tq_W + (size_t)i*589824, 1536, tq_b + (size_t)i*1536, nullptr, nullptr, 1.f,
         QB, 1536, 2048, 1536, 384, 0, 0);
    gemm(XG, 384, tk_W + (size_t)i*589824, 1536, tk_b + (size_t)i*1536, nullptr, nullptr, 1.f,
         KB, 1536, 2048, 1536, 384, 0, 0);
    gemm(XG, 384, tv_W + (size_t)i*589824, 1536, tv_b + (size_t)i*1536, nullptr, nullptr, 1.f,
         VB, 1536, 2048, 1536, 384, 0, 0);
    hipMemsetAsync(SQSK, 0, 8, stream);
    k_sumsq<<<dim3(512), B256, 0, stream>>>(QB, 2048*1536, SQSK);
    k_sumsq<<<dim3(512), B256, 0, stream>>>(KB, 2048*1536, SQSK+1);
    hipMemsetAsync(KSUM, 0, 1536*4, stream);
    k_colsum<<<dim3(6,8), B256, 0, stream>>>(KB, 2048, 1536, 1.0f, KSUM);
    k_dnm<<<dim3(2048), B256, 0, stream>>>(QB, KSUM, SQSK, DNM);
    /* KVS = K^T @ V per head; head-batched + L-split, atomic accumulate */
    hipMemsetAsync(KVS, 0, (size_t)4*147456*4, stream);
    gemm_atb_ks<<<dim3(6,6,32), B256, 0, stream>>>(KB, 1536, VB, 1536, KVS, 384,
        384, 384, 2048, 384, 384, 147456, 8);
    for (int h=0;h<4;h++)
      gemm(QB + h*384, 1536, KVS + (size_t)h*147456, 384, nullptr, nullptr, nullptr, 1.f,
           ZNUM + h*384, 1536, 2048, 384, 384, 0, 0);
    k_zcomb<<<dim3(3072), B256, 0, stream>>>(ZNUM, VB, DNM, SQSK, XG,
        bn_g + (size_t)(i+1)*384, bn_b + (size_t)(i+1)*384);
  }

  /* ---- h_mixed ---- */
  k_mix<<<dim3(3072), B256, 0, stream>>>(HS, XG, HM, 2048*384, 0.7f, 0.3f);

  /* ---- MHA helper ---- */
  auto run_mha = [&](const float* qin, int nq, const float* kvin, int nkv, int mi, float* OUT){
    const float* Wq = mWqkv + (size_t)mi*442368;
    const float* bq = mbqkv + (size_t)mi*1152;
    gemm(qin, 384, Wq, 1152, bq, nullptr, nullptr, 1.f, MQKV, 1152, nq, 384, 384, 0, 0);
    gemm(kvin, 384, Wq + 384, 1152, bq + 384, nullptr, nullptr, 1.f, MQKV + 384, 1152, nkv, 768, 384, 0, 0);
    hipMemsetAsync(AO, 0, (size_t)nq*384*4, stream);
    int nch = (nkv + 255)/256;
    for (int h=0;h<4;h++){
      gemm_abt(MQKV + h*96, 1152, MQKV + 384 + h*96, 1152, SSC, nkv, nq, nkv, 96, ISQ96);
      k_softmax<<<dim3(nq), B256, 0, stream>>>(SSC, nkv);
      gemm_nn_ks<<<dim3(2, (nq+63)/64, nch), B256, 0, stream>>>(
          SSC, nkv, MQKV + 768 + h*96, 1152, AO + h*96, 384, nq, 96, nkv, 1.0f);
    }
    gemm(AO, 384, mWo + (size_t)mi*147456, 384, mbo + (size_t)mi*384,
         nullptr, nullptr, 1.f, OUT, 384, nq, 384, 384, 0, 0);
  };

  /* ---- traj ---- */
  run_mha(HM, 2048, HM, 2048, 1, TRAJ);
  hipMemsetAsync(TRAJSUM, 0, 576*4, stream);
  k_colsum<<<dim3(2,8), B256, 0, stream>>>(TRAJ, 2048, 384, 1.0f/2048.0f, TRAJSUM);

  /* ---- conv path ---- */
  k_conv3<<<dim3(64,6), B256, 0, stream>>>(HM, c1W, c1b, C1O, 384, 384);
  k_conv3<<<dim3(64,3), B256, 0, stream>>>(C1O, c2W, c2b, C2O, 384, 192);
  k_colsum<<<dim3(1,8), B256, 0, stream>>>(C2O, 2048, 192, 1.0f/2048.0f, DECAYSUM);

  /* ---- traj_emb ---- */
  k_gemv1<<<dim3(1), B256, 0, stream>>>(TRAJSUM, 576, opW, 384, opb, TEMB, 384, 0);

  /* ---- ai_ctx ---- */
  run_mha(ai_h, 2048, user_h, 2048, 0, AICTX);
  hipMemsetAsync(AIPOOL, 0, 384*4, stream);
  k_colsum<<<dim3(2,8), B256, 0, stream>>>(AICTX, 2048, 384, 1.0f/2048.0f, AIPOOL);

  /* ---- pscores ---- */
  k_comb<<<dim3(6144), B256, 0, stream>>>(ai_h, user_h, CB);
  gemm(CB, 768, as1W, 384, as1b, nullptr, nullptr, 1.f, PT, 384, 2048, 384, 768, 1, 0);
  k_rowdot<<<dim3(512), B256, 0, stream>>>(PT, 384, 384, as2W, as2b, out + 2 + 2048, 2048);

  /* ---- bctx ---- */
  run_mha(ai_h, 2048, belief_h, 1024, 2, TRAJ);
  hipMemsetAsync(BCTXV, 0, 384*4, stream);
  k_colsum<<<dim3(2,8), B256, 0, stream>>>(TRAJ, 2048, 384, 1.0f/2048.0f, BCTXV);

  /* ---- stance delta ---- */
  hipMemcpyAsync(SDIN, stance_h, 384*4, hipMemcpyDeviceToDevice, stream);
  hipMemcpyAsync(SDIN + 384, stance_h + (size_t)2047*384, 384*4, hipMemcpyDeviceToDevice, stream);
  k_gemv1<<<dim3(1), B256, 0, stream>>>(SDIN, 768, sc1W, 384, sc1b, T1, 384, 1);
  k_gemv1<<<dim3(1), B256, 0, stream>>>(T1, 384, sc2W, 192, sc2b, SDELT, 192, 0);

  /* ---- classifier ---- */
  k_gemv1<<<dim3(1), B256, 0, stream>>>(TEMB, 1344, cl1W, 384, cl1b, Z1, 384, 0);
  k_lnrow<<<dim3(1), dim3(128), 0, stream>>>(Z1, Zb, cllng, cllnb, 1 /*relu*/);
  k_gemv1<<<dim3(1), B256, 0, stream>>>(Zb, 384, cl2W, 192, cl2b, Z2, 192, 1);
  k_final<<<dim3(1), dim3(64), 0, stream>>>(Z2, cl3W, cl3b, out);

  /* ---- per_turn ---- */
  k_rowdot<<<dim3(512), B256, 0, stream>>>(AICTX, 384, 384, tpW, tpb, out + 2, 2048);
}

// Round 6
// 6251.344 us; speedup vs baseline: 4.1288x; 1.1065x over previous
//
#include <hip/hip_runtime.h>
#include <hip/hip_bf16.h>

#define NEDGE 229376
#define NTOT  8192
#define BNCONST 0.9999950000374997f   /* 1/sqrt(1+1e-5) */
#define ISQ96   0.10206207261596575f  /* 1/sqrt(96) */

__constant__ int c_NT[5]     = {2048,2048,2048,1024,1024};
__constant__ int c_OFFS[5]   = {0,2048,4096,6144,7168};
__constant__ int c_ESRC[8]   = {0,1,1,2,0,3,1,4};
__constant__ int c_EDST[8]   = {1,0,2,2,3,1,4,2};
__constant__ int c_EOFF[9]   = {0,32768,65536,98304,131072,147456,180224,196608,229376};
__constant__ int c_RELROW[8] = {0,2048,4096,6144,8192,10240,11264,13312};

static const int h_NT[5]   = {2048,2048,2048,1024,1024};
static const int h_OFFS[5] = {0,2048,4096,6144,7168};

__device__ inline float gelu_f(float x){ return 0.5f*x*(1.0f+erff(x*0.70710678118654752f)); }
__device__ inline float sigm(float x){ return 1.0f/(1.0f+expf(-x)); }
__device__ inline float wsum64(float v){
  #pragma unroll
  for (int s=32;s>0;s>>=1) v += __shfl_xor(v, s, 64);
  return v;
}
__device__ inline float wmax64(float v){
  #pragma unroll
  for (int s=32;s>0;s>>=1) v = fmaxf(v, __shfl_xor(v, s, 64));
  return v;
}
__device__ inline unsigned encf(float f){
  unsigned b = __float_as_uint(f);
  return (b & 0x80000000u) ? ~b : (b | 0x80000000u);
}
__device__ inline float decf(unsigned u){
  unsigned b = (u & 0x80000000u) ? (u & 0x7FFFFFFFu) : ~u;
  return __uint_as_float(b);
}
__device__ inline int row_type(int row){
  return (row<2048)?0:((row<4096)?1:((row<6144)?2:((row<7168)?3:4)));
}

/* ---------------- simple utility kernels ---------------- */

__global__ void k_mix(const float* __restrict__ a, const float* __restrict__ b,
                      float* __restrict__ c, int n, float fa, float fb){
  int i = blockIdx.x*256 + threadIdx.x;
  if (i < n) c[i] = fa*a[i] + fb*b[i];
}

__global__ void k_comb(const float* __restrict__ ai, const float* __restrict__ user,
                       float* __restrict__ cb){
  int i = blockIdx.x*256 + threadIdx.x;
  if (i >= 2048*768) return;
  int n = i / 768, c = i - n*768;
  cb[i] = (c < 384) ? ai[n*384 + c] : user[n*384 + (c-384)];
}

/* ---------------- edge preprocessing (CSR by destination) ---------------- */

__global__ void k_edge_pre(const int* __restrict__ esrc, const int* __restrict__ edst,
                           int* edg, int* esr, int* erl, int* cnt){
  int e = blockIdx.x*256 + threadIdx.x;
  if (e >= NEDGE) return;
  int r = 0;
  #pragma unroll
  for (int q=1;q<8;q++) if (e >= c_EOFF[q]) r = q;
  int dg = c_OFFS[c_EDST[r]] + edst[e];
  edg[e] = dg;
  esr[e] = c_RELROW[r] + esrc[e];
  erl[e] = r;
  atomicAdd(&cnt[dg], 1);
}

__global__ __launch_bounds__(1024) void k_scan(const int* __restrict__ cnt, int* __restrict__ off){
  __shared__ int sh[1024];
  int tid = threadIdx.x;
  int base = tid*8;
  int loc[8]; int run = 0;
  #pragma unroll
  for (int i=0;i<8;i++){ loc[i] = run; run += cnt[base+i]; }
  sh[tid] = run;
  __syncthreads();
  for (int d=1; d<1024; d<<=1){
    int v = (tid >= d) ? sh[tid-d] : 0;
    __syncthreads();
    sh[tid] += v;
    __syncthreads();
  }
  int pre = (tid==0) ? 0 : sh[tid-1];
  #pragma unroll
  for (int i=0;i<8;i++) off[base+i] = pre + loc[i];
  if (tid==1023) off[8192] = sh[1023];
}

__global__ void k_scatter(const int* __restrict__ edg, const int* __restrict__ off,
                          int* cnt2, int* csr){
  int e = blockIdx.x*256 + threadIdx.x;
  if (e >= NEDGE) return;
  int dg = edg[e];
  int pos = off[dg] + atomicAdd(&cnt2[dg], 1);
  csr[pos] = e;
}

/* ------- tiled GEMMs: 64x64 tile, contiguous 4x4 microtile, b128 LDS reads ------- */

__global__ __launch_bounds__(256) void gemm_f(
    const float* __restrict__ A, int lda, const float* __restrict__ B, int ldb,
    const float* __restrict__ bias, const float* __restrict__ cs, const float* __restrict__ csh,
    float kmul, float* __restrict__ C, int ldc, int M, int N, int K, int act, int agelu)
{
  __shared__ float As[16][68];
  __shared__ float Bs[16][68];
  int tid = threadIdx.x;
  int tx = tid & 15, ty = tid >> 4;
  int m0 = blockIdx.y * 64, n0 = blockIdx.x * 64;
  float acc[4][4] = {};
  for (int kk = 0; kk < K; kk += 16) {
    #pragma unroll
    for (int i = 0; i < 4; i++) {
      int e = tid + i*256;
      int m = e >> 4, k = e & 15;
      int gm = m0 + m;
      float v = 0.f;
      if (gm < M && kk + k < K) v = A[(size_t)gm*lda + kk + k];
      if (agelu) v = gelu_f(v);
      As[k][m] = v;
    }
    #pragma unroll
    for (int i = 0; i < 4; i++) {
      int e = tid + i*256;
      int k = e >> 6, n = e & 63;
      int gn = n0 + n;
      Bs[k][n] = (gn < N && kk + k < K) ? B[(size_t)(kk + k)*ldb + gn] : 0.f;
    }
    __syncthreads();
    #pragma unroll
    for (int k = 0; k < 16; k++) {
      float4 a4 = *reinterpret_cast<const float4*>(&As[k][ty*4]);
      float4 b4 = *reinterpret_cast<const float4*>(&Bs[k][tx*4]);
      float a[4] = {a4.x, a4.y, a4.z, a4.w};
      float b[4] = {b4.x, b4.y, b4.z, b4.w};
      #pragma unroll
      for (int i=0;i<4;i++)
        #pragma unroll
        for (int j=0;j<4;j++) acc[i][j] += a[i]*b[j];
    }
    __syncthreads();
  }
  #pragma unroll
  for (int i=0;i<4;i++){
    int gm = m0 + ty*4 + i; if (gm >= M) continue;
    #pragma unroll
    for (int j=0;j<4;j++){
      int gn = n0 + tx*4 + j; if (gn >= N) continue;
      float v = acc[i][j];
      if (bias) v += bias[gn];
      float s = kmul;
      if (cs) s *= cs[gn];
      v *= s;
      if (csh) v += csh[gn];
      if (act==1) v = fmaxf(v, 0.f);
      C[(size_t)gm*ldc + gn] = v;
    }
  }
}

// C[m,n] = scale * sum_k A[m,k]*B[n,k]   (Q @ K^T)
__global__ __launch_bounds__(256) void gemm_abt_f(
    const float* __restrict__ A, int lda, const float* __restrict__ B, int ldb,
    float* __restrict__ C, int ldc, int M, int N, int K, float scale)
{
  __shared__ float As[16][68];
  __shared__ float Bs[16][68];
  int tid = threadIdx.x;
  int tx = tid & 15, ty = tid >> 4;
  int m0 = blockIdx.y * 64, n0 = blockIdx.x * 64;
  float acc[4][4] = {};
  for (int kk = 0; kk < K; kk += 16) {
    #pragma unroll
    for (int i = 0; i < 4; i++) {
      int e = tid + i*256;
      int m = e >> 4, k = e & 15;
      int gm = m0 + m;
      As[k][m] = (gm < M && kk + k < K) ? A[(size_t)gm*lda + kk + k] : 0.f;
    }
    #pragma unroll
    for (int i = 0; i < 4; i++) {
      int e = tid + i*256;
      int n = e >> 4, k = e & 15;
      int gn = n0 + n;
      Bs[k][n] = (gn < N && kk + k < K) ? B[(size_t)gn*ldb + kk + k] : 0.f;
    }
    __syncthreads();
    #pragma unroll
    for (int k = 0; k < 16; k++) {
      float4 a4 = *reinterpret_cast<const float4*>(&As[k][ty*4]);
      float4 b4 = *reinterpret_cast<const float4*>(&Bs[k][tx*4]);
      float a[4] = {a4.x, a4.y, a4.z, a4.w};
      float b[4] = {b4.x, b4.y, b4.z, b4.w};
      #pragma unroll
      for (int i=0;i<4;i++)
        #pragma unroll
        for (int j=0;j<4;j++) acc[i][j] += a[i]*b[j];
    }
    __syncthreads();
  }
  #pragma unroll
  for (int i=0;i<4;i++){
    int gm = m0 + ty*4 + i; if (gm >= M) continue;
    #pragma unroll
    for (int j=0;j<4;j++){
      int gn = n0 + tx*4 + j; if (gn >= N) continue;
      C[(size_t)gm*ldc + gn] = acc[i][j]*scale;
    }
  }
}

// C[m,n] += sum_l A[l,m]*B[l,n], head-batched + L-split (atomic accumulate).
__global__ __launch_bounds__(256) void gemm_atb_ks(
    const float* __restrict__ A0, int lda, const float* __restrict__ B0, int ldb,
    float* __restrict__ C0, int ldc, int M, int N, int L,
    int hsA, int hsB, int hsC, int nch)
{
  __shared__ float As[16][68];
  __shared__ float Bs[16][68];
  int h = blockIdx.z / nch, c = blockIdx.z % nch;
  const float* A = A0 + (size_t)h*hsA;
  const float* B = B0 + (size_t)h*hsB;
  float* C = C0 + (size_t)h*hsC;
  int l0 = c*256, l1 = min(L, l0+256);
  int tid = threadIdx.x;
  int tx = tid & 15, ty = tid >> 4;
  int m0 = blockIdx.y * 64, n0 = blockIdx.x * 64;
  float acc[4][4] = {};
  for (int ll = l0; ll < l1; ll += 16) {
    #pragma unroll
    for (int i = 0; i < 4; i++) {
      int e = tid + i*256;
      int l = e >> 6, m = e & 63;
      int gm = m0 + m;
      As[l][m] = (gm < M && ll + l < l1) ? A[(size_t)(ll + l)*lda + gm] : 0.f;
    }
    #pragma unroll
    for (int i = 0; i < 4; i++) {
      int e = tid + i*256;
      int l = e >> 6, n = e & 63;
      int gn = n0 + n;
      Bs[l][n] = (gn < N && ll + l < l1) ? B[(size_t)(ll + l)*ldb + gn] : 0.f;
    }
    __syncthreads();
    #pragma unroll
    for (int l = 0; l < 16; l++) {
      float4 a4 = *reinterpret_cast<const float4*>(&As[l][ty*4]);
      float4 b4 = *reinterpret_cast<const float4*>(&Bs[l][tx*4]);
      float a[4] = {a4.x, a4.y, a4.z, a4.w};
      float b[4] = {b4.x, b4.y, b4.z, b4.w};
      #pragma unroll
      for (int i=0;i<4;i++)
        #pragma unroll
        for (int j=0;j<4;j++) acc[i][j] += a[i]*b[j];
    }
    __syncthreads();
  }
  #pragma unroll
  for (int i=0;i<4;i++){
    int gm = m0 + ty*4 + i; if (gm >= M) continue;
    #pragma unroll
    for (int j=0;j<4;j++){
      int gn = n0 + tx*4 + j; if (gn >= N) continue;
      atomicAdd(&C[(size_t)gm*ldc + gn], acc[i][j]);
    }
  }
}

// C += (A@B)*scale over K-chunk (grid.z = chunk of 256); atomic accumulate.
__global__ __launch_bounds__(256) void gemm_nn_ks(
    const float* __restrict__ A, int lda, const float* __restrict__ B, int ldb,
    float* __restrict__ C, int ldc, int M, int N, int K, float scale)
{
  __shared__ float As[16][68];
  __shared__ float Bs[16][68];
  int k0 = blockIdx.z*256, k1 = min(K, k0+256);
  int tid = threadIdx.x;
  int tx = tid & 15, ty = tid >> 4;
  int m0 = blockIdx.y * 64, n0 = blockIdx.x * 64;
  float acc[4][4] = {};
  for (int kk = k0; kk < k1; kk += 16) {
    #pragma unroll
    for (int i = 0; i < 4; i++) {
      int e = tid + i*256;
      int m = e >> 4, k = e & 15;
      int gm = m0 + m;
      As[k][m] = (gm < M && kk + k < k1) ? A[(size_t)gm*lda + kk + k] : 0.f;
    }
    #pragma unroll
    for (int i = 0; i < 4; i++) {
      int e = tid + i*256;
      int k = e >> 6, n = e & 63;
      int gn = n0 + n;
      Bs[k][n] = (gn < N && kk + k < k1) ? B[(size_t)(kk + k)*ldb + gn] : 0.f;
    }
    __syncthreads();
    #pragma unroll
    for (int k = 0; k < 16; k++) {
      float4 a4 = *reinterpret_cast<const float4*>(&As[k][ty*4]);
      float4 b4 = *reinterpret_cast<const float4*>(&Bs[k][tx*4]);
      float a[4] = {a4.x, a4.y, a4.z, a4.w};
      float b[4] = {b4.x, b4.y, b4.z, b4.w};
      #pragma unroll
      for (int i=0;i<4;i++)
        #pragma unroll
        for (int j=0;j<4;j++) acc[i][j] += a[i]*b[j];
    }
    __syncthreads();
  }
  #pragma unroll
  for (int i=0;i<4;i++){
    int gm = m0 + ty*4 + i; if (gm >= M) continue;
    #pragma unroll
    for (int j=0;j<4;j++){
      int gn = n0 + tx*4 + j; if (gn >= N) continue;
      atomicAdd(&C[(size_t)gm*ldc + gn], acc[i][j]*scale);
    }
  }
}

/* ---------------- HGT relation projection ---------------- */
__global__ __launch_bounds__(192) void k_relproj(
    const float* __restrict__ KQV_, const float* __restrict__ krel_l,
    const float* __restrict__ vrel_l, float* __restrict__ KE_, float* __restrict__ VE_)
{
  int r = blockIdx.z >> 1, w = blockIdx.z & 1, h = blockIdx.y;
  int s = c_ESRC[r];
  int Ns = c_NT[s];
  int row0 = blockIdx.x * 16;
  if (row0 >= Ns) return;
  __shared__ float Wl[96*96];
  __shared__ float Ar[2][96];
  const float* Wp = (w ? vrel_l : krel_l) + (size_t)(r*4 + h)*9216;
  int tid = threadIdx.y*96 + threadIdx.x;
  for (int idx = tid; idx < 9216; idx += 192) Wl[idx] = Wp[idx];
  __syncthreads();
  int colbase = (w ? 768 : 0) + h*96;
  float* OUT = (w ? VE_ : KE_);
  for (int it = 0; it < 8; it++){
    int rr = row0 + it*2 + threadIdx.y;
    const float* a = KQV_ + (size_t)(c_OFFS[s] + rr)*1152 + colbase;
    Ar[threadIdx.y][threadIdx.x] = a[threadIdx.x];
    __syncthreads();
    float acc = 0.f;
    #pragma unroll 8
    for (int d = 0; d < 96; d++) acc += Ar[threadIdx.y][d] * Wl[d*96 + threadIdx.x];
    OUT[(size_t)(c_RELROW[r] + rr)*384 + h*96 + threadIdx.x] = acc;
    __syncthreads();
  }
}

/* ---------------- edge attention ---------------- */

__global__ __launch_bounds__(256) void k_escore(
    const float* __restrict__ KQV_, const float* __restrict__ KE_,
    const int* __restrict__ edg, const int* __restrict__ esr, const int* __restrict__ erl,
    const float* __restrict__ prel_l, float* __restrict__ EA)
{
  int e = blockIdx.x*4 + (threadIdx.x>>6);
  if (e >= NEDGE) return;
  int lane = threadIdx.x & 63;
  int h = lane >> 4, j = lane & 15;
  int dg = edg[e], sr = esr[e], r = erl[e];
  const float* q  = KQV_ + (size_t)dg*1152 + 384 + h*96;
  const float* ke = KE_  + (size_t)sr*384 + h*96;
  float p = 0.f;
  #pragma unroll
  for (int t=0;t<6;t++){ int d = j + t*16; p += q[d]*ke[d]; }
  p += __shfl_xor(p, 1, 64);
  p += __shfl_xor(p, 2, 64);
  p += __shfl_xor(p, 4, 64);
  p += __shfl_xor(p, 8, 64);
  if (j == 0) EA[(size_t)e*4 + h] = p * prel_l[r*4+h] * ISQ96;
}

__global__ void k_segmax(const float* __restrict__ EA, const int* __restrict__ edg,
                         unsigned* __restrict__ EMX){
  int i = blockIdx.x*256 + threadIdx.x;
  if (i >= NEDGE*4) return;
  int e = i >> 2, h = i & 3;
  atomicMax(&EMX[edg[e]*4 + h], encf(EA[i]));
}

__global__ void k_expsum(float* __restrict__ EA, const int* __restrict__ edg,
                         const unsigned* __restrict__ EMX, float* __restrict__ EDEN){
  int i = blockIdx.x*256 + threadIdx.x;
  if (i >= NEDGE*4) return;
  int e = i >> 2, h = i & 3;
  int dg = edg[e];
  float m = decf(EMX[dg*4 + h]);
  float ex = expf(EA[i] - m);
  EA[i] = ex;
  atomicAdd(&EDEN[dg*4 + h], ex);
}

__global__ __launch_bounds__(128) void k_agg(
    const float* __restrict__ EA, const float* __restrict__ VE_,
    const float* __restrict__ EDEN, const int* __restrict__ csr,
    const int* __restrict__ off, const int* __restrict__ esr, float* __restrict__ AGG)
{
  int node = blockIdx.x, tid = threadIdx.x;
  int b = off[node], e1 = off[node+1];
  int d0 = tid, d1 = tid+128, d2 = tid+256;
  int h0 = d0/96, h1 = d1/96, h2 = d2/96;
  float a0=0.f, a1=0.f, a2=0.f;
  if (e1 > b){
    float i0 = 1.0f/EDEN[node*4+h0];
    float i1 = 1.0f/EDEN[node*4+h1];
    float i2 = 1.0f/EDEN[node*4+h2];
    for (int p=b; p<e1; p++){
      int e = csr[p];
      const float* ve = VE_ + (size_t)esr[e]*384;
      const float* ea = EA + (size_t)e*4;
      a0 += ea[h0]*i0*ve[d0];
      a1 += ea[h1]*i1*ve[d1];
      a2 += ea[h2]*i2*ve[d2];
    }
  }
  AGG[(size_t)node*384 + d0] = a0;
  AGG[(size_t)node*384 + d1] = a1;
  AGG[(size_t)node*384 + d2] = a2;
}

/* ---------------- row-wise norm kernels ---------------- */

__global__ __launch_bounds__(128) void k_gateln(
    const float* __restrict__ O, float* __restrict__ X,
    const float* __restrict__ skip_l, const float* __restrict__ lng, const float* __restrict__ lnb)
{
  __shared__ float red[2];
  int row = blockIdx.x, tid = threadIdx.x;
  int t = row_type(row);
  float gt = sigm(skip_l[t]);
  const float* o = O + (size_t)row*384;
  float* x = X + (size_t)row*384;
  float v0 = gelu_f(gt*o[tid]     + (1.f-gt)*x[tid]);
  float v1 = gelu_f(gt*o[tid+128] + (1.f-gt)*x[tid+128]);
  float v2 = gelu_f(gt*o[tid+256] + (1.f-gt)*x[tid+256]);
  int lane = tid & 63, wid = tid >> 6;
  float s = wsum64(v0+v1+v2);
  if (lane==0) red[wid] = s;
  __syncthreads();
  float mean = (red[0]+red[1]) * (1.0f/384.0f);
  __syncthreads();
  float d0=v0-mean, d1=v1-mean, d2=v2-mean;
  float q = wsum64(d0*d0+d1*d1+d2*d2);
  if (lane==0) red[wid] = q;
  __syncthreads();
  float var = (red[0]+red[1]) * (1.0f/384.0f);
  float rs = 1.0f/sqrtf(var + 1e-5f);
  const float* g = lng + (size_t)t*384;
  const float* b = lnb + (size_t)t*384;
  x[tid]     = d0*rs*g[tid]     + b[tid];
  x[tid+128] = d1*rs*g[tid+128] + b[tid+128];
  x[tid+256] = d2*rs*g[tid+256] + b[tid+256];
}

__global__ __launch_bounds__(128) void k_lnrow(
    const float* __restrict__ X, float* __restrict__ Y,
    const float* __restrict__ g, const float* __restrict__ b, int act)
{
  __shared__ float red[2];
  int row = blockIdx.x, tid = threadIdx.x;
  const float* x = X + (size_t)row*384;
  float* y = Y + (size_t)row*384;
  float v0 = x[tid], v1 = x[tid+128], v2 = x[tid+256];
  int lane = tid & 63, wid = tid >> 6;
  float s = wsum64(v0+v1+v2);
  if (lane==0) red[wid] = s;
  __syncthreads();
  float mean = (red[0]+red[1]) * (1.0f/384.0f);
  __syncthreads();
  float d0=v0-mean, d1=v1-mean, d2=v2-mean;
  float q = wsum64(d0*d0+d1*d1+d2*d2);
  if (lane==0) red[wid] = q;
  __syncthreads();
  float var = (red[0]+red[1]) * (1.0f/384.0f);
  float rs = 1.0f/sqrtf(var + 1e-5f);
  float u0 = d0*rs*g[tid]     + b[tid];
  float u1 = d1*rs*g[tid+128] + b[tid+128];
  float u2 = d2*rs*g[tid+256] + b[tid+256];
  if (act==1){ u0=fmaxf(u0,0.f); u1=fmaxf(u1,0.f); u2=fmaxf(u2,0.f); }
  else       { u0=gelu_f(u0); u1=gelu_f(u1); u2=gelu_f(u2); }
  y[tid] = u0; y[tid+128] = u1; y[tid+256] = u2;
}

/* ---------------- softmax / reductions / misc ---------------- */

__global__ __launch_bounds__(256) void k_softmax(float* __restrict__ S, int L){
  __shared__ float red[4];
  int row = blockIdx.x, tid = threadIdx.x;
  float* p = S + (size_t)row*L;
  float m = -3.0e38f;
  for (int c=tid;c<L;c+=256) m = fmaxf(m, p[c]);
  m = wmax64(m);
  int lane = tid & 63, wid = tid >> 6;
  if (lane==0) red[wid] = m;
  __syncthreads();
  m = fmaxf(fmaxf(red[0],red[1]), fmaxf(red[2],red[3]));
  __syncthreads();
  float s = 0.f;
  for (int c=tid;c<L;c+=256){ float e = expf(p[c]-m); p[c]=e; s += e; }
  s = wsum64(s);
  if (lane==0) red[wid] = s;
  __syncthreads();
  float inv = 1.0f/(red[0]+red[1]+red[2]+red[3]);
  for (int c=tid;c<L;c+=256) p[c] *= inv;
}

__global__ __launch_bounds__(256) void k_sumsq(const float* __restrict__ x, int n, float* out){
  __shared__ float red[4];
  float s = 0.f;
  for (int i = blockIdx.x*256 + threadIdx.x; i < n; i += gridDim.x*256){ float v=x[i]; s += v*v; }
  s = wsum64(s);
  int lane = threadIdx.x & 63, wid = threadIdx.x >> 6;
  if (lane==0) red[wid] = s;
  __syncthreads();
  if (threadIdx.x==0) atomicAdd(out, red[0]+red[1]+red[2]+red[3]);
}

__global__ void k_colsum(const float* __restrict__ A, int R, int C, float scale,
                         float* __restrict__ out){
  int col = blockIdx.x*256 + threadIdx.x;
  if (col >= C) return;
  int nchunk = gridDim.y;
  int chunk = (R + nchunk - 1)/nchunk;
  int r0 = blockIdx.y*chunk, r1 = min(R, r0+chunk);
  float s = 0.f;
  for (int r=r0; r<r1; r++) s += A[(size_t)r*C + col];
  atomicAdd(&out[col], s*scale);
}

__global__ __launch_bounds__(256) void k_dnm(const float* __restrict__ QB,
    const float* __restrict__ KSUM, const float* __restrict__ sqsk, float* __restrict__ DNM){
  int wv = blockIdx.x*4 + (threadIdx.x>>6);
  int n = wv >> 2, h = wv & 3;
  int lane = threadIdx.x & 63;
  const float* q = QB + (size_t)n*1536 + h*384;
  const float* ks = KSUM + h*384;
  float p = 0.f;
  #pragma unroll
  for (int d=lane; d<384; d+=64) p += q[d]*ks[d];
  p = wsum64(p);
  if (lane==0) DNM[n*4+h] = p * (1.0f/sqrtf(sqsk[0]*sqsk[1])) + 2048.0f;
}

__global__ void k_zcomb(const float* __restrict__ ZN, const float* __restrict__ VB_,
                        const float* __restrict__ DNM_, const float* __restrict__ sqsk,
                        float* __restrict__ XG_,
                        const float* __restrict__ bng, const float* __restrict__ bnb){
  int i = blockIdx.x*256 + threadIdx.x;
  if (i >= 2048*384) return;
  int n = i / 384, c = i - n*384;
  float inv_s = 1.0f/sqrtf(sqsk[0]*sqsk[1]);
  float zm = 0.f;
  #pragma unroll
  for (int h=0;h<4;h++){
    float num = ZN[(size_t)n*1536 + h*384 + c]*inv_s + 2048.0f*VB_[(size_t)n*1536 + h*384 + c];
    zm += num / DNM_[n*4+h];
  }
  zm *= 0.25f;
  float y = 0.5f*zm + 0.5f*XG_[i];
  y = y * (bng[c] * BNCONST) + bnb[c];
  XG_[i] = fmaxf(y, 0.f);
}

/* ---------------- conv1d (kernel 3, pad 1) ---------------- */
__global__ __launch_bounds__(256) void k_conv3(
    const float* __restrict__ in, const float* __restrict__ W, const float* __restrict__ bias,
    float* __restrict__ out, int IC, int OC)
{
  __shared__ float xs[34][384];
  int tid = threadIdx.x;
  int p0 = blockIdx.x*32, oc0 = blockIdx.y*64;
  for (int idx = tid; idx < 34*IC; idx += 256){
    int rr = idx / IC, c = idx - rr*IC;
    int gp = p0 - 1 + rr;
    xs[rr][c] = (gp >= 0 && gp < 2048) ? in[(size_t)gp*IC + c] : 0.f;
  }
  __syncthreads();
  int oc = oc0 + (tid & 63);
  int py = tid >> 6;
  float acc[8] = {0,0,0,0,0,0,0,0};
  const float* Wp = W + (size_t)oc*IC*3;
  for (int c=0;c<IC;c++){
    float w0 = Wp[c*3+0], w1 = Wp[c*3+1], w2 = Wp[c*3+2];
    #pragma unroll
    for (int u=0;u<8;u++){
      int pl = py + u*4;
      acc[u] += w0*xs[pl][c] + w1*xs[pl+1][c] + w2*xs[pl+2][c];
    }
  }
  float b = bias[oc];
  #pragma unroll
  for (int u=0;u<8;u++){
    int pl = py + u*4;
    out[(size_t)(p0+pl)*OC + oc] = gelu_f(acc[u] + b);
  }
}

/* ---------------- parallel small GEMV: partials + finalize ---------------- */

// tmp[kch*N + c] = sum over this k-chunk of in[k]*W[k*ldw+c]
// grid (ceil(N/64), nk), block 256 (4 waves sub-split each chunk)
__global__ __launch_bounds__(256) void k_gemv_ks(
    const float* __restrict__ in, int K, const float* __restrict__ W, int ldw,
    float* __restrict__ tmp, int N)
{
  int c = blockIdx.x*64 + (threadIdx.x & 63);
  int w = threadIdx.x >> 6;
  int kch = blockIdx.y, nk = gridDim.y;
  int k0 = (int)(((long long)K * kch) / nk);
  int k1 = (int)(((long long)K * (kch+1)) / nk);
  float s = 0.f;
  if (c < N){
    for (int k = k0 + w; k < k1; k += 4)
      s += in[k] * W[(size_t)k*ldw + c];
  }
  __shared__ float red[4][64];
  red[w][threadIdx.x & 63] = s;
  __syncthreads();
  if (w == 0 && c < N){
    int l = threadIdx.x & 63;
    tmp[(size_t)kch*N + c] = red[0][l] + red[1][l] + red[2][l] + red[3][l];
  }
}

__global__ void k_gemv_fin(const float* __restrict__ tmp, int nk,
                           const float* __restrict__ b, float* __restrict__ out, int N, int act){
  int c = blockIdx.x*256 + threadIdx.x;
  if (c >= N) return;
  float v = 0.f;
  for (int i = 0; i < nk; i++) v += tmp[(size_t)i*N + c];
  v += b[c];
  if (act==1) v = fmaxf(v, 0.f);
  out[c] = v;
}

__global__ __launch_bounds__(256) void k_rowdot(const float* __restrict__ A, int lda, int K,
    const float* __restrict__ w, const float* __restrict__ b, float* __restrict__ out, int M){
  int r = blockIdx.x*4 + (threadIdx.x>>6);
  if (r >= M) return;
  int lane = threadIdx.x & 63;
  const float* a = A + (size_t)r*lda;
  float p = 0.f;
  for (int k = lane; k < K; k += 64) p += a[k]*w[k];
  p = wsum64(p);
  if (lane==0) out[r] = sigm(p + b[0]);
}

__global__ __launch_bounds__(64) void k_final(const float* __restrict__ z2,
    const float* __restrict__ w, const float* __restrict__ b, float* __restrict__ out){
  int lane = threadIdx.x;
  float p = 0.f;
  for (int k = lane; k < 192; k += 64) p += z2[k]*w[k];
  p = wsum64(p);
  if (lane==0){
    float l = p + b[0];
    out[0] = l;
    out[1] = sigm(l);
  }
}

/* ================================================================ */

extern "C" void kernel_launch(void* const* d_in, const int* in_sizes, int n_in,
                              void* d_out, int out_size, void* d_ws, size_t ws_size,
                              hipStream_t stream)
{
  const float* xin[5] = {(const float*)d_in[0], (const float*)d_in[1], (const float*)d_in[2],
                         (const float*)d_in[3], (const float*)d_in[4]};
  const float* Wkqv=(const float*)d_in[5];  const float* bkqv=(const float*)d_in[6];
  const float* Wout=(const float*)d_in[7];  const float* bout=(const float*)d_in[8];
  const float* krel=(const float*)d_in[9];  const float* vrel=(const float*)d_in[10];
  const float* prel=(const float*)d_in[11]; const float* skp =(const float*)d_in[12];
  const float* lng =(const float*)d_in[13]; const float* lnb =(const float*)d_in[14];
  const float* sp_W=(const float*)d_in[15]; const float* sp_b=(const float*)d_in[16];
  const float* sp_lng=(const float*)d_in[17]; const float* sp_lnb=(const float*)d_in[18];
  const float* fc0_W=(const float*)d_in[19]; const float* fc0_b=(const float*)d_in[20];
  const float* bn_g=(const float*)d_in[21]; const float* bn_b=(const float*)d_in[22];
  const float* tq_W=(const float*)d_in[23]; const float* tq_b=(const float*)d_in[24];
  const float* tk_W=(const float*)d_in[25]; const float* tk_b=(const float*)d_in[26];
  const float* tv_W=(const float*)d_in[27]; const float* tv_b=(const float*)d_in[28];
  const float* mWqkv=(const float*)d_in[29]; const float* mbqkv=(const float*)d_in[30];
  const float* mWo=(const float*)d_in[31];  const float* mbo=(const float*)d_in[32];
  const float* c1W=(const float*)d_in[33];  const float* c1b=(const float*)d_in[34];
  const float* c2W=(const float*)d_in[35];  const float* c2b=(const float*)d_in[36];
  const float* opW=(const float*)d_in[37];  const float* opb=(const float*)d_in[38];
  const float* as1W=(const float*)d_in[39]; const float* as1b=(const float*)d_in[40];
  const float* as2W=(const float*)d_in[41]; const float* as2b=(const float*)d_in[42];
  const float* sc1W=(const float*)d_in[43]; const float* sc1b=(const float*)d_in[44];
  const float* sc2W=(const float*)d_in[45]; const float* sc2b=(const float*)d_in[46];
  const float* cl1W=(const float*)d_in[47]; const float* cl1b=(const float*)d_in[48];
  const float* cllng=(const float*)d_in[49]; const float* cllnb=(const float*)d_in[50];
  const float* cl2W=(const float*)d_in[51]; const float* cl2b=(const float*)d_in[52];
  const float* cl3W=(const float*)d_in[53]; const float* cl3b=(const float*)d_in[54];
  const float* tpW=(const float*)d_in[55];  const float* tpb=(const float*)d_in[56];
  const int* e_src=(const int*)d_in[57];  const int* e_dst=(const int*)d_in[58];
  float* out = (float*)d_out;

  /* workspace arena */
  char* ws = (char*)d_ws;
  size_t off_b = 0;
  auto alloc = [&](size_t bytes)->char*{
    char* r = ws + off_b;
    off_b = (off_b + bytes + 255) & ~(size_t)255;
    return r;
  };
  float* X    = (float*)alloc((size_t)8192*384*4);
  float* KQV  = (float*)alloc((size_t)8192*1152*4);
  float* KE   = (float*)alloc((size_t)14336*384*4);
  float* VE   = (float*)alloc((size_t)14336*384*4);
  float* AGG  = (float*)alloc((size_t)8192*384*4);
  float* EA   = (float*)alloc((size_t)NEDGE*4*4);
  int* edg    = (int*)alloc((size_t)NEDGE*4);
  int* esr    = (int*)alloc((size_t)NEDGE*4);
  int* erl    = (int*)alloc((size_t)NEDGE*4);
  int* csr    = (int*)alloc((size_t)NEDGE*4);
  int* cnt    = (int*)alloc(8192*4);
  int* cnt2   = (int*)alloc(8192*4);
  int* coff   = (int*)alloc(8193*4);
  unsigned* EMX = (unsigned*)alloc(8192*4*4);
  float* EDEN = (float*)alloc(8192*4*4);
  float* SM   = (float*)alloc(65536);
  float* GT   = (float*)alloc(20*384*4);   /* gemv partials (nk<=20, N<=384) */
  if (off_b > ws_size) return;

  float* SQSK = SM;
  float* TRAJSUM = SM + 8;
  float* DECAYSUM = SM + 392;
  float* TEMB = SM + 600;
  float* AIPOOL = SM + 984;
  float* BCTXV = SM + 1368;
  float* SDELT = SM + 1752;
  float* SDIN = SM + 2048;
  float* T1   = SM + 2816;
  float* Z1   = SM + 3200;
  float* Zb   = SM + 3584;
  float* Z2   = SM + 3968;
  float* KSUM = SM + 4224;
  float* DNM  = SM + 6144;

  float* QB = KQV;
  float* KB = KQV + (size_t)2048*1536;
  float* VB = KQV + (size_t)2*2048*1536;
  float* MQKV = KQV;
  float* AO = KQV + (size_t)2*2048*1536;
  float* SSC = KE;
  float* ZNUM = KE;
  float* OWT = KE;
  float* HS = VE;
  float* XG = VE + (size_t)2048*384;
  float* HM = VE + (size_t)2*2048*384;
  float* C1O = VE + (size_t)3*2048*384;
  float* TRAJ = VE + (size_t)4*2048*384;
  float* AICTX = VE + (size_t)5*2048*384;
  float* C2O = VE + (size_t)6*2048*384;
  float* TMPA = AGG;
  float* CB = AGG;
  float* PT = AGG + (size_t)2048*768;
  float* KVS = AGG + (size_t)2048*1152;

  dim3 B256(256);
  auto gemm = [&](const float* A, int lda, const float* Bw, int ldb, const float* bias,
                  const float* cs, const float* csh, float kmul,
                  float* C, int ldc, int M, int N, int K, int act, int agelu){
    dim3 g((N+63)/64, (M+63)/64);
    gemm_f<<<g, B256, 0, stream>>>(A, lda, Bw, ldb, bias, cs, csh, kmul, C, ldc, M, N, K, act, agelu);
  };
  auto gemm_abt = [&](const float* A, int lda, const float* B, int ldb, float* C, int ldc,
                      int M, int N, int K, float scale){
    dim3 g((N+63)/64, (M+63)/64);
    gemm_abt_f<<<g, B256, 0, stream>>>(A, lda, B, ldb, C, ldc, M, N, K, scale);
  };
  /* parallel small gemv: partial + finalize (deterministic, no atomics) */
  auto gemv = [&](const float* in, int K, const float* W, int ldw, const float* b,
                  float* o, int N, int act){
    int nk = (K + 79) / 80; if (nk > 20) nk = 20; if (nk < 1) nk = 1;
    k_gemv_ks<<<dim3((N+63)/64, nk), B256, 0, stream>>>(in, K, W, ldw, GT, N);
    k_gemv_fin<<<dim3((N+255)/256), B256, 0, stream>>>(GT, nk, b, o, N, act);
  };

  /* ---- edge CSR ---- */
  hipMemsetAsync(cnt, 0, 8192*4, stream);
  hipMemsetAsync(cnt2, 0, 8192*4, stream);
  k_edge_pre<<<dim3(NEDGE/256), B256, 0, stream>>>(e_src, e_dst, edg, esr, erl, cnt);
  k_scan<<<dim3(1), dim3(1024), 0, stream>>>(cnt, coff);
  k_scatter<<<dim3(NEDGE/256), B256, 0, stream>>>(edg, coff, cnt2, csr);

  /* ---- inputs -> X ---- */
  for (int t=0;t<5;t++)
    hipMemcpyAsync(X + (size_t)h_OFFS[t]*384, xin[t], (size_t)h_NT[t]*384*4,
                   hipMemcpyDeviceToDevice, stream);

  /* ---- HGT layers ---- */
  for (int l=0;l<2;l++){
    for (int t=0;t<5;t++)
      gemm(X + (size_t)h_OFFS[t]*384, 384, Wkqv + (size_t)(l*5+t)*442368, 1152,
           bkqv + (size_t)(l*5+t)*1152, nullptr, nullptr, 1.f,
           KQV + (size_t)h_OFFS[t]*1152, 1152, h_NT[t], 1152, 384, 0, 0);
    k_relproj<<<dim3(128,4,16), dim3(96,2), 0, stream>>>(
        KQV, krel + (size_t)l*294912, vrel + (size_t)l*294912, KE, VE);
    k_escore<<<dim3(NEDGE/4), B256, 0, stream>>>(KQV, KE, edg, esr, erl, prel + (size_t)l*32, EA);
    hipMemsetAsync(EMX, 0, 8192*4*4, stream);
    hipMemsetAsync(EDEN, 0, 8192*4*4, stream);
    k_segmax<<<dim3(NEDGE*4/256), B256, 0, stream>>>(EA, edg, EMX);
    k_expsum<<<dim3(NEDGE*4/256), B256, 0, stream>>>(EA, edg, EMX, EDEN);
    k_agg<<<dim3(NTOT), dim3(128), 0, stream>>>(EA, VE, EDEN, csr, coff, esr, AGG);
    for (int t=0;t<5;t++)
      gemm(AGG + (size_t)h_OFFS[t]*384, 384, Wout + (size_t)(l*5+t)*147456, 384,
           bout + (size_t)(l*5+t)*384, nullptr, nullptr, 1.f,
           OWT + (size_t)h_OFFS[t]*384, 384, h_NT[t], 384, 384, 0, 1 /*gelu on A*/);
    k_gateln<<<dim3(NTOT), dim3(128), 0, stream>>>(OWT, X, skp + l*5, lng, lnb);
  }

  const float* user_h   = X;
  const float* ai_h     = X + (size_t)2048*384;
  const float* stance_h = X + (size_t)4096*384;
  const float* belief_h = X + (size_t)7168*384;

  /* ---- hs, xg ---- */
  gemm(stance_h, 384, sp_W, 384, sp_b, nullptr, nullptr, 1.f, TMPA, 384, 2048, 384, 384, 0, 0);
  k_lnrow<<<dim3(2048), dim3(128), 0, stream>>>(TMPA, HS, sp_lng, sp_lnb, 0 /*gelu*/);
  gemm(HS, 384, fc0_W, 384, fc0_b, bn_g, bn_b, BNCONST, XG, 384, 2048, 384, 384, 1 /*relu*/, 0);

  /* ---- linear-attention blocks ---- */
  for (int i=0;i<2;i++){
    gemm(XG, 384, tq_W + (size_t)i*589824, 1536, tq_b + (size_t)i*1536, nullptr, nullptr, 1.f,
         QB, 1536, 2048, 1536, 384, 0, 0);
    gemm(XG, 384, tk_W + (size_t)i*589824, 1536, tk_b + (size_t)i*1536, nullptr, nullptr, 1.f,
         KB, 1536, 2048, 1536, 384, 0, 0);
    gemm(XG, 384, tv_W + (size_t)i*589824, 1536, tv_b + (size_t)i*1536, nullptr, nullptr, 1.f,
         VB, 1536, 2048, 1536, 384, 0, 0);
    hipMemsetAsync(SQSK, 0, 8, stream);
    k_sumsq<<<dim3(512), B256, 0, stream>>>(QB, 2048*1536, SQSK);
    k_sumsq<<<dim3(512), B256, 0, stream>>>(KB, 2048*1536, SQSK+1);
    hipMemsetAsync(KSUM, 0, 1536*4, stream);
    k_colsum<<<dim3(6,8), B256, 0, stream>>>(KB, 2048, 1536, 1.0f, KSUM);
    k_dnm<<<dim3(2048), B256, 0, stream>>>(QB, KSUM, SQSK, DNM);
    hipMemsetAsync(KVS, 0, (size_t)4*147456*4, stream);
    gemm_atb_ks<<<dim3(6,6,32), B256, 0, stream>>>(KB, 1536, VB, 1536, KVS, 384,
        384, 384, 2048, 384, 384, 147456, 8);
    for (int h=0;h<4;h++)
      gemm(QB + h*384, 1536, KVS + (size_t)h*147456, 384, nullptr, nullptr, nullptr, 1.f,
           ZNUM + h*384, 1536, 2048, 384, 384, 0, 0);
    k_zcomb<<<dim3(3072), B256, 0, stream>>>(ZNUM, VB, DNM, SQSK, XG,
        bn_g + (size_t)(i+1)*384, bn_b + (size_t)(i+1)*384);
  }

  /* ---- h_mixed ---- */
  k_mix<<<dim3(3072), B256, 0, stream>>>(HS, XG, HM, 2048*384, 0.7f, 0.3f);

  /* ---- MHA helper ---- */
  auto run_mha = [&](const float* qin, int nq, const float* kvin, int nkv, int mi, float* OUT){
    const float* Wq = mWqkv + (size_t)mi*442368;
    const float* bq = mbqkv + (size_t)mi*1152;
    gemm(qin, 384, Wq, 1152, bq, nullptr, nullptr, 1.f, MQKV, 1152, nq, 384, 384, 0, 0);
    gemm(kvin, 384, Wq + 384, 1152, bq + 384, nullptr, nullptr, 1.f, MQKV + 384, 1152, nkv, 768, 384, 0, 0);
    hipMemsetAsync(AO, 0, (size_t)nq*384*4, stream);
    int nch = (nkv + 255)/256;
    for (int h=0;h<4;h++){
      gemm_abt(MQKV + h*96, 1152, MQKV + 384 + h*96, 1152, SSC, nkv, nq, nkv, 96, ISQ96);
      k_softmax<<<dim3(nq), B256, 0, stream>>>(SSC, nkv);
      gemm_nn_ks<<<dim3(2, (nq+63)/64, nch), B256, 0, stream>>>(
          SSC, nkv, MQKV + 768 + h*96, 1152, AO + h*96, 384, nq, 96, nkv, 1.0f);
    }
    gemm(AO, 384, mWo + (size_t)mi*147456, 384, mbo + (size_t)mi*384,
         nullptr, nullptr, 1.f, OUT, 384, nq, 384, 384, 0, 0);
  };

  /* ---- traj ---- */
  run_mha(HM, 2048, HM, 2048, 1, TRAJ);
  hipMemsetAsync(TRAJSUM, 0, 576*4, stream);
  k_colsum<<<dim3(2,8), B256, 0, stream>>>(TRAJ, 2048, 384, 1.0f/2048.0f, TRAJSUM);

  /* ---- conv path ---- */
  k_conv3<<<dim3(64,6), B256, 0, stream>>>(HM, c1W, c1b, C1O, 384, 384);
  k_conv3<<<dim3(64,3), B256, 0, stream>>>(C1O, c2W, c2b, C2O, 384, 192);
  k_colsum<<<dim3(1,8), B256, 0, stream>>>(C2O, 2048, 192, 1.0f/2048.0f, DECAYSUM);

  /* ---- traj_emb ---- */
  gemv(TRAJSUM, 576, opW, 384, opb, TEMB, 384, 0);

  /* ---- ai_ctx ---- */
  run_mha(ai_h, 2048, user_h, 2048, 0, AICTX);
  hipMemsetAsync(AIPOOL, 0, 384*4, stream);
  k_colsum<<<dim3(2,8), B256, 0, stream>>>(AICTX, 2048, 384, 1.0f/2048.0f, AIPOOL);

  /* ---- pscores ---- */
  k_comb<<<dim3(6144), B256, 0, stream>>>(ai_h, user_h, CB);
  gemm(CB, 768, as1W, 384, as1b, nullptr, nullptr, 1.f, PT, 384, 2048, 384, 768, 1, 0);
  k_rowdot<<<dim3(512), B256, 0, stream>>>(PT, 384, 384, as2W, as2b, out + 2 + 2048, 2048);

  /* ---- bctx ---- */
  run_mha(ai_h, 2048, belief_h, 1024, 2, TRAJ);
  hipMemsetAsync(BCTXV, 0, 384*4, stream);
  k_colsum<<<dim3(2,8), B256, 0, stream>>>(TRAJ, 2048, 384, 1.0f/2048.0f, BCTXV);

  /* ---- stance delta ---- */
  hipMemcpyAsync(SDIN, stance_h, 384*4, hipMemcpyDeviceToDevice, stream);
  hipMemcpyAsync(SDIN + 384, stance_h + (size_t)2047*384, 384*4, hipMemcpyDeviceToDevice, stream);
  gemv(SDIN, 768, sc1W, 384, sc1b, T1, 384, 1);
  gemv(T1, 384, sc2W, 192, sc2b, SDELT, 192, 0);

  /* ---- classifier ---- */
  gemv(TEMB, 1344, cl1W, 384, cl1b, Z1, 384, 0);
  k_lnrow<<<dim3(1), dim3(128), 0, stream>>>(Z1, Zb, cllng, cllnb, 1 /*relu*/);
  gemv(Zb, 384, cl2W, 192, cl2b, Z2, 192, 1);
  k_final<<<dim3(1), dim3(64), 0, stream>>>(Z2, cl3W, cl3b, out);

  /* ---- per_turn ---- */
  k_rowdot<<<dim3(512), B256, 0, stream>>>(AICTX, 384, 384, tpW, tpb, out + 2, 2048);
}

// Round 7
// 4073.138 us; speedup vs baseline: 6.3368x; 1.5348x over previous
//
#include <hip/hip_runtime.h>
#include <hip/hip_bf16.h>

#define NEDGE 229376
#define NTOT  8192
#define BNCONST 0.9999950000374997f   /* 1/sqrt(1+1e-5) */
#define ISQ96   0.10206207261596575f  /* 1/sqrt(96) */

__constant__ int c_NT[5]     = {2048,2048,2048,1024,1024};
__constant__ int c_OFFS[5]   = {0,2048,4096,6144,7168};
__constant__ int c_ESRC[8]   = {0,1,1,2,0,3,1,4};
__constant__ int c_EDST[8]   = {1,0,2,2,3,1,4,2};
__constant__ int c_EOFF[9]   = {0,32768,65536,98304,131072,147456,180224,196608,229376};
__constant__ int c_RELROW[8] = {0,2048,4096,6144,8192,10240,11264,13312};

static const int h_NT[5]   = {2048,2048,2048,1024,1024};
static const int h_OFFS[5] = {0,2048,4096,6144,7168};

__device__ inline float gelu_f(float x){ return 0.5f*x*(1.0f+erff(x*0.70710678118654752f)); }
__device__ inline float sigm(float x){ return 1.0f/(1.0f+expf(-x)); }
__device__ inline float wsum64(float v){
  #pragma unroll
  for (int s=32;s>0;s>>=1) v += __shfl_xor(v, s, 64);
  return v;
}
__device__ inline float wmax64(float v){
  #pragma unroll
  for (int s=32;s>0;s>>=1) v = fmaxf(v, __shfl_xor(v, s, 64));
  return v;
}
__device__ inline unsigned encf(float f){
  unsigned b = __float_as_uint(f);
  return (b & 0x80000000u) ? ~b : (b | 0x80000000u);
}
__device__ inline float decf(unsigned u){
  unsigned b = (u & 0x80000000u) ? (u & 0x7FFFFFFFu) : ~u;
  return __uint_as_float(b);
}
__device__ inline int row_type(int row){
  return (row<2048)?0:((row<4096)?1:((row<6144)?2:((row<7168)?3:4)));
}

/* ---------------- simple utility kernels ---------------- */

__global__ void k_mix(const float* __restrict__ a, const float* __restrict__ b,
                      float* __restrict__ c, int n, float fa, float fb){
  int i = blockIdx.x*256 + threadIdx.x;
  if (i < n) c[i] = fa*a[i] + fb*b[i];
}

__global__ void k_comb(const float* __restrict__ ai, const float* __restrict__ user,
                       float* __restrict__ cb){
  int i = blockIdx.x*256 + threadIdx.x;
  if (i >= 2048*768) return;
  int n = i / 768, c = i - n*768;
  cb[i] = (c < 384) ? ai[n*384 + c] : user[n*384 + (c-384)];
}

/* ---------------- edge preprocessing (CSR by destination) ---------------- */

__global__ void k_edge_pre(const int* __restrict__ esrc, const int* __restrict__ edst,
                           int* edg, int* esr, int* erl, int* cnt){
  int e = blockIdx.x*256 + threadIdx.x;
  if (e >= NEDGE) return;
  int r = 0;
  #pragma unroll
  for (int q=1;q<8;q++) if (e >= c_EOFF[q]) r = q;
  int dg = c_OFFS[c_EDST[r]] + edst[e];
  edg[e] = dg;
  esr[e] = c_RELROW[r] + esrc[e];
  erl[e] = r;
  atomicAdd(&cnt[dg], 1);
}

__global__ __launch_bounds__(1024) void k_scan(const int* __restrict__ cnt, int* __restrict__ off){
  __shared__ int sh[1024];
  int tid = threadIdx.x;
  int base = tid*8;
  int loc[8]; int run = 0;
  #pragma unroll
  for (int i=0;i<8;i++){ loc[i] = run; run += cnt[base+i]; }
  sh[tid] = run;
  __syncthreads();
  for (int d=1; d<1024; d<<=1){
    int v = (tid >= d) ? sh[tid-d] : 0;
    __syncthreads();
    sh[tid] += v;
    __syncthreads();
  }
  int pre = (tid==0) ? 0 : sh[tid-1];
  #pragma unroll
  for (int i=0;i<8;i++) off[base+i] = pre + loc[i];
  if (tid==1023) off[8192] = sh[1023];
}

__global__ void k_scatter(const int* __restrict__ edg, const int* __restrict__ off,
                          int* cnt2, int* csr){
  int e = blockIdx.x*256 + threadIdx.x;
  if (e >= NEDGE) return;
  int dg = edg[e];
  int pos = off[dg] + atomicAdd(&cnt2[dg], 1);
  csr[pos] = e;
}

/* ------- tiled GEMMs: 64x64 tile, 4x4 microtile, double-buffered + float4 stage ------- */
/* K must be a multiple of 16 at every call site (384/768/96/chunked-256). */

__global__ __launch_bounds__(256) void gemm_f(
    const float* __restrict__ A, int lda, const float* __restrict__ B, int ldb,
    const float* __restrict__ bias, const float* __restrict__ cs, const float* __restrict__ csh,
    float kmul, float* __restrict__ C, int ldc, int M, int N, int K, int act, int agelu)
{
  __shared__ float As[2][16][68];
  __shared__ float Bs[2][16][68];
  int tid = threadIdx.x;
  int tx = tid & 15, ty = tid >> 4;
  int am = tid >> 2, ak = (tid & 3) * 4;     /* A stage: row am, k-quad ak */
  int bk = tid >> 4, bn = (tid & 15) * 4;    /* B stage: k-row bk, col-quad bn */
  int m0 = blockIdx.y * 64, n0 = blockIdx.x * 64;
  int gmA = m0 + am;
  int gnB = n0 + bn;
  int ntiles = K >> 4;
  float4 ra, rb;
  float acc[4][4] = {};

  auto fetch = [&](int kk){
    if (gmA < M){
      ra = *reinterpret_cast<const float4*>(&A[(size_t)gmA*lda + kk + ak]);
      if (agelu){ ra.x=gelu_f(ra.x); ra.y=gelu_f(ra.y); ra.z=gelu_f(ra.z); ra.w=gelu_f(ra.w); }
    } else ra = make_float4(0.f,0.f,0.f,0.f);
    if (gnB + 3 < N){
      rb = *reinterpret_cast<const float4*>(&B[(size_t)(kk + bk)*ldb + gnB]);
    } else {
      rb.x = (gnB   < N) ? B[(size_t)(kk + bk)*ldb + gnB  ] : 0.f;
      rb.y = (gnB+1 < N) ? B[(size_t)(kk + bk)*ldb + gnB+1] : 0.f;
      rb.z = (gnB+2 < N) ? B[(size_t)(kk + bk)*ldb + gnB+2] : 0.f;
      rb.w = (gnB+3 < N) ? B[(size_t)(kk + bk)*ldb + gnB+3] : 0.f;
    }
  };
  auto stage = [&](int b){
    As[b][ak  ][am] = ra.x;
    As[b][ak+1][am] = ra.y;
    As[b][ak+2][am] = ra.z;
    As[b][ak+3][am] = ra.w;
    *reinterpret_cast<float4*>(&Bs[b][bk][bn]) = rb;
  };

  fetch(0);
  stage(0);
  __syncthreads();
  for (int t = 0; t < ntiles; t++){
    int cur = t & 1;
    if (t + 1 < ntiles) fetch((t+1) << 4);
    #pragma unroll
    for (int k = 0; k < 16; k++) {
      float4 a4 = *reinterpret_cast<const float4*>(&As[cur][k][ty*4]);
      float4 b4 = *reinterpret_cast<const float4*>(&Bs[cur][k][tx*4]);
      float a[4] = {a4.x, a4.y, a4.z, a4.w};
      float b[4] = {b4.x, b4.y, b4.z, b4.w};
      #pragma unroll
      for (int i=0;i<4;i++)
        #pragma unroll
        for (int j=0;j<4;j++) acc[i][j] += a[i]*b[j];
    }
    if (t + 1 < ntiles) stage(cur ^ 1);
    __syncthreads();
  }
  #pragma unroll
  for (int i=0;i<4;i++){
    int gm = m0 + ty*4 + i; if (gm >= M) continue;
    #pragma unroll
    for (int j=0;j<4;j++){
      int gn = n0 + tx*4 + j; if (gn >= N) continue;
      float v = acc[i][j];
      if (bias) v += bias[gn];
      float s = kmul;
      if (cs) s *= cs[gn];
      v *= s;
      if (csh) v += csh[gn];
      if (act==1) v = fmaxf(v, 0.f);
      C[(size_t)gm*ldc + gn] = v;
    }
  }
}

// C[m,n] = scale * sum_k A[m,k]*B[n,k]   (Q @ K^T)
__global__ __launch_bounds__(256) void gemm_abt_f(
    const float* __restrict__ A, int lda, const float* __restrict__ B, int ldb,
    float* __restrict__ C, int ldc, int M, int N, int K, float scale)
{
  __shared__ float As[2][16][68];
  __shared__ float Bs[2][16][68];
  int tid = threadIdx.x;
  int tx = tid & 15, ty = tid >> 4;
  int am = tid >> 2, ak = (tid & 3) * 4;
  int m0 = blockIdx.y * 64, n0 = blockIdx.x * 64;
  int gmA = m0 + am;
  int gnB = n0 + am;              /* B staged same geometry: row gn, k-quad ak */
  int ntiles = K >> 4;
  float4 ra, rb;
  float acc[4][4] = {};

  auto fetch = [&](int kk){
    ra = (gmA < M) ? *reinterpret_cast<const float4*>(&A[(size_t)gmA*lda + kk + ak])
                   : make_float4(0.f,0.f,0.f,0.f);
    rb = (gnB < N) ? *reinterpret_cast<const float4*>(&B[(size_t)gnB*ldb + kk + ak])
                   : make_float4(0.f,0.f,0.f,0.f);
  };
  auto stage = [&](int b){
    As[b][ak  ][am] = ra.x;
    As[b][ak+1][am] = ra.y;
    As[b][ak+2][am] = ra.z;
    As[b][ak+3][am] = ra.w;
    Bs[b][ak  ][am] = rb.x;
    Bs[b][ak+1][am] = rb.y;
    Bs[b][ak+2][am] = rb.z;
    Bs[b][ak+3][am] = rb.w;
  };

  fetch(0);
  stage(0);
  __syncthreads();
  for (int t = 0; t < ntiles; t++){
    int cur = t & 1;
    if (t + 1 < ntiles) fetch((t+1) << 4);
    #pragma unroll
    for (int k = 0; k < 16; k++) {
      float4 a4 = *reinterpret_cast<const float4*>(&As[cur][k][ty*4]);
      float4 b4 = *reinterpret_cast<const float4*>(&Bs[cur][k][tx*4]);
      float a[4] = {a4.x, a4.y, a4.z, a4.w};
      float b[4] = {b4.x, b4.y, b4.z, b4.w};
      #pragma unroll
      for (int i=0;i<4;i++)
        #pragma unroll
        for (int j=0;j<4;j++) acc[i][j] += a[i]*b[j];
    }
    if (t + 1 < ntiles) stage(cur ^ 1);
    __syncthreads();
  }
  #pragma unroll
  for (int i=0;i<4;i++){
    int gm = m0 + ty*4 + i; if (gm >= M) continue;
    #pragma unroll
    for (int j=0;j<4;j++){
      int gn = n0 + tx*4 + j; if (gn >= N) continue;
      C[(size_t)gm*ldc + gn] = acc[i][j]*scale;
    }
  }
}

// C[m,n] += sum_l A[l,m]*B[l,n], head-batched + L-split (atomic accumulate).
__global__ __launch_bounds__(256) void gemm_atb_ks(
    const float* __restrict__ A0, int lda, const float* __restrict__ B0, int ldb,
    float* __restrict__ C0, int ldc, int M, int N, int L,
    int hsA, int hsB, int hsC, int nch)
{
  __shared__ float As[2][16][68];
  __shared__ float Bs[2][16][68];
  int h = blockIdx.z / nch, c = blockIdx.z % nch;
  const float* A = A0 + (size_t)h*hsA;
  const float* B = B0 + (size_t)h*hsB;
  float* C = C0 + (size_t)h*hsC;
  int l0 = c*256;
  int tid = threadIdx.x;
  int tx = tid & 15, ty = tid >> 4;
  int sl = tid >> 4, sq = (tid & 15) * 4;   /* stage: l-row sl, quad sq (cols of A/B) */
  int m0 = blockIdx.y * 64, n0 = blockIdx.x * 64;
  int gmA = m0 + sq, gnB = n0 + sq;
  int ntiles = 16;                           /* 256 / 16 */
  float4 ra, rb;
  float acc[4][4] = {};

  auto fetch = [&](int ll){
    if (gmA + 3 < M){
      ra = *reinterpret_cast<const float4*>(&A[(size_t)(ll + sl)*lda + gmA]);
    } else {
      ra.x = (gmA   < M) ? A[(size_t)(ll + sl)*lda + gmA  ] : 0.f;
      ra.y = (gmA+1 < M) ? A[(size_t)(ll + sl)*lda + gmA+1] : 0.f;
      ra.z = (gmA+2 < M) ? A[(size_t)(ll + sl)*lda + gmA+2] : 0.f;
      ra.w = (gmA+3 < M) ? A[(size_t)(ll + sl)*lda + gmA+3] : 0.f;
    }
    if (gnB + 3 < N){
      rb = *reinterpret_cast<const float4*>(&B[(size_t)(ll + sl)*ldb + gnB]);
    } else {
      rb.x = (gnB   < N) ? B[(size_t)(ll + sl)*ldb + gnB  ] : 0.f;
      rb.y = (gnB+1 < N) ? B[(size_t)(ll + sl)*ldb + gnB+1] : 0.f;
      rb.z = (gnB+2 < N) ? B[(size_t)(ll + sl)*ldb + gnB+2] : 0.f;
      rb.w = (gnB+3 < N) ? B[(size_t)(ll + sl)*ldb + gnB+3] : 0.f;
    }
  };
  auto stage = [&](int b){
    *reinterpret_cast<float4*>(&As[b][sl][sq]) = ra;
    *reinterpret_cast<float4*>(&Bs[b][sl][sq]) = rb;
  };

  fetch(l0);
  stage(0);
  __syncthreads();
  for (int t = 0; t < ntiles; t++){
    int cur = t & 1;
    if (t + 1 < ntiles) fetch(l0 + ((t+1) << 4));
    #pragma unroll
    for (int l = 0; l < 16; l++) {
      float4 a4 = *reinterpret_cast<const float4*>(&As[cur][l][ty*4]);
      float4 b4 = *reinterpret_cast<const float4*>(&Bs[cur][l][tx*4]);
      float a[4] = {a4.x, a4.y, a4.z, a4.w};
      float b[4] = {b4.x, b4.y, b4.z, b4.w};
      #pragma unroll
      for (int i=0;i<4;i++)
        #pragma unroll
        for (int j=0;j<4;j++) acc[i][j] += a[i]*b[j];
    }
    if (t + 1 < ntiles) stage(cur ^ 1);
    __syncthreads();
  }
  #pragma unroll
  for (int i=0;i<4;i++){
    int gm = m0 + ty*4 + i; if (gm >= M) continue;
    #pragma unroll
    for (int j=0;j<4;j++){
      int gn = n0 + tx*4 + j; if (gn >= N) continue;
      atomicAdd(&C[(size_t)gm*ldc + gn], acc[i][j]);
    }
  }
}

// C += (A@B)*scale over K-chunk (grid.z = chunk of 256); atomic accumulate.
__global__ __launch_bounds__(256) void gemm_nn_ks(
    const float* __restrict__ A, int lda, const float* __restrict__ B, int ldb,
    float* __restrict__ C, int ldc, int M, int N, int K, float scale)
{
  __shared__ float As[2][16][68];
  __shared__ float Bs[2][16][68];
  int k0 = blockIdx.z*256, k1 = min(K, k0+256);
  int tid = threadIdx.x;
  int tx = tid & 15, ty = tid >> 4;
  int am = tid >> 2, ak = (tid & 3) * 4;
  int bk = tid >> 4, bn = (tid & 15) * 4;
  int m0 = blockIdx.y * 64, n0 = blockIdx.x * 64;
  int gmA = m0 + am, gnB = n0 + bn;
  int ntiles = (k1 - k0) >> 4;
  float4 ra, rb;
  float acc[4][4] = {};

  auto fetch = [&](int kk){
    ra = (gmA < M) ? *reinterpret_cast<const float4*>(&A[(size_t)gmA*lda + kk + ak])
                   : make_float4(0.f,0.f,0.f,0.f);
    if (gnB + 3 < N){
      rb = *reinterpret_cast<const float4*>(&B[(size_t)(kk + bk)*ldb + gnB]);
    } else {
      rb.x = (gnB   < N) ? B[(size_t)(kk + bk)*ldb + gnB  ] : 0.f;
      rb.y = (gnB+1 < N) ? B[(size_t)(kk + bk)*ldb + gnB+1] : 0.f;
      rb.z = (gnB+2 < N) ? B[(size_t)(kk + bk)*ldb + gnB+2] : 0.f;
      rb.w = (gnB+3 < N) ? B[(size_t)(kk + bk)*ldb + gnB+3] : 0.f;
    }
  };
  auto stage = [&](int b){
    As[b][ak  ][am] = ra.x;
    As[b][ak+1][am] = ra.y;
    As[b][ak+2][am] = ra.z;
    As[b][ak+3][am] = ra.w;
    *reinterpret_cast<float4*>(&Bs[b][bk][bn]) = rb;
  };

  fetch(k0);
  stage(0);
  __syncthreads();
  for (int t = 0; t < ntiles; t++){
    int cur = t & 1;
    if (t + 1 < ntiles) fetch(k0 + ((t+1) << 4));
    #pragma unroll
    for (int k = 0; k < 16; k++) {
      float4 a4 = *reinterpret_cast<const float4*>(&As[cur][k][ty*4]);
      float4 b4 = *reinterpret_cast<const float4*>(&Bs[cur][k][tx*4]);
      float a[4] = {a4.x, a4.y, a4.z, a4.w};
      float b[4] = {b4.x, b4.y, b4.z, b4.w};
      #pragma unroll
      for (int i=0;i<4;i++)
        #pragma unroll
        for (int j=0;j<4;j++) acc[i][j] += a[i]*b[j];
    }
    if (t + 1 < ntiles) stage(cur ^ 1);
    __syncthreads();
  }
  #pragma unroll
  for (int i=0;i<4;i++){
    int gm = m0 + ty*4 + i; if (gm >= M) continue;
    #pragma unroll
    for (int j=0;j<4;j++){
      int gn = n0 + tx*4 + j; if (gn >= N) continue;
      atomicAdd(&C[(size_t)gm*ldc + gn], acc[i][j]*scale);
    }
  }
}

/* ---------------- HGT relation projection ---------------- */
__global__ __launch_bounds__(192) void k_relproj(
    const float* __restrict__ KQV_, const float* __restrict__ krel_l,
    const float* __restrict__ vrel_l, float* __restrict__ KE_, float* __restrict__ VE_)
{
  int r = blockIdx.z >> 1, w = blockIdx.z & 1, h = blockIdx.y;
  int s = c_ESRC[r];
  int Ns = c_NT[s];
  int row0 = blockIdx.x * 16;
  if (row0 >= Ns) return;
  __shared__ float Wl[96*96];
  __shared__ float Ar[2][96];
  const float* Wp = (w ? vrel_l : krel_l) + (size_t)(r*4 + h)*9216;
  int tid = threadIdx.y*96 + threadIdx.x;
  for (int idx = tid; idx < 9216; idx += 192) Wl[idx] = Wp[idx];
  __syncthreads();
  int colbase = (w ? 768 : 0) + h*96;
  float* OUT = (w ? VE_ : KE_);
  for (int it = 0; it < 8; it++){
    int rr = row0 + it*2 + threadIdx.y;
    const float* a = KQV_ + (size_t)(c_OFFS[s] + rr)*1152 + colbase;
    Ar[threadIdx.y][threadIdx.x] = a[threadIdx.x];
    __syncthreads();
    float acc = 0.f;
    #pragma unroll 8
    for (int d = 0; d < 96; d++) acc += Ar[threadIdx.y][d] * Wl[d*96 + threadIdx.x];
    OUT[(size_t)(c_RELROW[r] + rr)*384 + h*96 + threadIdx.x] = acc;
    __syncthreads();
  }
}

/* ---------------- edge attention ---------------- */

__global__ __launch_bounds__(256) void k_escore(
    const float* __restrict__ KQV_, const float* __restrict__ KE_,
    const int* __restrict__ edg, const int* __restrict__ esr, const int* __restrict__ erl,
    const float* __restrict__ prel_l, float* __restrict__ EA)
{
  int e = blockIdx.x*4 + (threadIdx.x>>6);
  if (e >= NEDGE) return;
  int lane = threadIdx.x & 63;
  int h = lane >> 4, j = lane & 15;
  int dg = edg[e], sr = esr[e], r = erl[e];
  const float* q  = KQV_ + (size_t)dg*1152 + 384 + h*96;
  const float* ke = KE_  + (size_t)sr*384 + h*96;
  float p = 0.f;
  #pragma unroll
  for (int t=0;t<6;t++){ int d = j + t*16; p += q[d]*ke[d]; }
  p += __shfl_xor(p, 1, 64);
  p += __shfl_xor(p, 2, 64);
  p += __shfl_xor(p, 4, 64);
  p += __shfl_xor(p, 8, 64);
  if (j == 0) EA[(size_t)e*4 + h] = p * prel_l[r*4+h] * ISQ96;
}

__global__ void k_segmax(const float* __restrict__ EA, const int* __restrict__ edg,
                         unsigned* __restrict__ EMX){
  int i = blockIdx.x*256 + threadIdx.x;
  if (i >= NEDGE*4) return;
  int e = i >> 2, h = i & 3;
  atomicMax(&EMX[edg[e]*4 + h], encf(EA[i]));
}

__global__ void k_expsum(float* __restrict__ EA, const int* __restrict__ edg,
                         const unsigned* __restrict__ EMX, float* __restrict__ EDEN){
  int i = blockIdx.x*256 + threadIdx.x;
  if (i >= NEDGE*4) return;
  int e = i >> 2, h = i & 3;
  int dg = edg[e];
  float m = decf(EMX[dg*4 + h]);
  float ex = expf(EA[i] - m);
  EA[i] = ex;
  atomicAdd(&EDEN[dg*4 + h], ex);
}

__global__ __launch_bounds__(128) void k_agg(
    const float* __restrict__ EA, const float* __restrict__ VE_,
    const float* __restrict__ EDEN, const int* __restrict__ csr,
    const int* __restrict__ off, const int* __restrict__ esr, float* __restrict__ AGG)
{
  int node = blockIdx.x, tid = threadIdx.x;
  int b = off[node], e1 = off[node+1];
  int d0 = tid, d1 = tid+128, d2 = tid+256;
  int h0 = d0/96, h1 = d1/96, h2 = d2/96;
  float a0=0.f, a1=0.f, a2=0.f;
  if (e1 > b){
    float i0 = 1.0f/EDEN[node*4+h0];
    float i1 = 1.0f/EDEN[node*4+h1];
    float i2 = 1.0f/EDEN[node*4+h2];
    for (int p=b; p<e1; p++){
      int e = csr[p];
      const float* ve = VE_ + (size_t)esr[e]*384;
      const float* ea = EA + (size_t)e*4;
      a0 += ea[h0]*i0*ve[d0];
      a1 += ea[h1]*i1*ve[d1];
      a2 += ea[h2]*i2*ve[d2];
    }
  }
  AGG[(size_t)node*384 + d0] = a0;
  AGG[(size_t)node*384 + d1] = a1;
  AGG[(size_t)node*384 + d2] = a2;
}

/* ---------------- row-wise norm kernels ---------------- */

__global__ __launch_bounds__(128) void k_gateln(
    const float* __restrict__ O, float* __restrict__ X,
    const float* __restrict__ skip_l, const float* __restrict__ lng, const float* __restrict__ lnb)
{
  __shared__ float red[2];
  int row = blockIdx.x, tid = threadIdx.x;
  int t = row_type(row);
  float gt = sigm(skip_l[t]);
  const float* o = O + (size_t)row*384;
  float* x = X + (size_t)row*384;
  float v0 = gelu_f(gt*o[tid]     + (1.f-gt)*x[tid]);
  float v1 = gelu_f(gt*o[tid+128] + (1.f-gt)*x[tid+128]);
  float v2 = gelu_f(gt*o[tid+256] + (1.f-gt)*x[tid+256]);
  int lane = tid & 63, wid = tid >> 6;
  float s = wsum64(v0+v1+v2);
  if (lane==0) red[wid] = s;
  __syncthreads();
  float mean = (red[0]+red[1]) * (1.0f/384.0f);
  __syncthreads();
  float d0=v0-mean, d1=v1-mean, d2=v2-mean;
  float q = wsum64(d0*d0+d1*d1+d2*d2);
  if (lane==0) red[wid] = q;
  __syncthreads();
  float var = (red[0]+red[1]) * (1.0f/384.0f);
  float rs = 1.0f/sqrtf(var + 1e-5f);
  const float* g = lng + (size_t)t*384;
  const float* b = lnb + (size_t)t*384;
  x[tid]     = d0*rs*g[tid]     + b[tid];
  x[tid+128] = d1*rs*g[tid+128] + b[tid+128];
  x[tid+256] = d2*rs*g[tid+256] + b[tid+256];
}

__global__ __launch_bounds__(128) void k_lnrow(
    const float* __restrict__ X, float* __restrict__ Y,
    const float* __restrict__ g, const float* __restrict__ b, int act)
{
  __shared__ float red[2];
  int row = blockIdx.x, tid = threadIdx.x;
  const float* x = X + (size_t)row*384;
  float* y = Y + (size_t)row*384;
  float v0 = x[tid], v1 = x[tid+128], v2 = x[tid+256];
  int lane = tid & 63, wid = tid >> 6;
  float s = wsum64(v0+v1+v2);
  if (lane==0) red[wid] = s;
  __syncthreads();
  float mean = (red[0]+red[1]) * (1.0f/384.0f);
  __syncthreads();
  float d0=v0-mean, d1=v1-mean, d2=v2-mean;
  float q = wsum64(d0*d0+d1*d1+d2*d2);
  if (lane==0) red[wid] = q;
  __syncthreads();
  float var = (red[0]+red[1]) * (1.0f/384.0f);
  float rs = 1.0f/sqrtf(var + 1e-5f);
  float u0 = d0*rs*g[tid]     + b[tid];
  float u1 = d1*rs*g[tid+128] + b[tid+128];
  float u2 = d2*rs*g[tid+256] + b[tid+256];
  if (act==1){ u0=fmaxf(u0,0.f); u1=fmaxf(u1,0.f); u2=fmaxf(u2,0.f); }
  else       { u0=gelu_f(u0); u1=gelu_f(u1); u2=gelu_f(u2); }
  y[tid] = u0; y[tid+128] = u1; y[tid+256] = u2;
}

/* ---------------- softmax / reductions / misc ---------------- */

__global__ __launch_bounds__(256) void k_softmax(float* __restrict__ S, int L){
  __shared__ float red[4];
  int row = blockIdx.x, tid = threadIdx.x;
  float* p = S + (size_t)row*L;
  float m = -3.0e38f;
  for (int c=tid;c<L;c+=256) m = fmaxf(m, p[c]);
  m = wmax64(m);
  int lane = tid & 63, wid = tid >> 6;
  if (lane==0) red[wid] = m;
  __syncthreads();
  m = fmaxf(fmaxf(red[0],red[1]), fmaxf(red[2],red[3]));
  __syncthreads();
  float s = 0.f;
  for (int c=tid;c<L;c+=256){ float e = expf(p[c]-m); p[c]=e; s += e; }
  s = wsum64(s);
  if (lane==0) red[wid] = s;
  __syncthreads();
  float inv = 1.0f/(red[0]+red[1]+red[2]+red[3]);
  for (int c=tid;c<L;c+=256) p[c] *= inv;
}

__global__ __launch_bounds__(256) void k_sumsq(const float* __restrict__ x, int n, float* out){
  __shared__ float red[4];
  float s = 0.f;
  for (int i = blockIdx.x*256 + threadIdx.x; i < n; i += gridDim.x*256){ float v=x[i]; s += v*v; }
  s = wsum64(s);
  int lane = threadIdx.x & 63, wid = threadIdx.x >> 6;
  if (lane==0) red[wid] = s;
  __syncthreads();
  if (threadIdx.x==0) atomicAdd(out, red[0]+red[1]+red[2]+red[3]);
}

__global__ void k_colsum(const float* __restrict__ A, int R, int C, float scale,
                         float* __restrict__ out){
  int col = blockIdx.x*256 + threadIdx.x;
  if (col >= C) return;
  int nchunk = gridDim.y;
  int chunk = (R + nchunk - 1)/nchunk;
  int r0 = blockIdx.y*chunk, r1 = min(R, r0+chunk);
  float s = 0.f;
  for (int r=r0; r<r1; r++) s += A[(size_t)r*C + col];
  atomicAdd(&out[col], s*scale);
}

__global__ __launch_bounds__(256) void k_dnm(const float* __restrict__ QB,
    const float* __restrict__ KSUM, const float* __restrict__ sqsk, float* __restrict__ DNM){
  int wv = blockIdx.x*4 + (threadIdx.x>>6);
  int n = wv >> 2, h = wv & 3;
  int lane = threadIdx.x & 63;
  const float* q = QB + (size_t)n*1536 + h*384;
  const float* ks = KSUM + h*384;
  float p = 0.f;
  #pragma unroll
  for (int d=lane; d<384; d+=64) p += q[d]*ks[d];
  p = wsum64(p);
  if (lane==0) DNM[n*4+h] = p * (1.0f/sqrtf(sqsk[0]*sqsk[1])) + 2048.0f;
}

__global__ void k_zcomb(const float* __restrict__ ZN, const float* __restrict__ VB_,
                        const float* __restrict__ DNM_, const float* __restrict__ sqsk,
                        float* __restrict__ XG_,
                        const float* __restrict__ bng, const float* __restrict__ bnb){
  int i = blockIdx.x*256 + threadIdx.x;
  if (i >= 2048*384) return;
  int n = i / 384, c = i - n*384;
  float inv_s = 1.0f/sqrtf(sqsk[0]*sqsk[1]);
  float zm = 0.f;
  #pragma unroll
  for (int h=0;h<4;h++){
    float num = ZN[(size_t)n*1536 + h*384 + c]*inv_s + 2048.0f*VB_[(size_t)n*1536 + h*384 + c];
    zm += num / DNM_[n*4+h];
  }
  zm *= 0.25f;
  float y = 0.5f*zm + 0.5f*XG_[i];
  y = y * (bng[c] * BNCONST) + bnb[c];
  XG_[i] = fmaxf(y, 0.f);
}

/* ---------------- conv1d (kernel 3, pad 1) ---------------- */
__global__ __launch_bounds__(256) void k_conv3(
    const float* __restrict__ in, const float* __restrict__ W, const float* __restrict__ bias,
    float* __restrict__ out, int IC, int OC)
{
  __shared__ float xs[34][384];
  int tid = threadIdx.x;
  int p0 = blockIdx.x*32, oc0 = blockIdx.y*64;
  for (int idx = tid; idx < 34*IC; idx += 256){
    int rr = idx / IC, c = idx - rr*IC;
    int gp = p0 - 1 + rr;
    xs[rr][c] = (gp >= 0 && gp < 2048) ? in[(size_t)gp*IC + c] : 0.f;
  }
  __syncthreads();
  int oc = oc0 + (tid & 63);
  int py = tid >> 6;
  float acc[8] = {0,0,0,0,0,0,0,0};
  const float* Wp = W + (size_t)oc*IC*3;
  for (int c=0;c<IC;c++){
    float w0 = Wp[c*3+0], w1 = Wp[c*3+1], w2 = Wp[c*3+2];
    #pragma unroll
    for (int u=0;u<8;u++){
      int pl = py + u*4;
      acc[u] += w0*xs[pl][c] + w1*xs[pl+1][c] + w2*xs[pl+2][c];
    }
  }
  float b = bias[oc];
  #pragma unroll
  for (int u=0;u<8;u++){
    int pl = py + u*4;
    out[(size_t)(p0+pl)*OC + oc] = gelu_f(acc[u] + b);
  }
}

/* ---------------- parallel small GEMV: partials + finalize ---------------- */

__global__ __launch_bounds__(256) void k_gemv_ks(
    const float* __restrict__ in, int K, const float* __restrict__ W, int ldw,
    float* __restrict__ tmp, int N)
{
  int c = blockIdx.x*64 + (threadIdx.x & 63);
  int w = threadIdx.x >> 6;
  int kch = blockIdx.y, nk = gridDim.y;
  int k0 = (int)(((long long)K * kch) / nk);
  int k1 = (int)(((long long)K * (kch+1)) / nk);
  float s = 0.f;
  if (c < N){
    for (int k = k0 + w; k < k1; k += 4)
      s += in[k] * W[(size_t)k*ldw + c];
  }
  __shared__ float red[4][64];
  red[w][threadIdx.x & 63] = s;
  __syncthreads();
  if (w == 0 && c < N){
    int l = threadIdx.x & 63;
    tmp[(size_t)kch*N + c] = red[0][l] + red[1][l] + red[2][l] + red[3][l];
  }
}

__global__ void k_gemv_fin(const float* __restrict__ tmp, int nk,
                           const float* __restrict__ b, float* __restrict__ out, int N, int act){
  int c = blockIdx.x*256 + threadIdx.x;
  if (c >= N) return;
  float v = 0.f;
  for (int i = 0; i < nk; i++) v += tmp[(size_t)i*N + c];
  v += b[c];
  if (act==1) v = fmaxf(v, 0.f);
  out[c] = v;
}

__global__ __launch_bounds__(256) void k_rowdot(const float* __restrict__ A, int lda, int K,
    const float* __restrict__ w, const float* __restrict__ b, float* __restrict__ out, int M){
  int r = blockIdx.x*4 + (threadIdx.x>>6);
  if (r >= M) return;
  int lane = threadIdx.x & 63;
  const float* a = A + (size_t)r*lda;
  float p = 0.f;
  for (int k = lane; k < K; k += 64) p += a[k]*w[k];
  p = wsum64(p);
  if (lane==0) out[r] = sigm(p + b[0]);
}

__global__ __launch_bounds__(64) void k_final(const float* __restrict__ z2,
    const float* __restrict__ w, const float* __restrict__ b, float* __restrict__ out){
  int lane = threadIdx.x;
  float p = 0.f;
  for (int k = lane; k < 192; k += 64) p += z2[k]*w[k];
  p = wsum64(p);
  if (lane==0){
    float l = p + b[0];
    out[0] = l;
    out[1] = sigm(l);
  }
}

/* ================================================================ */

extern "C" void kernel_launch(void* const* d_in, const int* in_sizes, int n_in,
                              void* d_out, int out_size, void* d_ws, size_t ws_size,
                              hipStream_t stream)
{
  const float* xin[5] = {(const float*)d_in[0], (const float*)d_in[1], (const float*)d_in[2],
                         (const float*)d_in[3], (const float*)d_in[4]};
  const float* Wkqv=(const float*)d_in[5];  const float* bkqv=(const float*)d_in[6];
  const float* Wout=(const float*)d_in[7];  const float* bout=(const float*)d_in[8];
  const float* krel=(const float*)d_in[9];  const float* vrel=(const float*)d_in[10];
  const float* prel=(const float*)d_in[11]; const float* skp =(const float*)d_in[12];
  const float* lng =(const float*)d_in[13]; const float* lnb =(const float*)d_in[14];
  const float* sp_W=(const float*)d_in[15]; const float* sp_b=(const float*)d_in[16];
  const float* sp_lng=(const float*)d_in[17]; const float* sp_lnb=(const float*)d_in[18];
  const float* fc0_W=(const float*)d_in[19]; const float* fc0_b=(const float*)d_in[20];
  const float* bn_g=(const float*)d_in[21]; const float* bn_b=(const float*)d_in[22];
  const float* tq_W=(const float*)d_in[23]; const float* tq_b=(const float*)d_in[24];
  const float* tk_W=(const float*)d_in[25]; const float* tk_b=(const float*)d_in[26];
  const float* tv_W=(const float*)d_in[27]; const float* tv_b=(const float*)d_in[28];
  const float* mWqkv=(const float*)d_in[29]; const float* mbqkv=(const float*)d_in[30];
  const float* mWo=(const float*)d_in[31];  const float* mbo=(const float*)d_in[32];
  const float* c1W=(const float*)d_in[33];  const float* c1b=(const float*)d_in[34];
  const float* c2W=(const float*)d_in[35];  const float* c2b=(const float*)d_in[36];
  const float* opW=(const float*)d_in[37];  const float* opb=(const float*)d_in[38];
  const float* as1W=(const float*)d_in[39]; const float* as1b=(const float*)d_in[40];
  const float* as2W=(const float*)d_in[41]; const float* as2b=(const float*)d_in[42];
  const float* sc1W=(const float*)d_in[43]; const float* sc1b=(const float*)d_in[44];
  const float* sc2W=(const float*)d_in[45]; const float* sc2b=(const float*)d_in[46];
  const float* cl1W=(const float*)d_in[47]; const float* cl1b=(const float*)d_in[48];
  const float* cllng=(const float*)d_in[49]; const float* cllnb=(const float*)d_in[50];
  const float* cl2W=(const float*)d_in[51]; const float* cl2b=(const float*)d_in[52];
  const float* cl3W=(const float*)d_in[53]; const float* cl3b=(const float*)d_in[54];
  const float* tpW=(const float*)d_in[55];  const float* tpb=(const float*)d_in[56];
  const int* e_src=(const int*)d_in[57];  const int* e_dst=(const int*)d_in[58];
  float* out = (float*)d_out;

  /* workspace arena */
  char* ws = (char*)d_ws;
  size_t off_b = 0;
  auto alloc = [&](size_t bytes)->char*{
    char* r = ws + off_b;
    off_b = (off_b + bytes + 255) & ~(size_t)255;
    return r;
  };
  float* X    = (float*)alloc((size_t)8192*384*4);
  float* KQV  = (float*)alloc((size_t)8192*1152*4);
  float* KE   = (float*)alloc((size_t)14336*384*4);
  float* VE   = (float*)alloc((size_t)14336*384*4);
  float* AGG  = (float*)alloc((size_t)8192*384*4);
  float* EA   = (float*)alloc((size_t)NEDGE*4*4);
  int* edg    = (int*)alloc((size_t)NEDGE*4);
  int* esr    = (int*)alloc((size_t)NEDGE*4);
  int* erl    = (int*)alloc((size_t)NEDGE*4);
  int* csr    = (int*)alloc((size_t)NEDGE*4);
  int* cnt    = (int*)alloc(8192*4);
  int* cnt2   = (int*)alloc(8192*4);
  int* coff   = (int*)alloc(8193*4);
  unsigned* EMX = (unsigned*)alloc(8192*4*4);
  float* EDEN = (float*)alloc(8192*4*4);
  float* SM   = (float*)alloc(65536);
  float* GT   = (float*)alloc(20*384*4);
  if (off_b > ws_size) return;

  float* SQSK = SM;
  float* TRAJSUM = SM + 8;
  float* DECAYSUM = SM + 392;
  float* TEMB = SM + 600;
  float* AIPOOL = SM + 984;
  float* BCTXV = SM + 1368;
  float* SDELT = SM + 1752;
  float* SDIN = SM + 2048;
  float* T1   = SM + 2816;
  float* Z1   = SM + 3200;
  float* Zb   = SM + 3584;
  float* Z2   = SM + 3968;
  float* KSUM = SM + 4224;
  float* DNM  = SM + 6144;

  float* QB = KQV;
  float* KB = KQV + (size_t)2048*1536;
  float* VB = KQV + (size_t)2*2048*1536;
  float* MQKV = KQV;
  float* AO = KQV + (size_t)2*2048*1536;
  float* SSC = KE;
  float* ZNUM = KE;
  float* OWT = KE;
  float* HS = VE;
  float* XG = VE + (size_t)2048*384;
  float* HM = VE + (size_t)2*2048*384;
  float* C1O = VE + (size_t)3*2048*384;
  float* TRAJ = VE + (size_t)4*2048*384;
  float* AICTX = VE + (size_t)5*2048*384;
  float* C2O = VE + (size_t)6*2048*384;
  float* TMPA = AGG;
  float* CB = AGG;
  float* PT = AGG + (size_t)2048*768;
  float* KVS = AGG + (size_t)2048*1152;

  dim3 B256(256);
  auto gemm = [&](const float* A, int lda, const float* Bw, int ldb, const float* bias,
                  const float* cs, const float* csh, float kmul,
                  float* C, int ldc, int M, int N, int K, int act, int agelu){
    dim3 g((N+63)/64, (M+63)/64);
    gemm_f<<<g, B256, 0, stream>>>(A, lda, Bw, ldb, bias, cs, csh, kmul, C, ldc, M, N, K, act, agelu);
  };
  auto gemm_abt = [&](const float* A, int lda, const float* B, int ldb, float* C, int ldc,
                      int M, int N, int K, float scale){
    dim3 g((N+63)/64, (M+63)/64);
    gemm_abt_f<<<g, B256, 0, stream>>>(A, lda, B, ldb, C, ldc, M, N, K, scale);
  };
  auto gemv = [&](const float* in, int K, const float* W, int ldw, const float* b,
                  float* o, int N, int act){
    int nk = (K + 79) / 80; if (nk > 20) nk = 20; if (nk < 1) nk = 1;
    k_gemv_ks<<<dim3((N+63)/64, nk), B256, 0, stream>>>(in, K, W, ldw, GT, N);
    k_gemv_fin<<<dim3((N+255)/256), B256, 0, stream>>>(GT, nk, b, o, N, act);
  };

  /* ---- edge CSR ---- */
  hipMemsetAsync(cnt, 0, 8192*4, stream);
  hipMemsetAsync(cnt2, 0, 8192*4, stream);
  k_edge_pre<<<dim3(NEDGE/256), B256, 0, stream>>>(e_src, e_dst, edg, esr, erl, cnt);
  k_scan<<<dim3(1), dim3(1024), 0, stream>>>(cnt, coff);
  k_scatter<<<dim3(NEDGE/256), B256, 0, stream>>>(edg, coff, cnt2, csr);

  /* ---- inputs -> X ---- */
  for (int t=0;t<5;t++)
    hipMemcpyAsync(X + (size_t)h_OFFS[t]*384, xin[t], (size_t)h_NT[t]*384*4,
                   hipMemcpyDeviceToDevice, stream);

  /* ---- HGT layers ---- */
  for (int l=0;l<2;l++){
    for (int t=0;t<5;t++)
      gemm(X + (size_t)h_OFFS[t]*384, 384, Wkqv + (size_t)(l*5+t)*442368, 1152,
           bkqv + (size_t)(l*5+t)*1152, nullptr, nullptr, 1.f,
           KQV + (size_t)h_OFFS[t]*1152, 1152, h_NT[t], 1152, 384, 0, 0);
    k_relproj<<<dim3(128,4,16), dim3(96,2), 0, stream>>>(
        KQV, krel + (size_t)l*294912, vrel + (size_t)l*294912, KE, VE);
    k_escore<<<dim3(NEDGE/4), B256, 0, stream>>>(KQV, KE, edg, esr, erl, prel + (size_t)l*32, EA);
    hipMemsetAsync(EMX, 0, 8192*4*4, stream);
    hipMemsetAsync(EDEN, 0, 8192*4*4, stream);
    k_segmax<<<dim3(NEDGE*4/256), B256, 0, stream>>>(EA, edg, EMX);
    k_expsum<<<dim3(NEDGE*4/256), B256, 0, stream>>>(EA, edg, EMX, EDEN);
    k_agg<<<dim3(NTOT), dim3(128), 0, stream>>>(EA, VE, EDEN, csr, coff, esr, AGG);
    for (int t=0;t<5;t++)
      gemm(AGG + (size_t)h_OFFS[t]*384, 384, Wout + (size_t)(l*5+t)*147456, 384,
           bout + (size_t)(l*5+t)*384, nullptr, nullptr, 1.f,
           OWT + (size_t)h_OFFS[t]*384, 384, h_NT[t], 384, 384, 0, 1 /*gelu on A*/);
    k_gateln<<<dim3(NTOT), dim3(128), 0, stream>>>(OWT, X, skp + l*5, lng, lnb);
  }

  const float* user_h   = X;
  const float* ai_h     = X + (size_t)2048*384;
  const float* stance_h = X + (size_t)4096*384;
  const float* belief_h = X + (size_t)7168*384;

  /* ---- hs, xg ---- */
  gemm(stance_h, 384, sp_W, 384, sp_b, nullptr, nullptr, 1.f, TMPA, 384, 2048, 384, 384, 0, 0);
  k_lnrow<<<dim3(2048), dim3(128), 0, stream>>>(TMPA, HS, sp_lng, sp_lnb, 0 /*gelu*/);
  gemm(HS, 384, fc0_W, 384, fc0_b, bn_g, bn_b, BNCONST, XG, 384, 2048, 384, 384, 1 /*relu*/, 0);

  /* ---- linear-attention blocks ---- */
  for (int i=0;i<2;i++){
    gemm(XG, 384, tq_W + (size_t)i*589824, 1536, tq_b + (size_t)i*1536, nullptr, nullptr, 1.f,
         QB, 1536, 2048, 1536, 384, 0, 0);
    gemm(XG, 384, tk_W + (size_t)i*589824, 1536, tk_b + (size_t)i*1536, nullptr, nullptr, 1.f,
         KB, 1536, 2048, 1536, 384, 0, 0);
    gemm(XG, 384, tv_W + (size_t)i*589824, 1536, tv_b + (size_t)i*1536, nullptr, nullptr, 1.f,
         VB, 1536, 2048, 1536, 384, 0, 0);
    hipMemsetAsync(SQSK, 0, 8, stream);
    k_sumsq<<<dim3(512), B256, 0, stream>>>(QB, 2048*1536, SQSK);
    k_sumsq<<<dim3(512), B256, 0, stream>>>(KB, 2048*1536, SQSK+1);
    hipMemsetAsync(KSUM, 0, 1536*4, stream);
    k_colsum<<<dim3(6,8), B256, 0, stream>>>(KB, 2048, 1536, 1.0f, KSUM);
    k_dnm<<<dim3(2048), B256, 0, stream>>>(QB, KSUM, SQSK, DNM);
    hipMemsetAsync(KVS, 0, (size_t)4*147456*4, stream);
    gemm_atb_ks<<<dim3(6,6,32), B256, 0, stream>>>(KB, 1536, VB, 1536, KVS, 384,
        384, 384, 2048, 384, 384, 147456, 8);
    for (int h=0;h<4;h++)
      gemm(QB + h*384, 1536, KVS + (size_t)h*147456, 384, nullptr, nullptr, nullptr, 1.f,
           ZNUM + h*384, 1536, 2048, 384, 384, 0, 0);
    k_zcomb<<<dim3(3072), B256, 0, stream>>>(ZNUM, VB, DNM, SQSK, XG,
        bn_g + (size_t)(i+1)*384, bn_b + (size_t)(i+1)*384);
  }

  /* ---- h_mixed ---- */
  k_mix<<<dim3(3072), B256, 0, stream>>>(HS, XG, HM, 2048*384, 0.7f, 0.3f);

  /* ---- MHA helper ---- */
  auto run_mha = [&](const float* qin, int nq, const float* kvin, int nkv, int mi, float* OUT){
    const float* Wq = mWqkv + (size_t)mi*442368;
    const float* bq = mbqkv + (size_t)mi*1152;
    gemm(qin, 384, Wq, 1152, bq, nullptr, nullptr, 1.f, MQKV, 1152, nq, 384, 384, 0, 0);
    gemm(kvin, 384, Wq + 384, 1152, bq + 384, nullptr, nullptr, 1.f, MQKV + 384, 1152, nkv, 768, 384, 0, 0);
    hipMemsetAsync(AO, 0, (size_t)nq*384*4, stream);
    int nch = (nkv + 255)/256;
    for (int h=0;h<4;h++){
      gemm_abt(MQKV + h*96, 1152, MQKV + 384 + h*96, 1152, SSC, nkv, nq, nkv, 96, ISQ96);
      k_softmax<<<dim3(nq), B256, 0, stream>>>(SSC, nkv);
      gemm_nn_ks<<<dim3(2, (nq+63)/64, nch), B256, 0, stream>>>(
          SSC, nkv, MQKV + 768 + h*96, 1152, AO + h*96, 384, nq, 96, nkv, 1.0f);
    }
    gemm(AO, 384, mWo + (size_t)mi*147456, 384, mbo + (size_t)mi*384,
         nullptr, nullptr, 1.f, OUT, 384, nq, 384, 384, 0, 0);
  };

  /* ---- traj ---- */
  run_mha(HM, 2048, HM, 2048, 1, TRAJ);
  hipMemsetAsync(TRAJSUM, 0, 576*4, stream);
  k_colsum<<<dim3(2,8), B256, 0, stream>>>(TRAJ, 2048, 384, 1.0f/2048.0f, TRAJSUM);

  /* ---- conv path ---- */
  k_conv3<<<dim3(64,6), B256, 0, stream>>>(HM, c1W, c1b, C1O, 384, 384);
  k_conv3<<<dim3(64,3), B256, 0, stream>>>(C1O, c2W, c2b, C2O, 384, 192);
  k_colsum<<<dim3(1,8), B256, 0, stream>>>(C2O, 2048, 192, 1.0f/2048.0f, DECAYSUM);

  /* ---- traj_emb ---- */
  gemv(TRAJSUM, 576, opW, 384, opb, TEMB, 384, 0);

  /* ---- ai_ctx ---- */
  run_mha(ai_h, 2048, user_h, 2048, 0, AICTX);
  hipMemsetAsync(AIPOOL, 0, 384*4, stream);
  k_colsum<<<dim3(2,8), B256, 0, stream>>>(AICTX, 2048, 384, 1.0f/2048.0f, AIPOOL);

  /* ---- pscores ---- */
  k_comb<<<dim3(6144), B256, 0, stream>>>(ai_h, user_h, CB);
  gemm(CB, 768, as1W, 384, as1b, nullptr, nullptr, 1.f, PT, 384, 2048, 384, 768, 1, 0);
  k_rowdot<<<dim3(512), B256, 0, stream>>>(PT, 384, 384, as2W, as2b, out + 2 + 2048, 2048);

  /* ---- bctx ---- */
  run_mha(ai_h, 2048, belief_h, 1024, 2, TRAJ);
  hipMemsetAsync(BCTXV, 0, 384*4, stream);
  k_colsum<<<dim3(2,8), B256, 0, stream>>>(TRAJ, 2048, 384, 1.0f/2048.0f, BCTXV);

  /* ---- stance delta ---- */
  hipMemcpyAsync(SDIN, stance_h, 384*4, hipMemcpyDeviceToDevice, stream);
  hipMemcpyAsync(SDIN + 384, stance_h + (size_t)2047*384, 384*4, hipMemcpyDeviceToDevice, stream);
  gemv(SDIN, 768, sc1W, 384, sc1b, T1, 384, 1);
  gemv(T1, 384, sc2W, 192, sc2b, SDELT, 192, 0);

  /* ---- classifier ---- */
  gemv(TEMB, 1344, cl1W, 384, cl1b, Z1, 384, 0);
  k_lnrow<<<dim3(1), dim3(128), 0, stream>>>(Z1, Zb, cllng, cllnb, 1 /*relu*/);
  gemv(Zb, 384, cl2W, 192, cl2b, Z2, 192, 1);
  k_final<<<dim3(1), dim3(64), 0, stream>>>(Z2, cl3W, cl3b, out);

  /* ---- per_turn ---- */
  k_rowdot<<<dim3(512), B256, 0, stream>>>(AICTX, 384, 384, tpW, tpb, out + 2, 2048);
}

// Round 8
// 3962.568 us; speedup vs baseline: 6.5136x; 1.0279x over previous
//
#include <hip/hip_runtime.h>
#include <hip/hip_bf16.h>

#define NEDGE 229376
#define NTOT  8192
#define BNCONST 0.9999950000374997f   /* 1/sqrt(1+1e-5) */
#define ISQ96   0.10206207261596575f  /* 1/sqrt(96) */

__constant__ int c_NT[5]     = {2048,2048,2048,1024,1024};
__constant__ int c_OFFS[5]   = {0,2048,4096,6144,7168};
__constant__ int c_ESRC[8]   = {0,1,1,2,0,3,1,4};
__constant__ int c_EDST[8]   = {1,0,2,2,3,1,4,2};
__constant__ int c_EOFF[9]   = {0,32768,65536,98304,131072,147456,180224,196608,229376};
__constant__ int c_RELROW[8] = {0,2048,4096,6144,8192,10240,11264,13312};

static const int h_NT[5]   = {2048,2048,2048,1024,1024};
static const int h_OFFS[5] = {0,2048,4096,6144,7168};

__device__ inline float gelu_f(float x){ return 0.5f*x*(1.0f+erff(x*0.70710678118654752f)); }
__device__ inline float sigm(float x){ return 1.0f/(1.0f+expf(-x)); }
__device__ inline float wsum64(float v){
  #pragma unroll
  for (int s=32;s>0;s>>=1) v += __shfl_xor(v, s, 64);
  return v;
}
__device__ inline float wmax64(float v){
  #pragma unroll
  for (int s=32;s>0;s>>=1) v = fmaxf(v, __shfl_xor(v, s, 64));
  return v;
}
__device__ inline unsigned encf(float f){
  unsigned b = __float_as_uint(f);
  return (b & 0x80000000u) ? ~b : (b | 0x80000000u);
}
__device__ inline float decf(unsigned u){
  unsigned b = (u & 0x80000000u) ? (u & 0x7FFFFFFFu) : ~u;
  return __uint_as_float(b);
}
__device__ inline int row_type(int row){
  return (row<2048)?0:((row<4096)?1:((row<6144)?2:((row<7168)?3:4)));
}

/* ---------------- simple utility kernels ---------------- */

__global__ void k_mix(const float* __restrict__ a, const float* __restrict__ b,
                      float* __restrict__ c, int n, float fa, float fb){
  int i = blockIdx.x*256 + threadIdx.x;
  if (i < n) c[i] = fa*a[i] + fb*b[i];
}

__global__ void k_comb(const float* __restrict__ ai, const float* __restrict__ user,
                       float* __restrict__ cb){
  int i = blockIdx.x*256 + threadIdx.x;
  if (i >= 2048*768) return;
  int n = i / 768, c = i - n*768;
  cb[i] = (c < 384) ? ai[n*384 + c] : user[n*384 + (c-384)];
}

/* ---------------- edge preprocessing (CSR by destination) ---------------- */

__global__ void k_edge_pre(const int* __restrict__ esrc, const int* __restrict__ edst,
                           int* edg, int* esr, int* erl, int* cnt){
  int e = blockIdx.x*256 + threadIdx.x;
  if (e >= NEDGE) return;
  int r = 0;
  #pragma unroll
  for (int q=1;q<8;q++) if (e >= c_EOFF[q]) r = q;
  int dg = c_OFFS[c_EDST[r]] + edst[e];
  edg[e] = dg;
  esr[e] = c_RELROW[r] + esrc[e];
  erl[e] = r;
  atomicAdd(&cnt[dg], 1);
}

__global__ __launch_bounds__(1024) void k_scan(const int* __restrict__ cnt, int* __restrict__ off){
  __shared__ int sh[1024];
  int tid = threadIdx.x;
  int base = tid*8;
  int loc[8]; int run = 0;
  #pragma unroll
  for (int i=0;i<8;i++){ loc[i] = run; run += cnt[base+i]; }
  sh[tid] = run;
  __syncthreads();
  for (int d=1; d<1024; d<<=1){
    int v = (tid >= d) ? sh[tid-d] : 0;
    __syncthreads();
    sh[tid] += v;
    __syncthreads();
  }
  int pre = (tid==0) ? 0 : sh[tid-1];
  #pragma unroll
  for (int i=0;i<8;i++) off[base+i] = pre + loc[i];
  if (tid==1023) off[8192] = sh[1023];
}

__global__ void k_scatter(const int* __restrict__ edg, const int* __restrict__ off,
                          int* cnt2, int* csr){
  int e = blockIdx.x*256 + threadIdx.x;
  if (e >= NEDGE) return;
  int dg = edg[e];
  int pos = off[dg] + atomicAdd(&cnt2[dg], 1);
  csr[pos] = e;
}

/* ------- tiled GEMMs: 64x64 tile, 4x4 microtile, double-buffered + float4 stage ------- */
/* K must be a multiple of 16 at every call site. */

__global__ __launch_bounds__(256) void gemm_f(
    const float* __restrict__ A, int lda, const float* __restrict__ B, int ldb,
    const float* __restrict__ bias, const float* __restrict__ cs, const float* __restrict__ csh,
    float kmul, float* __restrict__ C, int ldc, int M, int N, int K, int act, int agelu)
{
  __shared__ float As[2][16][68];
  __shared__ float Bs[2][16][68];
  int tid = threadIdx.x;
  int tx = tid & 15, ty = tid >> 4;
  int am = tid >> 2, ak = (tid & 3) * 4;
  int bk = tid >> 4, bn = (tid & 15) * 4;
  int m0 = blockIdx.y * 64, n0 = blockIdx.x * 64;
  int gmA = m0 + am;
  int gnB = n0 + bn;
  int ntiles = K >> 4;
  float4 ra, rb;
  float acc[4][4] = {};

  auto fetch = [&](int kk){
    if (gmA < M){
      ra = *reinterpret_cast<const float4*>(&A[(size_t)gmA*lda + kk + ak]);
      if (agelu){ ra.x=gelu_f(ra.x); ra.y=gelu_f(ra.y); ra.z=gelu_f(ra.z); ra.w=gelu_f(ra.w); }
    } else ra = make_float4(0.f,0.f,0.f,0.f);
    if (gnB + 3 < N){
      rb = *reinterpret_cast<const float4*>(&B[(size_t)(kk + bk)*ldb + gnB]);
    } else {
      rb.x = (gnB   < N) ? B[(size_t)(kk + bk)*ldb + gnB  ] : 0.f;
      rb.y = (gnB+1 < N) ? B[(size_t)(kk + bk)*ldb + gnB+1] : 0.f;
      rb.z = (gnB+2 < N) ? B[(size_t)(kk + bk)*ldb + gnB+2] : 0.f;
      rb.w = (gnB+3 < N) ? B[(size_t)(kk + bk)*ldb + gnB+3] : 0.f;
    }
  };
  auto stage = [&](int b){
    As[b][ak  ][am] = ra.x;
    As[b][ak+1][am] = ra.y;
    As[b][ak+2][am] = ra.z;
    As[b][ak+3][am] = ra.w;
    *reinterpret_cast<float4*>(&Bs[b][bk][bn]) = rb;
  };

  fetch(0);
  stage(0);
  __syncthreads();
  for (int t = 0; t < ntiles; t++){
    int cur = t & 1;
    if (t + 1 < ntiles) fetch((t+1) << 4);
    #pragma unroll
    for (int k = 0; k < 16; k++) {
      float4 a4 = *reinterpret_cast<const float4*>(&As[cur][k][ty*4]);
      float4 b4 = *reinterpret_cast<const float4*>(&Bs[cur][k][tx*4]);
      float a[4] = {a4.x, a4.y, a4.z, a4.w};
      float b[4] = {b4.x, b4.y, b4.z, b4.w};
      #pragma unroll
      for (int i=0;i<4;i++)
        #pragma unroll
        for (int j=0;j<4;j++) acc[i][j] += a[i]*b[j];
    }
    if (t + 1 < ntiles) stage(cur ^ 1);
    __syncthreads();
  }
  #pragma unroll
  for (int i=0;i<4;i++){
    int gm = m0 + ty*4 + i; if (gm >= M) continue;
    #pragma unroll
    for (int j=0;j<4;j++){
      int gn = n0 + tx*4 + j; if (gn >= N) continue;
      float v = acc[i][j];
      if (bias) v += bias[gn];
      float s = kmul;
      if (cs) s *= cs[gn];
      v *= s;
      if (csh) v += csh[gn];
      if (act==1) v = fmaxf(v, 0.f);
      C[(size_t)gm*ldc + gn] = v;
    }
  }
}

/* batched HGT relation projection as GEMM: z = (r*4+h)*2 + w
   A = KQV rows of src type (cols h*96 [+768 for v]), B = rel (96x96), C = KE/VE */
__global__ __launch_bounds__(256) void gemm_rel(
    const float* __restrict__ KQV_, const float* __restrict__ krel_l,
    const float* __restrict__ vrel_l, float* __restrict__ KE_, float* __restrict__ VE_)
{
  int z = blockIdx.z;
  int w = z & 1, h = (z >> 1) & 3, r = z >> 3;
  int s = c_ESRC[r];
  int Ns = c_NT[s];
  int m0 = blockIdx.y * 64;
  if (m0 >= Ns) return;
  int n0 = blockIdx.x * 64;            /* N = 96: tiles 0..63, 64..95 */
  const float* A = KQV_ + (size_t)c_OFFS[s]*1152 + (w ? 768 : 0) + h*96;
  const float* B = (w ? vrel_l : krel_l) + (size_t)(r*4 + h)*9216;
  float* C = (w ? VE_ : KE_) + (size_t)c_RELROW[r]*384 + h*96;

  __shared__ float As[2][16][68];
  __shared__ float Bs[2][16][68];
  int tid = threadIdx.x;
  int tx = tid & 15, ty = tid >> 4;
  int am = tid >> 2, ak = (tid & 3) * 4;
  int bk = tid >> 4, bn = (tid & 15) * 4;
  int gmA = m0 + am;
  int gnB = n0 + bn;
  float4 ra, rb;
  float acc[4][4] = {};

  auto fetch = [&](int kk){
    ra = (gmA < Ns) ? *reinterpret_cast<const float4*>(&A[(size_t)gmA*1152 + kk + ak])
                    : make_float4(0.f,0.f,0.f,0.f);
    if (gnB + 3 < 96){
      rb = *reinterpret_cast<const float4*>(&B[(size_t)(kk + bk)*96 + gnB]);
    } else {
      rb.x = (gnB   < 96) ? B[(size_t)(kk + bk)*96 + gnB  ] : 0.f;
      rb.y = (gnB+1 < 96) ? B[(size_t)(kk + bk)*96 + gnB+1] : 0.f;
      rb.z = (gnB+2 < 96) ? B[(size_t)(kk + bk)*96 + gnB+2] : 0.f;
      rb.w = (gnB+3 < 96) ? B[(size_t)(kk + bk)*96 + gnB+3] : 0.f;
    }
  };
  auto stage = [&](int b){
    As[b][ak  ][am] = ra.x;
    As[b][ak+1][am] = ra.y;
    As[b][ak+2][am] = ra.z;
    As[b][ak+3][am] = ra.w;
    *reinterpret_cast<float4*>(&Bs[b][bk][bn]) = rb;
  };

  fetch(0);
  stage(0);
  __syncthreads();
  for (int t = 0; t < 6; t++){               /* K = 96 */
    int cur = t & 1;
    if (t + 1 < 6) fetch((t+1) << 4);
    #pragma unroll
    for (int k = 0; k < 16; k++) {
      float4 a4 = *reinterpret_cast<const float4*>(&As[cur][k][ty*4]);
      float4 b4 = *reinterpret_cast<const float4*>(&Bs[cur][k][tx*4]);
      float a[4] = {a4.x, a4.y, a4.z, a4.w};
      float b[4] = {b4.x, b4.y, b4.z, b4.w};
      #pragma unroll
      for (int i=0;i<4;i++)
        #pragma unroll
        for (int j=0;j<4;j++) acc[i][j] += a[i]*b[j];
    }
    if (t + 1 < 6) stage(cur ^ 1);
    __syncthreads();
  }
  #pragma unroll
  for (int i=0;i<4;i++){
    int gm = m0 + ty*4 + i; if (gm >= Ns) continue;
    #pragma unroll
    for (int j=0;j<4;j++){
      int gn = n0 + tx*4 + j; if (gn >= 96) continue;
      C[(size_t)gm*384 + gn] = acc[i][j];
    }
  }
}

// C[m,n] = scale * sum_k A[m,k]*B[n,k]   (Q @ K^T)
__global__ __launch_bounds__(256) void gemm_abt_f(
    const float* __restrict__ A, int lda, const float* __restrict__ B, int ldb,
    float* __restrict__ C, int ldc, int M, int N, int K, float scale)
{
  __shared__ float As[2][16][68];
  __shared__ float Bs[2][16][68];
  int tid = threadIdx.x;
  int tx = tid & 15, ty = tid >> 4;
  int am = tid >> 2, ak = (tid & 3) * 4;
  int m0 = blockIdx.y * 64, n0 = blockIdx.x * 64;
  int gmA = m0 + am;
  int gnB = n0 + am;
  int ntiles = K >> 4;
  float4 ra, rb;
  float acc[4][4] = {};

  auto fetch = [&](int kk){
    ra = (gmA < M) ? *reinterpret_cast<const float4*>(&A[(size_t)gmA*lda + kk + ak])
                   : make_float4(0.f,0.f,0.f,0.f);
    rb = (gnB < N) ? *reinterpret_cast<const float4*>(&B[(size_t)gnB*ldb + kk + ak])
                   : make_float4(0.f,0.f,0.f,0.f);
  };
  auto stage = [&](int b){
    As[b][ak  ][am] = ra.x;
    As[b][ak+1][am] = ra.y;
    As[b][ak+2][am] = ra.z;
    As[b][ak+3][am] = ra.w;
    Bs[b][ak  ][am] = rb.x;
    Bs[b][ak+1][am] = rb.y;
    Bs[b][ak+2][am] = rb.z;
    Bs[b][ak+3][am] = rb.w;
  };

  fetch(0);
  stage(0);
  __syncthreads();
  for (int t = 0; t < ntiles; t++){
    int cur = t & 1;
    if (t + 1 < ntiles) fetch((t+1) << 4);
    #pragma unroll
    for (int k = 0; k < 16; k++) {
      float4 a4 = *reinterpret_cast<const float4*>(&As[cur][k][ty*4]);
      float4 b4 = *reinterpret_cast<const float4*>(&Bs[cur][k][tx*4]);
      float a[4] = {a4.x, a4.y, a4.z, a4.w};
      float b[4] = {b4.x, b4.y, b4.z, b4.w};
      #pragma unroll
      for (int i=0;i<4;i++)
        #pragma unroll
        for (int j=0;j<4;j++) acc[i][j] += a[i]*b[j];
    }
    if (t + 1 < ntiles) stage(cur ^ 1);
    __syncthreads();
  }
  #pragma unroll
  for (int i=0;i<4;i++){
    int gm = m0 + ty*4 + i; if (gm >= M) continue;
    #pragma unroll
    for (int j=0;j<4;j++){
      int gn = n0 + tx*4 + j; if (gn >= N) continue;
      C[(size_t)gm*ldc + gn] = acc[i][j]*scale;
    }
  }
}

// C[m,n] += sum_l A[l,m]*B[l,n], head-batched + L-split (atomic accumulate).
__global__ __launch_bounds__(256) void gemm_atb_ks(
    const float* __restrict__ A0, int lda, const float* __restrict__ B0, int ldb,
    float* __restrict__ C0, int ldc, int M, int N, int L,
    int hsA, int hsB, int hsC, int nch)
{
  __shared__ float As[2][16][68];
  __shared__ float Bs[2][16][68];
  int h = blockIdx.z / nch, c = blockIdx.z % nch;
  const float* A = A0 + (size_t)h*hsA;
  const float* B = B0 + (size_t)h*hsB;
  float* C = C0 + (size_t)h*hsC;
  int l0 = c*256;
  int tid = threadIdx.x;
  int tx = tid & 15, ty = tid >> 4;
  int sl = tid >> 4, sq = (tid & 15) * 4;
  int m0 = blockIdx.y * 64, n0 = blockIdx.x * 64;
  int gmA = m0 + sq, gnB = n0 + sq;
  int ntiles = 16;
  float4 ra, rb;
  float acc[4][4] = {};

  auto fetch = [&](int ll){
    if (gmA + 3 < M){
      ra = *reinterpret_cast<const float4*>(&A[(size_t)(ll + sl)*lda + gmA]);
    } else {
      ra.x = (gmA   < M) ? A[(size_t)(ll + sl)*lda + gmA  ] : 0.f;
      ra.y = (gmA+1 < M) ? A[(size_t)(ll + sl)*lda + gmA+1] : 0.f;
      ra.z = (gmA+2 < M) ? A[(size_t)(ll + sl)*lda + gmA+2] : 0.f;
      ra.w = (gmA+3 < M) ? A[(size_t)(ll + sl)*lda + gmA+3] : 0.f;
    }
    if (gnB + 3 < N){
      rb = *reinterpret_cast<const float4*>(&B[(size_t)(ll + sl)*ldb + gnB]);
    } else {
      rb.x = (gnB   < N) ? B[(size_t)(ll + sl)*ldb + gnB  ] : 0.f;
      rb.y = (gnB+1 < N) ? B[(size_t)(ll + sl)*ldb + gnB+1] : 0.f;
      rb.z = (gnB+2 < N) ? B[(size_t)(ll + sl)*ldb + gnB+2] : 0.f;
      rb.w = (gnB+3 < N) ? B[(size_t)(ll + sl)*ldb + gnB+3] : 0.f;
    }
  };
  auto stage = [&](int b){
    *reinterpret_cast<float4*>(&As[b][sl][sq]) = ra;
    *reinterpret_cast<float4*>(&Bs[b][sl][sq]) = rb;
  };

  fetch(l0);
  stage(0);
  __syncthreads();
  for (int t = 0; t < ntiles; t++){
    int cur = t & 1;
    if (t + 1 < ntiles) fetch(l0 + ((t+1) << 4));
    #pragma unroll
    for (int l = 0; l < 16; l++) {
      float4 a4 = *reinterpret_cast<const float4*>(&As[cur][l][ty*4]);
      float4 b4 = *reinterpret_cast<const float4*>(&Bs[cur][l][tx*4]);
      float a[4] = {a4.x, a4.y, a4.z, a4.w};
      float b[4] = {b4.x, b4.y, b4.z, b4.w};
      #pragma unroll
      for (int i=0;i<4;i++)
        #pragma unroll
        for (int j=0;j<4;j++) acc[i][j] += a[i]*b[j];
    }
    if (t + 1 < ntiles) stage(cur ^ 1);
    __syncthreads();
  }
  #pragma unroll
  for (int i=0;i<4;i++){
    int gm = m0 + ty*4 + i; if (gm >= M) continue;
    #pragma unroll
    for (int j=0;j<4;j++){
      int gn = n0 + tx*4 + j; if (gn >= N) continue;
      atomicAdd(&C[(size_t)gm*ldc + gn], acc[i][j]);
    }
  }
}

// C += (A@B)*scale over K-chunk (grid.z = chunk of 256); atomic accumulate.
__global__ __launch_bounds__(256) void gemm_nn_ks(
    const float* __restrict__ A, int lda, const float* __restrict__ B, int ldb,
    float* __restrict__ C, int ldc, int M, int N, int K, float scale)
{
  __shared__ float As[2][16][68];
  __shared__ float Bs[2][16][68];
  int k0 = blockIdx.z*256, k1 = min(K, k0+256);
  int tid = threadIdx.x;
  int tx = tid & 15, ty = tid >> 4;
  int am = tid >> 2, ak = (tid & 3) * 4;
  int bk = tid >> 4, bn = (tid & 15) * 4;
  int m0 = blockIdx.y * 64, n0 = blockIdx.x * 64;
  int gmA = m0 + am, gnB = n0 + bn;
  int ntiles = (k1 - k0) >> 4;
  float4 ra, rb;
  float acc[4][4] = {};

  auto fetch = [&](int kk){
    ra = (gmA < M) ? *reinterpret_cast<const float4*>(&A[(size_t)gmA*lda + kk + ak])
                   : make_float4(0.f,0.f,0.f,0.f);
    if (gnB + 3 < N){
      rb = *reinterpret_cast<const float4*>(&B[(size_t)(kk + bk)*ldb + gnB]);
    } else {
      rb.x = (gnB   < N) ? B[(size_t)(kk + bk)*ldb + gnB  ] : 0.f;
      rb.y = (gnB+1 < N) ? B[(size_t)(kk + bk)*ldb + gnB+1] : 0.f;
      rb.z = (gnB+2 < N) ? B[(size_t)(kk + bk)*ldb + gnB+2] : 0.f;
      rb.w = (gnB+3 < N) ? B[(size_t)(kk + bk)*ldb + gnB+3] : 0.f;
    }
  };
  auto stage = [&](int b){
    As[b][ak  ][am] = ra.x;
    As[b][ak+1][am] = ra.y;
    As[b][ak+2][am] = ra.z;
    As[b][ak+3][am] = ra.w;
    *reinterpret_cast<float4*>(&Bs[b][bk][bn]) = rb;
  };

  fetch(k0);
  stage(0);
  __syncthreads();
  for (int t = 0; t < ntiles; t++){
    int cur = t & 1;
    if (t + 1 < ntiles) fetch(k0 + ((t+1) << 4));
    #pragma unroll
    for (int k = 0; k < 16; k++) {
      float4 a4 = *reinterpret_cast<const float4*>(&As[cur][k][ty*4]);
      float4 b4 = *reinterpret_cast<const float4*>(&Bs[cur][k][tx*4]);
      float a[4] = {a4.x, a4.y, a4.z, a4.w};
      float b[4] = {b4.x, b4.y, b4.z, b4.w};
      #pragma unroll
      for (int i=0;i<4;i++)
        #pragma unroll
        for (int j=0;j<4;j++) acc[i][j] += a[i]*b[j];
    }
    if (t + 1 < ntiles) stage(cur ^ 1);
    __syncthreads();
  }
  #pragma unroll
  for (int i=0;i<4;i++){
    int gm = m0 + ty*4 + i; if (gm >= M) continue;
    #pragma unroll
    for (int j=0;j<4;j++){
      int gn = n0 + tx*4 + j; if (gn >= N) continue;
      atomicAdd(&C[(size_t)gm*ldc + gn], acc[i][j]*scale);
    }
  }
}

/* ---------------- edge attention ---------------- */

__global__ __launch_bounds__(256) void k_escore(
    const float* __restrict__ KQV_, const float* __restrict__ KE_,
    const int* __restrict__ edg, const int* __restrict__ esr, const int* __restrict__ erl,
    const float* __restrict__ prel_l, float* __restrict__ EA)
{
  int e = blockIdx.x*4 + (threadIdx.x>>6);
  if (e >= NEDGE) return;
  int lane = threadIdx.x & 63;
  int h = lane >> 4, j = lane & 15;
  int dg = edg[e], sr = esr[e], r = erl[e];
  const float* q  = KQV_ + (size_t)dg*1152 + 384 + h*96;
  const float* ke = KE_  + (size_t)sr*384 + h*96;
  float p = 0.f;
  #pragma unroll
  for (int t=0;t<6;t++){ int d = j + t*16; p += q[d]*ke[d]; }
  p += __shfl_xor(p, 1, 64);
  p += __shfl_xor(p, 2, 64);
  p += __shfl_xor(p, 4, 64);
  p += __shfl_xor(p, 8, 64);
  if (j == 0) EA[(size_t)e*4 + h] = p * prel_l[r*4+h] * ISQ96;
}

__global__ void k_segmax(const float* __restrict__ EA, const int* __restrict__ edg,
                         unsigned* __restrict__ EMX){
  int i = blockIdx.x*256 + threadIdx.x;
  if (i >= NEDGE*4) return;
  int e = i >> 2, h = i & 3;
  atomicMax(&EMX[edg[e]*4 + h], encf(EA[i]));
}

__global__ void k_expsum(float* __restrict__ EA, const int* __restrict__ edg,
                         const unsigned* __restrict__ EMX, float* __restrict__ EDEN){
  int i = blockIdx.x*256 + threadIdx.x;
  if (i >= NEDGE*4) return;
  int e = i >> 2, h = i & 3;
  int dg = edg[e];
  float m = decf(EMX[dg*4 + h]);
  float ex = expf(EA[i] - m);
  EA[i] = ex;
  atomicAdd(&EDEN[dg*4 + h], ex);
}

__global__ __launch_bounds__(128) void k_agg(
    const float* __restrict__ EA, const float* __restrict__ VE_,
    const float* __restrict__ EDEN, const int* __restrict__ csr,
    const int* __restrict__ off, const int* __restrict__ esr, float* __restrict__ AGG)
{
  int node = blockIdx.x, tid = threadIdx.x;
  int b = off[node], e1 = off[node+1];
  int d0 = tid, d1 = tid+128, d2 = tid+256;
  int h0 = d0/96, h1 = d1/96, h2 = d2/96;
  float a0=0.f, a1=0.f, a2=0.f;
  if (e1 > b){
    float i0 = 1.0f/EDEN[node*4+h0];
    float i1 = 1.0f/EDEN[node*4+h1];
    float i2 = 1.0f/EDEN[node*4+h2];
    for (int p=b; p<e1; p++){
      int e = csr[p];
      const float* ve = VE_ + (size_t)esr[e]*384;
      const float* ea = EA + (size_t)e*4;
      a0 += ea[h0]*i0*ve[d0];
      a1 += ea[h1]*i1*ve[d1];
      a2 += ea[h2]*i2*ve[d2];
    }
  }
  AGG[(size_t)node*384 + d0] = a0;
  AGG[(size_t)node*384 + d1] = a1;
  AGG[(size_t)node*384 + d2] = a2;
}

/* ---------------- row-wise norm kernels ---------------- */

__global__ __launch_bounds__(128) void k_gateln(
    const float* __restrict__ O, float* __restrict__ X,
    const float* __restrict__ skip_l, const float* __restrict__ lng, const float* __restrict__ lnb)
{
  __shared__ float red[2];
  int row = blockIdx.x, tid = threadIdx.x;
  int t = row_type(row);
  float gt = sigm(skip_l[t]);
  const float* o = O + (size_t)row*384;
  float* x = X + (size_t)row*384;
  float v0 = gelu_f(gt*o[tid]     + (1.f-gt)*x[tid]);
  float v1 = gelu_f(gt*o[tid+128] + (1.f-gt)*x[tid+128]);
  float v2 = gelu_f(gt*o[tid+256] + (1.f-gt)*x[tid+256]);
  int lane = tid & 63, wid = tid >> 6;
  float s = wsum64(v0+v1+v2);
  if (lane==0) red[wid] = s;
  __syncthreads();
  float mean = (red[0]+red[1]) * (1.0f/384.0f);
  __syncthreads();
  float d0=v0-mean, d1=v1-mean, d2=v2-mean;
  float q = wsum64(d0*d0+d1*d1+d2*d2);
  if (lane==0) red[wid] = q;
  __syncthreads();
  float var = (red[0]+red[1]) * (1.0f/384.0f);
  float rs = 1.0f/sqrtf(var + 1e-5f);
  const float* g = lng + (size_t)t*384;
  const float* b = lnb + (size_t)t*384;
  x[tid]     = d0*rs*g[tid]     + b[tid];
  x[tid+128] = d1*rs*g[tid+128] + b[tid+128];
  x[tid+256] = d2*rs*g[tid+256] + b[tid+256];
}

__global__ __launch_bounds__(128) void k_lnrow(
    const float* __restrict__ X, float* __restrict__ Y,
    const float* __restrict__ g, const float* __restrict__ b, int act)
{
  __shared__ float red[2];
  int row = blockIdx.x, tid = threadIdx.x;
  const float* x = X + (size_t)row*384;
  float* y = Y + (size_t)row*384;
  float v0 = x[tid], v1 = x[tid+128], v2 = x[tid+256];
  int lane = tid & 63, wid = tid >> 6;
  float s = wsum64(v0+v1+v2);
  if (lane==0) red[wid] = s;
  __syncthreads();
  float mean = (red[0]+red[1]) * (1.0f/384.0f);
  __syncthreads();
  float d0=v0-mean, d1=v1-mean, d2=v2-mean;
  float q = wsum64(d0*d0+d1*d1+d2*d2);
  if (lane==0) red[wid] = q;
  __syncthreads();
  float var = (red[0]+red[1]) * (1.0f/384.0f);
  float rs = 1.0f/sqrtf(var + 1e-5f);
  float u0 = d0*rs*g[tid]     + b[tid];
  float u1 = d1*rs*g[tid+128] + b[tid+128];
  float u2 = d2*rs*g[tid+256] + b[tid+256];
  if (act==1){ u0=fmaxf(u0,0.f); u1=fmaxf(u1,0.f); u2=fmaxf(u2,0.f); }
  else       { u0=gelu_f(u0); u1=gelu_f(u1); u2=gelu_f(u2); }
  y[tid] = u0; y[tid+128] = u1; y[tid+256] = u2;
}

/* ---------------- softmax (single pass, cols in registers, L<=2048) ---------------- */

__global__ __launch_bounds__(256) void k_softmax(float* __restrict__ S, int L){
  __shared__ float red[4];
  int row = blockIdx.x, tid = threadIdx.x;
  float* p = S + (size_t)row*L;
  float v[8];
  int n = 0;
  float m = -3.0e38f;
  for (int c = tid; c < L; c += 256){ v[n] = p[c]; m = fmaxf(m, v[n]); n++; }
  m = wmax64(m);
  int lane = tid & 63, wid = tid >> 6;
  if (lane==0) red[wid] = m;
  __syncthreads();
  m = fmaxf(fmaxf(red[0],red[1]), fmaxf(red[2],red[3]));
  __syncthreads();
  float s = 0.f;
  #pragma unroll
  for (int i=0;i<8;i++) if (i < n){ v[i] = expf(v[i]-m); s += v[i]; }
  s = wsum64(s);
  if (lane==0) red[wid] = s;
  __syncthreads();
  float inv = 1.0f/(red[0]+red[1]+red[2]+red[3]);
  n = 0;
  for (int c = tid; c < L; c += 256){ p[c] = v[n]*inv; n++; }
}

/* ---------------- reductions / misc ---------------- */

__global__ __launch_bounds__(256) void k_sumsq(const float* __restrict__ x, int n, float* out){
  __shared__ float red[4];
  float s = 0.f;
  for (int i = blockIdx.x*256 + threadIdx.x; i < n; i += gridDim.x*256){ float v=x[i]; s += v*v; }
  s = wsum64(s);
  int lane = threadIdx.x & 63, wid = threadIdx.x >> 6;
  if (lane==0) red[wid] = s;
  __syncthreads();
  if (threadIdx.x==0) atomicAdd(out, red[0]+red[1]+red[2]+red[3]);
}

__global__ void k_colsum(const float* __restrict__ A, int R, int C, float scale,
                         float* __restrict__ out){
  int col = blockIdx.x*256 + threadIdx.x;
  if (col >= C) return;
  int nchunk = gridDim.y;
  int chunk = (R + nchunk - 1)/nchunk;
  int r0 = blockIdx.y*chunk, r1 = min(R, r0+chunk);
  float s = 0.f;
  for (int r=r0; r<r1; r++) s += A[(size_t)r*C + col];
  atomicAdd(&out[col], s*scale);
}

__global__ __launch_bounds__(256) void k_dnm(const float* __restrict__ QB,
    const float* __restrict__ KSUM, const float* __restrict__ sqsk, float* __restrict__ DNM){
  int wv = blockIdx.x*4 + (threadIdx.x>>6);
  int n = wv >> 2, h = wv & 3;
  int lane = threadIdx.x & 63;
  const float* q = QB + (size_t)n*1536 + h*384;
  const float* ks = KSUM + h*384;
  float p = 0.f;
  #pragma unroll
  for (int d=lane; d<384; d+=64) p += q[d]*ks[d];
  p = wsum64(p);
  if (lane==0) DNM[n*4+h] = p * (1.0f/sqrtf(sqsk[0]*sqsk[1])) + 2048.0f;
}

__global__ void k_zcomb(const float* __restrict__ ZN, const float* __restrict__ VB_,
                        const float* __restrict__ DNM_, const float* __restrict__ sqsk,
                        float* __restrict__ XG_,
                        const float* __restrict__ bng, const float* __restrict__ bnb){
  int i = blockIdx.x*256 + threadIdx.x;
  if (i >= 2048*384) return;
  int n = i / 384, c = i - n*384;
  float inv_s = 1.0f/sqrtf(sqsk[0]*sqsk[1]);
  float zm = 0.f;
  #pragma unroll
  for (int h=0;h<4;h++){
    float num = ZN[(size_t)n*1536 + h*384 + c]*inv_s + 2048.0f*VB_[(size_t)n*1536 + h*384 + c];
    zm += num / DNM_[n*4+h];
  }
  zm *= 0.25f;
  float y = 0.5f*zm + 0.5f*XG_[i];
  y = y * (bng[c] * BNCONST) + bnb[c];
  XG_[i] = fmaxf(y, 0.f);
}

/* ---------------- conv1d (kernel 3, pad 1) ---------------- */
__global__ __launch_bounds__(256) void k_conv3(
    const float* __restrict__ in, const float* __restrict__ W, const float* __restrict__ bias,
    float* __restrict__ out, int IC, int OC)
{
  __shared__ float xs[34][384];
  int tid = threadIdx.x;
  int p0 = blockIdx.x*32, oc0 = blockIdx.y*64;
  for (int idx = tid; idx < 34*IC; idx += 256){
    int rr = idx / IC, c = idx - rr*IC;
    int gp = p0 - 1 + rr;
    xs[rr][c] = (gp >= 0 && gp < 2048) ? in[(size_t)gp*IC + c] : 0.f;
  }
  __syncthreads();
  int oc = oc0 + (tid & 63);
  int py = tid >> 6;
  float acc[8] = {0,0,0,0,0,0,0,0};
  const float* Wp = W + (size_t)oc*IC*3;
  for (int c=0;c<IC;c++){
    float w0 = Wp[c*3+0], w1 = Wp[c*3+1], w2 = Wp[c*3+2];
    #pragma unroll
    for (int u=0;u<8;u++){
      int pl = py + u*4;
      acc[u] += w0*xs[pl][c] + w1*xs[pl+1][c] + w2*xs[pl+2][c];
    }
  }
  float b = bias[oc];
  #pragma unroll
  for (int u=0;u<8;u++){
    int pl = py + u*4;
    out[(size_t)(p0+pl)*OC + oc] = gelu_f(acc[u] + b);
  }
}

/* ---------------- parallel small GEMV: partials + finalize ---------------- */

__global__ __launch_bounds__(256) void k_gemv_ks(
    const float* __restrict__ in, int K, const float* __restrict__ W, int ldw,
    float* __restrict__ tmp, int N)
{
  int c = blockIdx.x*64 + (threadIdx.x & 63);
  int w = threadIdx.x >> 6;
  int kch = blockIdx.y, nk = gridDim.y;
  int k0 = (int)(((long long)K * kch) / nk);
  int k1 = (int)(((long long)K * (kch+1)) / nk);
  float s = 0.f;
  if (c < N){
    for (int k = k0 + w; k < k1; k += 4)
      s += in[k] * W[(size_t)k*ldw + c];
  }
  __shared__ float red[4][64];
  red[w][threadIdx.x & 63] = s;
  __syncthreads();
  if (w == 0 && c < N){
    int l = threadIdx.x & 63;
    tmp[(size_t)kch*N + c] = red[0][l] + red[1][l] + red[2][l] + red[3][l];
  }
}

__global__ void k_gemv_fin(const float* __restrict__ tmp, int nk,
                           const float* __restrict__ b, float* __restrict__ out, int N, int act){
  int c = blockIdx.x*256 + threadIdx.x;
  if (c >= N) return;
  float v = 0.f;
  for (int i = 0; i < nk; i++) v += tmp[(size_t)i*N + c];
  v += b[c];
  if (act==1) v = fmaxf(v, 0.f);
  out[c] = v;
}

__global__ __launch_bounds__(256) void k_rowdot(const float* __restrict__ A, int lda, int K,
    const float* __restrict__ w, const float* __restrict__ b, float* __restrict__ out, int M){
  int r = blockIdx.x*4 + (threadIdx.x>>6);
  if (r >= M) return;
  int lane = threadIdx.x & 63;
  const float* a = A + (size_t)r*lda;
  float p = 0.f;
  for (int k = lane; k < K; k += 64) p += a[k]*w[k];
  p = wsum64(p);
  if (lane==0) out[r] = sigm(p + b[0]);
}

__global__ __launch_bounds__(64) void k_final(const float* __restrict__ z2,
    const float* __restrict__ w, const float* __restrict__ b, float* __restrict__ out){
  int lane = threadIdx.x;
  float p = 0.f;
  for (int k = lane; k < 192; k += 64) p += z2[k]*w[k];
  p = wsum64(p);
  if (lane==0){
    float l = p + b[0];
    out[0] = l;
    out[1] = sigm(l);
  }
}

/* ================================================================ */

extern "C" void kernel_launch(void* const* d_in, const int* in_sizes, int n_in,
                              void* d_out, int out_size, void* d_ws, size_t ws_size,
                              hipStream_t stream)
{
  const float* xin[5] = {(const float*)d_in[0], (const float*)d_in[1], (const float*)d_in[2],
                         (const float*)d_in[3], (const float*)d_in[4]};
  const float* Wkqv=(const float*)d_in[5];  const float* bkqv=(const float*)d_in[6];
  const float* Wout=(const float*)d_in[7];  const float* bout=(const float*)d_in[8];
  const float* krel=(const float*)d_in[9];  const float* vrel=(const float*)d_in[10];
  const float* prel=(const float*)d_in[11]; const float* skp =(const float*)d_in[12];
  const float* lng =(const float*)d_in[13]; const float* lnb =(const float*)d_in[14];
  const float* sp_W=(const float*)d_in[15]; const float* sp_b=(const float*)d_in[16];
  const float* sp_lng=(const float*)d_in[17]; const float* sp_lnb=(const float*)d_in[18];
  const float* fc0_W=(const float*)d_in[19]; const float* fc0_b=(const float*)d_in[20];
  const float* bn_g=(const float*)d_in[21]; const float* bn_b=(const float*)d_in[22];
  const float* tq_W=(const float*)d_in[23]; const float* tq_b=(const float*)d_in[24];
  const float* tk_W=(const float*)d_in[25]; const float* tk_b=(const float*)d_in[26];
  const float* tv_W=(const float*)d_in[27]; const float* tv_b=(const float*)d_in[28];
  const float* mWqkv=(const float*)d_in[29]; const float* mbqkv=(const float*)d_in[30];
  const float* mWo=(const float*)d_in[31];  const float* mbo=(const float*)d_in[32];
  const float* c1W=(const float*)d_in[33];  const float* c1b=(const float*)d_in[34];
  const float* c2W=(const float*)d_in[35];  const float* c2b=(const float*)d_in[36];
  const float* opW=(const float*)d_in[37];  const float* opb=(const float*)d_in[38];
  const float* as1W=(const float*)d_in[39]; const float* as1b=(const float*)d_in[40];
  const float* as2W=(const float*)d_in[41]; const float* as2b=(const float*)d_in[42];
  const float* sc1W=(const float*)d_in[43]; const float* sc1b=(const float*)d_in[44];
  const float* sc2W=(const float*)d_in[45]; const float* sc2b=(const float*)d_in[46];
  const float* cl1W=(const float*)d_in[47]; const float* cl1b=(const float*)d_in[48];
  const float* cllng=(const float*)d_in[49]; const float* cllnb=(const float*)d_in[50];
  const float* cl2W=(const float*)d_in[51]; const float* cl2b=(const float*)d_in[52];
  const float* cl3W=(const float*)d_in[53]; const float* cl3b=(const float*)d_in[54];
  const float* tpW=(const float*)d_in[55];  const float* tpb=(const float*)d_in[56];
  const int* e_src=(const int*)d_in[57];  const int* e_dst=(const int*)d_in[58];
  float* out = (float*)d_out;

  /* workspace arena */
  char* ws = (char*)d_ws;
  size_t off_b = 0;
  auto alloc = [&](size_t bytes)->char*{
    char* r = ws + off_b;
    off_b = (off_b + bytes + 255) & ~(size_t)255;
    return r;
  };
  float* X    = (float*)alloc((size_t)8192*384*4);
  float* KQV  = (float*)alloc((size_t)8192*1152*4);
  float* KE   = (float*)alloc((size_t)14336*384*4);
  float* VE   = (float*)alloc((size_t)14336*384*4);
  float* AGG  = (float*)alloc((size_t)8192*384*4);
  float* EA   = (float*)alloc((size_t)NEDGE*4*4);
  int* edg    = (int*)alloc((size_t)NEDGE*4);
  int* esr    = (int*)alloc((size_t)NEDGE*4);
  int* erl    = (int*)alloc((size_t)NEDGE*4);
  int* csr    = (int*)alloc((size_t)NEDGE*4);
  int* cnt    = (int*)alloc(8192*4);
  int* cnt2   = (int*)alloc(8192*4);
  int* coff   = (int*)alloc(8193*4);
  unsigned* EMX = (unsigned*)alloc(8192*4*4);
  float* EDEN = (float*)alloc(8192*4*4);
  float* SM   = (float*)alloc(65536);
  float* GT   = (float*)alloc(20*384*4);
  if (off_b > ws_size) return;

  float* SQSK = SM;
  float* TRAJSUM = SM + 8;
  float* DECAYSUM = SM + 392;
  float* TEMB = SM + 600;
  float* AIPOOL = SM + 984;
  float* BCTXV = SM + 1368;
  float* SDELT = SM + 1752;
  float* SDIN = SM + 2048;
  float* T1   = SM + 2816;
  float* Z1   = SM + 3200;
  float* Zb   = SM + 3584;
  float* Z2   = SM + 3968;
  float* KSUM = SM + 4224;
  float* DNM  = SM + 6144;

  float* QB = KQV;
  float* KB = KQV + (size_t)2048*1536;
  float* VB = KQV + (size_t)2*2048*1536;
  float* MQKV = KQV;
  float* AO = KQV + (size_t)2*2048*1536;
  float* SSC = KE;
  float* ZNUM = KE;
  float* OWT = KE;
  float* HS = VE;
  float* XG = VE + (size_t)2048*384;
  float* HM = VE + (size_t)2*2048*384;
  float* C1O = VE + (size_t)3*2048*384;
  float* TRAJ = VE + (size_t)4*2048*384;
  float* AICTX = VE + (size_t)5*2048*384;
  float* C2O = VE + (size_t)6*2048*384;
  float* TMPA = AGG;
  float* CB = AGG;
  float* PT = AGG + (size_t)2048*768;
  float* KVS = AGG + (size_t)2048*1152;

  dim3 B256(256);
  auto gemm = [&](const float* A, int lda, const float* Bw, int ldb, const float* bias,
                  const float* cs, const float* csh, float kmul,
                  float* C, int ldc, int M, int N, int K, int act, int agelu){
    dim3 g((N+63)/64, (M+63)/64);
    gemm_f<<<g, B256, 0, stream>>>(A, lda, Bw, ldb, bias, cs, csh, kmul, C, ldc, M, N, K, act, agelu);
  };
  auto gemm_abt = [&](const float* A, int lda, const float* B, int ldb, float* C, int ldc,
                      int M, int N, int K, float scale){
    dim3 g((N+63)/64, (M+63)/64);
    gemm_abt_f<<<g, B256, 0, stream>>>(A, lda, B, ldb, C, ldc, M, N, K, scale);
  };
  auto gemv = [&](const float* in, int K, const float* W, int ldw, const float* b,
                  float* o, int N, int act){
    int nk = (K + 79) / 80; if (nk > 20) nk = 20; if (nk < 1) nk = 1;
    k_gemv_ks<<<dim3((N+63)/64, nk), B256, 0, stream>>>(in, K, W, ldw, GT, N);
    k_gemv_fin<<<dim3((N+255)/256), B256, 0, stream>>>(GT, nk, b, o, N, act);
  };

  /* ---- edge CSR ---- */
  hipMemsetAsync(cnt, 0, 8192*4, stream);
  hipMemsetAsync(cnt2, 0, 8192*4, stream);
  k_edge_pre<<<dim3(NEDGE/256), B256, 0, stream>>>(e_src, e_dst, edg, esr, erl, cnt);
  k_scan<<<dim3(1), dim3(1024), 0, stream>>>(cnt, coff);
  k_scatter<<<dim3(NEDGE/256), B256, 0, stream>>>(edg, coff, cnt2, csr);

  /* ---- inputs -> X ---- */
  for (int t=0;t<5;t++)
    hipMemcpyAsync(X + (size_t)h_OFFS[t]*384, xin[t], (size_t)h_NT[t]*384*4,
                   hipMemcpyDeviceToDevice, stream);

  /* ---- HGT layers ---- */
  for (int l=0;l<2;l++){
    for (int t=0;t<5;t++)
      gemm(X + (size_t)h_OFFS[t]*384, 384, Wkqv + (size_t)(l*5+t)*442368, 1152,
           bkqv + (size_t)(l*5+t)*1152, nullptr, nullptr, 1.f,
           KQV + (size_t)h_OFFS[t]*1152, 1152, h_NT[t], 1152, 384, 0, 0);
    gemm_rel<<<dim3(2,32,64), B256, 0, stream>>>(
        KQV, krel + (size_t)l*294912, vrel + (size_t)l*294912, KE, VE);
    k_escore<<<dim3(NEDGE/4), B256, 0, stream>>>(KQV, KE, edg, esr, erl, prel + (size_t)l*32, EA);
    hipMemsetAsync(EMX, 0, 8192*4*4, stream);
    hipMemsetAsync(EDEN, 0, 8192*4*4, stream);
    k_segmax<<<dim3(NEDGE*4/256), B256, 0, stream>>>(EA, edg, EMX);
    k_expsum<<<dim3(NEDGE*4/256), B256, 0, stream>>>(EA, edg, EMX, EDEN);
    k_agg<<<dim3(NTOT), dim3(128), 0, stream>>>(EA, VE, EDEN, csr, coff, esr, AGG);
    for (int t=0;t<5;t++)
      gemm(AGG + (size_t)h_OFFS[t]*384, 384, Wout + (size_t)(l*5+t)*147456, 384,
           bout + (size_t)(l*5+t)*384, nullptr, nullptr, 1.f,
           OWT + (size_t)h_OFFS[t]*384, 384, h_NT[t], 384, 384, 0, 1 /*gelu on A*/);
    k_gateln<<<dim3(NTOT), dim3(128), 0, stream>>>(OWT, X, skp + l*5, lng, lnb);
  }

  const float* user_h   = X;
  const float* ai_h     = X + (size_t)2048*384;
  const float* stance_h = X + (size_t)4096*384;
  const float* belief_h = X + (size_t)7168*384;

  /* ---- hs, xg ---- */
  gemm(stance_h, 384, sp_W, 384, sp_b, nullptr, nullptr, 1.f, TMPA, 384, 2048, 384, 384, 0, 0);
  k_lnrow<<<dim3(2048), dim3(128), 0, stream>>>(TMPA, HS, sp_lng, sp_lnb, 0 /*gelu*/);
  gemm(HS, 384, fc0_W, 384, fc0_b, bn_g, bn_b, BNCONST, XG, 384, 2048, 384, 384, 1 /*relu*/, 0);

  /* ---- linear-attention blocks ---- */
  for (int i=0;i<2;i++){
    gemm(XG, 384, tq_W + (size_t)i*589824, 1536, tq_b + (size_t)i*1536, nullptr, nullptr, 1.f,
         QB, 1536, 2048, 1536, 384, 0, 0);
    gemm(XG, 384, tk_W + (size_t)i*589824, 1536, tk_b + (size_t)i*1536, nullptr, nullptr, 1.f,
         KB, 1536, 2048, 1536, 384, 0, 0);
    gemm(XG, 384, tv_W + (size_t)i*589824, 1536, tv_b + (size_t)i*1536, nullptr, nullptr, 1.f,
         VB, 1536, 2048, 1536, 384, 0, 0);
    hipMemsetAsync(SQSK, 0, 8, stream);
    k_sumsq<<<dim3(512), B256, 0, stream>>>(QB, 2048*1536, SQSK);
    k_sumsq<<<dim3(512), B256, 0, stream>>>(KB, 2048*1536, SQSK+1);
    hipMemsetAsync(KSUM, 0, 1536*4, stream);
    k_colsum<<<dim3(6,8), B256, 0, stream>>>(KB, 2048, 1536, 1.0f, KSUM);
    k_dnm<<<dim3(2048), B256, 0, stream>>>(QB, KSUM, SQSK, DNM);
    hipMemsetAsync(KVS, 0, (size_t)4*147456*4, stream);
    gemm_atb_ks<<<dim3(6,6,32), B256, 0, stream>>>(KB, 1536, VB, 1536, KVS, 384,
        384, 384, 2048, 384, 384, 147456, 8);
    for (int h=0;h<4;h++)
      gemm(QB + h*384, 1536, KVS + (size_t)h*147456, 384, nullptr, nullptr, nullptr, 1.f,
           ZNUM + h*384, 1536, 2048, 384, 384, 0, 0);
    k_zcomb<<<dim3(3072), B256, 0, stream>>>(ZNUM, VB, DNM, SQSK, XG,
        bn_g + (size_t)(i+1)*384, bn_b + (size_t)(i+1)*384);
  }

  /* ---- h_mixed ---- */
  k_mix<<<dim3(3072), B256, 0, stream>>>(HS, XG, HM, 2048*384, 0.7f, 0.3f);

  /* ---- MHA helper ---- */
  auto run_mha = [&](const float* qin, int nq, const float* kvin, int nkv, int mi, float* OUT){
    const float* Wq = mWqkv + (size_t)mi*442368;
    const float* bq = mbqkv + (size_t)mi*1152;
    gemm(qin, 384, Wq, 1152, bq, nullptr, nullptr, 1.f, MQKV, 1152, nq, 384, 384, 0, 0);
    gemm(kvin, 384, Wq + 384, 1152, bq + 384, nullptr, nullptr, 1.f, MQKV + 384, 1152, nkv, 768, 384, 0, 0);
    hipMemsetAsync(AO, 0, (size_t)nq*384*4, stream);
    int nch = (nkv + 255)/256;
    for (int h=0;h<4;h++){
      gemm_abt(MQKV + h*96, 1152, MQKV + 384 + h*96, 1152, SSC, nkv, nq, nkv, 96, ISQ96);
      k_softmax<<<dim3(nq), B256, 0, stream>>>(SSC, nkv);
      gemm_nn_ks<<<dim3(2, (nq+63)/64, nch), B256, 0, stream>>>(
          SSC, nkv, MQKV + 768 + h*96, 1152, AO + h*96, 384, nq, 96, nkv, 1.0f);
    }
    gemm(AO, 384, mWo + (size_t)mi*147456, 384, mbo + (size_t)mi*384,
         nullptr, nullptr, 1.f, OUT, 384, nq, 384, 384, 0, 0);
  };

  /* ---- traj ---- */
  run_mha(HM, 2048, HM, 2048, 1, TRAJ);
  hipMemsetAsync(TRAJSUM, 0, 576*4, stream);
  k_colsum<<<dim3(2,8), B256, 0, stream>>>(TRAJ, 2048, 384, 1.0f/2048.0f, TRAJSUM);

  /* ---- conv path ---- */
  k_conv3<<<dim3(64,6), B256, 0, stream>>>(HM, c1W, c1b, C1O, 384, 384);
  k_conv3<<<dim3(64,3), B256, 0, stream>>>(C1O, c2W, c2b, C2O, 384, 192);
  k_colsum<<<dim3(1,8), B256, 0, stream>>>(C2O, 2048, 192, 1.0f/2048.0f, DECAYSUM);

  /* ---- traj_emb ---- */
  gemv(TRAJSUM, 576, opW, 384, opb, TEMB, 384, 0);

  /* ---- ai_ctx ---- */
  run_mha(ai_h, 2048, user_h, 2048, 0, AICTX);
  hipMemsetAsync(AIPOOL, 0, 384*4, stream);
  k_colsum<<<dim3(2,8), B256, 0, stream>>>(AICTX, 2048, 384, 1.0f/2048.0f, AIPOOL);

  /* ---- pscores ---- */
  k_comb<<<dim3(6144), B256, 0, stream>>>(ai_h, user_h, CB);
  gemm(CB, 768, as1W, 384, as1b, nullptr, nullptr, 1.f, PT, 384, 2048, 384, 768, 1, 0);
  k_rowdot<<<dim3(512), B256, 0, stream>>>(PT, 384, 384, as2W, as2b, out + 2 + 2048, 2048);

  /* ---- bctx ---- */
  run_mha(ai_h, 2048, belief_h, 1024, 2, TRAJ);
  hipMemsetAsync(BCTXV, 0, 384*4, stream);
  k_colsum<<<dim3(2,8), B256, 0, stream>>>(TRAJ, 2048, 384, 1.0f/2048.0f, BCTXV);

  /* ---- stance delta ---- */
  hipMemcpyAsync(SDIN, stance_h, 384*4, hipMemcpyDeviceToDevice, stream);
  hipMemcpyAsync(SDIN + 384, stance_h + (size_t)2047*384, 384*4, hipMemcpyDeviceToDevice, stream);
  gemv(SDIN, 768, sc1W, 384, sc1b, T1, 384, 1);
  gemv(T1, 384, sc2W, 192, sc2b, SDELT, 192, 0);

  /* ---- classifier ---- */
  gemv(TEMB, 1344, cl1W, 384, cl1b, Z1, 384, 0);
  k_lnrow<<<dim3(1), dim3(128), 0, stream>>>(Z1, Zb, cllng, cllnb, 1 /*relu*/);
  gemv(Zb, 384, cl2W, 192, cl2b, Z2, 192, 1);
  k_final<<<dim3(1), dim3(64), 0, stream>>>(Z2, cl3W, cl3b, out);

  /* ---- per_turn ---- */
  k_rowdot<<<dim3(512), B256, 0, stream>>>(AICTX, 384, 384, tpW, tpb, out + 2, 2048);
}

// Round 9
// 3490.166 us; speedup vs baseline: 7.3952x; 1.1354x over previous
//
#include <hip/hip_runtime.h>
#include <hip/hip_bf16.h>

#define NEDGE 229376
#define NTOT  8192
#define BNCONST 0.9999950000374997f   /* 1/sqrt(1+1e-5) */
#define ISQ96   0.10206207261596575f  /* 1/sqrt(96) */

__constant__ int c_NT[5]     = {2048,2048,2048,1024,1024};
__constant__ int c_OFFS[5]   = {0,2048,4096,6144,7168};
__constant__ int c_ESRC[8]   = {0,1,1,2,0,3,1,4};
__constant__ int c_EDST[8]   = {1,0,2,2,3,1,4,2};
__constant__ int c_EOFF[9]   = {0,32768,65536,98304,131072,147456,180224,196608,229376};
__constant__ int c_RELROW[8] = {0,2048,4096,6144,8192,10240,11264,13312};

static const int h_NT[5]   = {2048,2048,2048,1024,1024};
static const int h_OFFS[5] = {0,2048,4096,6144,7168};

__device__ inline float gelu_f(float x){ return 0.5f*x*(1.0f+erff(x*0.70710678118654752f)); }
__device__ inline float sigm(float x){ return 1.0f/(1.0f+expf(-x)); }
__device__ inline float wsum64(float v){
  #pragma unroll
  for (int s=32;s>0;s>>=1) v += __shfl_xor(v, s, 64);
  return v;
}
__device__ inline unsigned encf(float f){
  unsigned b = __float_as_uint(f);
  return (b & 0x80000000u) ? ~b : (b | 0x80000000u);
}
__device__ inline float decf(unsigned u){
  unsigned b = (u & 0x80000000u) ? (u & 0x7FFFFFFFu) : ~u;
  return __uint_as_float(b);
}
__device__ inline int row_type(int row){
  return (row<2048)?0:((row<4096)?1:((row<6144)?2:((row<7168)?3:4)));
}
/* reduce across the 16-lane row group (lanes ty*16..+15) */
__device__ inline float rgmax(float v){
  v = fmaxf(v, __shfl_xor(v, 1, 64));
  v = fmaxf(v, __shfl_xor(v, 2, 64));
  v = fmaxf(v, __shfl_xor(v, 4, 64));
  v = fmaxf(v, __shfl_xor(v, 8, 64));
  return v;
}
__device__ inline float rgsum(float v){
  v += __shfl_xor(v, 1, 64);
  v += __shfl_xor(v, 2, 64);
  v += __shfl_xor(v, 4, 64);
  v += __shfl_xor(v, 8, 64);
  return v;
}

/* ---------------- simple utility kernels ---------------- */

__global__ void k_mix(const float* __restrict__ a, const float* __restrict__ b,
                      float* __restrict__ c, int n, float fa, float fb){
  int i = blockIdx.x*256 + threadIdx.x;
  if (i < n) c[i] = fa*a[i] + fb*b[i];
}

__global__ void k_comb(const float* __restrict__ ai, const float* __restrict__ user,
                       float* __restrict__ cb){
  int i = blockIdx.x*256 + threadIdx.x;
  if (i >= 2048*768) return;
  int n = i / 768, c = i - n*768;
  cb[i] = (c < 384) ? ai[n*384 + c] : user[n*384 + (c-384)];
}

/* ---------------- edge preprocessing (CSR by destination) ---------------- */

__global__ void k_edge_pre(const int* __restrict__ esrc, const int* __restrict__ edst,
                           int* edg, int* esr, int* erl, int* cnt){
  int e = blockIdx.x*256 + threadIdx.x;
  if (e >= NEDGE) return;
  int r = 0;
  #pragma unroll
  for (int q=1;q<8;q++) if (e >= c_EOFF[q]) r = q;
  int dg = c_OFFS[c_EDST[r]] + edst[e];
  edg[e] = dg;
  esr[e] = c_RELROW[r] + esrc[e];
  erl[e] = r;
  atomicAdd(&cnt[dg], 1);
}

__global__ __launch_bounds__(1024) void k_scan(const int* __restrict__ cnt, int* __restrict__ off){
  __shared__ int sh[1024];
  int tid = threadIdx.x;
  int base = tid*8;
  int loc[8]; int run = 0;
  #pragma unroll
  for (int i=0;i<8;i++){ loc[i] = run; run += cnt[base+i]; }
  sh[tid] = run;
  __syncthreads();
  for (int d=1; d<1024; d<<=1){
    int v = (tid >= d) ? sh[tid-d] : 0;
    __syncthreads();
    sh[tid] += v;
    __syncthreads();
  }
  int pre = (tid==0) ? 0 : sh[tid-1];
  #pragma unroll
  for (int i=0;i<8;i++) off[base+i] = pre + loc[i];
  if (tid==1023) off[8192] = sh[1023];
}

__global__ void k_scatter(const int* __restrict__ edg, const int* __restrict__ off,
                          int* cnt2, int* csr){
  int e = blockIdx.x*256 + threadIdx.x;
  if (e >= NEDGE) return;
  int dg = edg[e];
  int pos = off[dg] + atomicAdd(&cnt2[dg], 1);
  csr[pos] = e;
}

/* ------- tiled GEMMs: 64x64 tile, 4x4 microtile, double-buffered + float4 stage ------- */

__global__ __launch_bounds__(256) void gemm_f(
    const float* __restrict__ A, int lda, const float* __restrict__ B, int ldb,
    const float* __restrict__ bias, const float* __restrict__ cs, const float* __restrict__ csh,
    float kmul, float* __restrict__ C, int ldc, int M, int N, int K, int act, int agelu)
{
  __shared__ float As[2][16][68];
  __shared__ float Bs[2][16][68];
  int tid = threadIdx.x;
  int tx = tid & 15, ty = tid >> 4;
  int am = tid >> 2, ak = (tid & 3) * 4;
  int bk = tid >> 4, bn = (tid & 15) * 4;
  int m0 = blockIdx.y * 64, n0 = blockIdx.x * 64;
  int gmA = m0 + am;
  int gnB = n0 + bn;
  int ntiles = K >> 4;
  float4 ra, rb;
  float acc[4][4] = {};

  auto fetch = [&](int kk){
    if (gmA < M){
      ra = *reinterpret_cast<const float4*>(&A[(size_t)gmA*lda + kk + ak]);
      if (agelu){ ra.x=gelu_f(ra.x); ra.y=gelu_f(ra.y); ra.z=gelu_f(ra.z); ra.w=gelu_f(ra.w); }
    } else ra = make_float4(0.f,0.f,0.f,0.f);
    if (gnB + 3 < N){
      rb = *reinterpret_cast<const float4*>(&B[(size_t)(kk + bk)*ldb + gnB]);
    } else {
      rb.x = (gnB   < N) ? B[(size_t)(kk + bk)*ldb + gnB  ] : 0.f;
      rb.y = (gnB+1 < N) ? B[(size_t)(kk + bk)*ldb + gnB+1] : 0.f;
      rb.z = (gnB+2 < N) ? B[(size_t)(kk + bk)*ldb + gnB+2] : 0.f;
      rb.w = (gnB+3 < N) ? B[(size_t)(kk + bk)*ldb + gnB+3] : 0.f;
    }
  };
  auto stage = [&](int b){
    As[b][ak  ][am] = ra.x;
    As[b][ak+1][am] = ra.y;
    As[b][ak+2][am] = ra.z;
    As[b][ak+3][am] = ra.w;
    *reinterpret_cast<float4*>(&Bs[b][bk][bn]) = rb;
  };

  fetch(0);
  stage(0);
  __syncthreads();
  for (int t = 0; t < ntiles; t++){
    int cur = t & 1;
    if (t + 1 < ntiles) fetch((t+1) << 4);
    #pragma unroll
    for (int k = 0; k < 16; k++) {
      float4 a4 = *reinterpret_cast<const float4*>(&As[cur][k][ty*4]);
      float4 b4 = *reinterpret_cast<const float4*>(&Bs[cur][k][tx*4]);
      float a[4] = {a4.x, a4.y, a4.z, a4.w};
      float b[4] = {b4.x, b4.y, b4.z, b4.w};
      #pragma unroll
      for (int i=0;i<4;i++)
        #pragma unroll
        for (int j=0;j<4;j++) acc[i][j] += a[i]*b[j];
    }
    if (t + 1 < ntiles) stage(cur ^ 1);
    __syncthreads();
  }
  #pragma unroll
  for (int i=0;i<4;i++){
    int gm = m0 + ty*4 + i; if (gm >= M) continue;
    #pragma unroll
    for (int j=0;j<4;j++){
      int gn = n0 + tx*4 + j; if (gn >= N) continue;
      float v = acc[i][j];
      if (bias) v += bias[gn];
      float s = kmul;
      if (cs) s *= cs[gn];
      v *= s;
      if (csh) v += csh[gn];
      if (act==1) v = fmaxf(v, 0.f);
      else if (act==2) v = gelu_f(v);
      C[(size_t)gm*ldc + gn] = v;
    }
  }
}

/* batched HGT relation projection as GEMM: z = (r*4+h)*2 + w */
__global__ __launch_bounds__(256) void gemm_rel(
    const float* __restrict__ KQV_, const float* __restrict__ krel_l,
    const float* __restrict__ vrel_l, float* __restrict__ KE_, float* __restrict__ VE_)
{
  int z = blockIdx.z;
  int w = z & 1, h = (z >> 1) & 3, r = z >> 3;
  int s = c_ESRC[r];
  int Ns = c_NT[s];
  int m0 = blockIdx.y * 64;
  if (m0 >= Ns) return;
  int n0 = blockIdx.x * 64;
  const float* A = KQV_ + (size_t)c_OFFS[s]*1152 + (w ? 768 : 0) + h*96;
  const float* B = (w ? vrel_l : krel_l) + (size_t)(r*4 + h)*9216;
  float* C = (w ? VE_ : KE_) + (size_t)c_RELROW[r]*384 + h*96;

  __shared__ float As[2][16][68];
  __shared__ float Bs[2][16][68];
  int tid = threadIdx.x;
  int tx = tid & 15, ty = tid >> 4;
  int am = tid >> 2, ak = (tid & 3) * 4;
  int bk = tid >> 4, bn = (tid & 15) * 4;
  int gmA = m0 + am;
  int gnB = n0 + bn;
  float4 ra, rb;
  float acc[4][4] = {};

  auto fetch = [&](int kk){
    ra = (gmA < Ns) ? *reinterpret_cast<const float4*>(&A[(size_t)gmA*1152 + kk + ak])
                    : make_float4(0.f,0.f,0.f,0.f);
    if (gnB + 3 < 96){
      rb = *reinterpret_cast<const float4*>(&B[(size_t)(kk + bk)*96 + gnB]);
    } else {
      rb.x = (gnB   < 96) ? B[(size_t)(kk + bk)*96 + gnB  ] : 0.f;
      rb.y = (gnB+1 < 96) ? B[(size_t)(kk + bk)*96 + gnB+1] : 0.f;
      rb.z = (gnB+2 < 96) ? B[(size_t)(kk + bk)*96 + gnB+2] : 0.f;
      rb.w = (gnB+3 < 96) ? B[(size_t)(kk + bk)*96 + gnB+3] : 0.f;
    }
  };
  auto stage = [&](int b){
    As[b][ak  ][am] = ra.x;
    As[b][ak+1][am] = ra.y;
    As[b][ak+2][am] = ra.z;
    As[b][ak+3][am] = ra.w;
    *reinterpret_cast<float4*>(&Bs[b][bk][bn]) = rb;
  };

  fetch(0);
  stage(0);
  __syncthreads();
  for (int t = 0; t < 6; t++){
    int cur = t & 1;
    if (t + 1 < 6) fetch((t+1) << 4);
    #pragma unroll
    for (int k = 0; k < 16; k++) {
      float4 a4 = *reinterpret_cast<const float4*>(&As[cur][k][ty*4]);
      float4 b4 = *reinterpret_cast<const float4*>(&Bs[cur][k][tx*4]);
      float a[4] = {a4.x, a4.y, a4.z, a4.w};
      float b[4] = {b4.x, b4.y, b4.z, b4.w};
      #pragma unroll
      for (int i=0;i<4;i++)
        #pragma unroll
        for (int j=0;j<4;j++) acc[i][j] += a[i]*b[j];
    }
    if (t + 1 < 6) stage(cur ^ 1);
    __syncthreads();
  }
  #pragma unroll
  for (int i=0;i<4;i++){
    int gm = m0 + ty*4 + i; if (gm >= Ns) continue;
    #pragma unroll
    for (int j=0;j<4;j++){
      int gn = n0 + tx*4 + j; if (gn >= 96) continue;
      C[(size_t)gm*384 + gn] = acc[i][j];
    }
  }
}

// C[m,n] += sum_l A[l,m]*B[l,n], head-batched + L-split (atomic accumulate).
__global__ __launch_bounds__(256) void gemm_atb_ks(
    const float* __restrict__ A0, int lda, const float* __restrict__ B0, int ldb,
    float* __restrict__ C0, int ldc, int M, int N, int L,
    int hsA, int hsB, int hsC, int nch)
{
  __shared__ float As[2][16][68];
  __shared__ float Bs[2][16][68];
  int h = blockIdx.z / nch, c = blockIdx.z % nch;
  const float* A = A0 + (size_t)h*hsA;
  const float* B = B0 + (size_t)h*hsB;
  float* C = C0 + (size_t)h*hsC;
  int l0 = c*256;
  int tid = threadIdx.x;
  int tx = tid & 15, ty = tid >> 4;
  int sl = tid >> 4, sq = (tid & 15) * 4;
  int m0 = blockIdx.y * 64, n0 = blockIdx.x * 64;
  int gmA = m0 + sq, gnB = n0 + sq;
  int ntiles = 16;
  float4 ra, rb;
  float acc[4][4] = {};

  auto fetch = [&](int ll){
    if (gmA + 3 < M){
      ra = *reinterpret_cast<const float4*>(&A[(size_t)(ll + sl)*lda + gmA]);
    } else {
      ra.x = (gmA   < M) ? A[(size_t)(ll + sl)*lda + gmA  ] : 0.f;
      ra.y = (gmA+1 < M) ? A[(size_t)(ll + sl)*lda + gmA+1] : 0.f;
      ra.z = (gmA+2 < M) ? A[(size_t)(ll + sl)*lda + gmA+2] : 0.f;
      ra.w = (gmA+3 < M) ? A[(size_t)(ll + sl)*lda + gmA+3] : 0.f;
    }
    if (gnB + 3 < N){
      rb = *reinterpret_cast<const float4*>(&B[(size_t)(ll + sl)*ldb + gnB]);
    } else {
      rb.x = (gnB   < N) ? B[(size_t)(ll + sl)*ldb + gnB  ] : 0.f;
      rb.y = (gnB+1 < N) ? B[(size_t)(ll + sl)*ldb + gnB+1] : 0.f;
      rb.z = (gnB+2 < N) ? B[(size_t)(ll + sl)*ldb + gnB+2] : 0.f;
      rb.w = (gnB+3 < N) ? B[(size_t)(ll + sl)*ldb + gnB+3] : 0.f;
    }
  };
  auto stage = [&](int b){
    *reinterpret_cast<float4*>(&As[b][sl][sq]) = ra;
    *reinterpret_cast<float4*>(&Bs[b][sl][sq]) = rb;
  };

  fetch(l0);
  stage(0);
  __syncthreads();
  for (int t = 0; t < ntiles; t++){
    int cur = t & 1;
    if (t + 1 < ntiles) fetch(l0 + ((t+1) << 4));
    #pragma unroll
    for (int l = 0; l < 16; l++) {
      float4 a4 = *reinterpret_cast<const float4*>(&As[cur][l][ty*4]);
      float4 b4 = *reinterpret_cast<const float4*>(&Bs[cur][l][tx*4]);
      float a[4] = {a4.x, a4.y, a4.z, a4.w};
      float b[4] = {b4.x, b4.y, b4.z, b4.w};
      #pragma unroll
      for (int i=0;i<4;i++)
        #pragma unroll
        for (int j=0;j<4;j++) acc[i][j] += a[i]*b[j];
    }
    if (t + 1 < ntiles) stage(cur ^ 1);
    __syncthreads();
  }
  #pragma unroll
  for (int i=0;i<4;i++){
    int gm = m0 + ty*4 + i; if (gm >= M) continue;
    #pragma unroll
    for (int j=0;j<4;j++){
      int gn = n0 + tx*4 + j; if (gn >= N) continue;
      atomicAdd(&C[(size_t)gm*ldc + gn], acc[i][j]);
    }
  }
}

/* ---------------- flash attention: q-tile 64, kv-tile 32, kv-chunk 512 ---------------- */
/* grid (nq/64, 4 heads, nkv/512); MQKV layout row*1152: Q[0..383] K[384..767] V[768..1151] */
__global__ __launch_bounds__(256) void fa_kernel(
    const float* __restrict__ MQ, int nq, float* __restrict__ OP, float* __restrict__ ML)
{
  __shared__ float Qs[96][68];
  __shared__ float Ksf[96][36];
  __shared__ float Vs[32][104];
  __shared__ float Ps[64][36];
  int tid = threadIdx.x;
  int tx = tid & 15, ty = tid >> 4;
  int q0 = blockIdx.x * 64;
  int h = blockIdx.y;
  int z = blockIdx.z, nch = gridDim.z;
  int kvbase = z * 512;

  /* stage Q tile [k][r] */
  #pragma unroll
  for (int i = 0; i < 6; i++){
    int e = tid + i*256;
    int r = e & 63, kq = (e >> 6) * 4;
    float4 f = *reinterpret_cast<const float4*>(&MQ[(size_t)(q0+r)*1152 + h*96 + kq]);
    Qs[kq  ][r] = f.x;
    Qs[kq+1][r] = f.y;
    Qs[kq+2][r] = f.z;
    Qs[kq+3][r] = f.w;
  }

  float m_i[4], l_i[4], acc[4][6];
  #pragma unroll
  for (int i=0;i<4;i++){
    m_i[i] = -3.0e38f; l_i[i] = 0.f;
    #pragma unroll
    for (int c=0;c<6;c++) acc[i][c] = 0.f;
  }
  int c0 = tx*6;
  __syncthreads();

  for (int t = 0; t < 16; t++){
    int kv0 = kvbase + t*32;
    /* stage K tile [k][n] and V tile [n][c] */
    #pragma unroll
    for (int i = 0; i < 3; i++){
      int e = tid + i*256;
      int n = e & 31, kq = (e >> 5) * 4;
      float4 f = *reinterpret_cast<const float4*>(&MQ[(size_t)(kv0+n)*1152 + 384 + h*96 + kq]);
      Ksf[kq  ][n] = f.x;
      Ksf[kq+1][n] = f.y;
      Ksf[kq+2][n] = f.z;
      Ksf[kq+3][n] = f.w;
      int nv = e / 24, cq = (e - nv*24) * 4;
      float4 g = *reinterpret_cast<const float4*>(&MQ[(size_t)(kv0+nv)*1152 + 768 + h*96 + cq]);
      *reinterpret_cast<float4*>(&Vs[nv][cq]) = g;
    }
    __syncthreads();

    /* S = Q @ K^T (64x32), thread: rows ty*4..+3, kv cols tx*2..+1 */
    float s0[4] = {0,0,0,0}, s1[4] = {0,0,0,0};
    #pragma unroll 8
    for (int k = 0; k < 96; k++){
      float4 a4 = *reinterpret_cast<const float4*>(&Qs[k][ty*4]);
      float2 b2 = *reinterpret_cast<const float2*>(&Ksf[k][tx*2]);
      s0[0] += a4.x*b2.x; s1[0] += a4.x*b2.y;
      s0[1] += a4.y*b2.x; s1[1] += a4.y*b2.y;
      s0[2] += a4.z*b2.x; s1[2] += a4.z*b2.y;
      s0[3] += a4.w*b2.x; s1[3] += a4.w*b2.y;
    }
    /* online softmax per row */
    #pragma unroll
    for (int i=0;i<4;i++){
      float a = s0[i]*ISQ96, b = s1[i]*ISQ96;
      float rm = rgmax(fmaxf(a, b));
      float mn = fmaxf(m_i[i], rm);
      float alpha = expf(m_i[i] - mn);
      float p0 = expf(a - mn), p1 = expf(b - mn);
      float rs = rgsum(p0 + p1);
      l_i[i] = l_i[i]*alpha + rs;
      m_i[i] = mn;
      #pragma unroll
      for (int c=0;c<6;c++) acc[i][c] *= alpha;
      Ps[ty*4+i][tx*2  ] = p0;
      Ps[ty*4+i][tx*2+1] = p1;
    }
    __syncthreads();
    /* O += P @ V : thread rows ty*4..+3, cols c0..c0+5 */
    for (int kv = 0; kv < 32; kv++){
      float2 v01 = *reinterpret_cast<const float2*>(&Vs[kv][c0]);
      float2 v23 = *reinterpret_cast<const float2*>(&Vs[kv][c0+2]);
      float2 v45 = *reinterpret_cast<const float2*>(&Vs[kv][c0+4]);
      #pragma unroll
      for (int i=0;i<4;i++){
        float p = Ps[ty*4+i][kv];
        acc[i][0] += p*v01.x; acc[i][1] += p*v01.y;
        acc[i][2] += p*v23.x; acc[i][3] += p*v23.y;
        acc[i][4] += p*v45.x; acc[i][5] += p*v45.y;
      }
    }
    __syncthreads();
  }

  /* write unnormalized partials */
  size_t base = ((size_t)(h*nch + z)*nq + q0);
  #pragma unroll
  for (int i=0;i<4;i++){
    size_t row = base + ty*4 + i;
    #pragma unroll
    for (int c=0;c<6;c++) OP[row*96 + c0 + c] = acc[i][c];
    if (tx == 0){
      ML[row*2  ] = m_i[i];
      ML[row*2+1] = l_i[i];
    }
  }
}

__global__ void k_famerge(const float* __restrict__ OP, const float* __restrict__ ML,
                          float* __restrict__ AO_, int nq, int nch){
  int e = blockIdx.x*256 + threadIdx.x;
  int total = 4*nq*96;
  if (e >= total) return;
  int c = e % 96;
  int q = (e / 96) % nq;
  int h = e / (96*nq);
  float M = -3.0e38f;
  for (int z = 0; z < nch; z++)
    M = fmaxf(M, ML[((size_t)(h*nch+z)*nq + q)*2]);
  float L = 0.f, O = 0.f;
  for (int z = 0; z < nch; z++){
    size_t row = (size_t)(h*nch+z)*nq + q;
    float w = expf(ML[row*2] - M);
    L += ML[row*2+1]*w;
    O += OP[row*96 + c]*w;
  }
  AO_[(size_t)q*384 + h*96 + c] = O / L;
}

/* ---------------- conv1d as im2col + GEMM ---------------- */
/* imcol[p][ic*3+j] = in[p-1+j][ic] (0-pad); matches per-ic j-inner accumulation order */
__global__ void k_im2col(const float* __restrict__ in, float* __restrict__ imc){
  int e = blockIdx.x*256 + threadIdx.x;
  if (e >= 2048*1152) return;
  int p = e / 1152, k = e - p*1152;
  int ic = k / 3, j = k - ic*3;
  int gp = p - 1 + j;
  imc[e] = (gp >= 0 && gp < 2048) ? in[(size_t)gp*384 + ic] : 0.f;
}
/* WT[k][oc] = W[oc][k], K = 1152 */
__global__ void k_wtr(const float* __restrict__ W, float* __restrict__ WT, int OC){
  int e = blockIdx.x*256 + threadIdx.x;
  if (e >= OC*1152) return;
  int oc = e / 1152, k = e - oc*1152;
  WT[(size_t)k*OC + oc] = W[e];
}

/* ---------------- edge attention ---------------- */

__global__ __launch_bounds__(256) void k_escore(
    const float* __restrict__ KQV_, const float* __restrict__ KE_,
    const int* __restrict__ edg, const int* __restrict__ esr, const int* __restrict__ erl,
    const float* __restrict__ prel_l, float* __restrict__ EA)
{
  int e = blockIdx.x*4 + (threadIdx.x>>6);
  if (e >= NEDGE) return;
  int lane = threadIdx.x & 63;
  int h = lane >> 4, j = lane & 15;
  int dg = edg[e], sr = esr[e], r = erl[e];
  const float* q  = KQV_ + (size_t)dg*1152 + 384 + h*96;
  const float* ke = KE_  + (size_t)sr*384 + h*96;
  float p = 0.f;
  #pragma unroll
  for (int t=0;t<6;t++){ int d = j + t*16; p += q[d]*ke[d]; }
  p += __shfl_xor(p, 1, 64);
  p += __shfl_xor(p, 2, 64);
  p += __shfl_xor(p, 4, 64);
  p += __shfl_xor(p, 8, 64);
  if (j == 0) EA[(size_t)e*4 + h] = p * prel_l[r*4+h] * ISQ96;
}

__global__ void k_segmax(const float* __restrict__ EA, const int* __restrict__ edg,
                         unsigned* __restrict__ EMX){
  int i = blockIdx.x*256 + threadIdx.x;
  if (i >= NEDGE*4) return;
  int e = i >> 2, h = i & 3;
  atomicMax(&EMX[edg[e]*4 + h], encf(EA[i]));
}

__global__ void k_expsum(float* __restrict__ EA, const int* __restrict__ edg,
                         const unsigned* __restrict__ EMX, float* __restrict__ EDEN){
  int i = blockIdx.x*256 + threadIdx.x;
  if (i >= NEDGE*4) return;
  int e = i >> 2, h = i & 3;
  int dg = edg[e];
  float m = decf(EMX[dg*4 + h]);
  float ex = expf(EA[i] - m);
  EA[i] = ex;
  atomicAdd(&EDEN[dg*4 + h], ex);
}

__global__ __launch_bounds__(128) void k_agg(
    const float* __restrict__ EA, const float* __restrict__ VE_,
    const float* __restrict__ EDEN, const int* __restrict__ csr,
    const int* __restrict__ off, const int* __restrict__ esr, float* __restrict__ AGG)
{
  int node = blockIdx.x, tid = threadIdx.x;
  int b = off[node], e1 = off[node+1];
  int d0 = tid, d1 = tid+128, d2 = tid+256;
  int h0 = d0/96, h1 = d1/96, h2 = d2/96;
  float a0=0.f, a1=0.f, a2=0.f;
  if (e1 > b){
    float i0 = 1.0f/EDEN[node*4+h0];
    float i1 = 1.0f/EDEN[node*4+h1];
    float i2 = 1.0f/EDEN[node*4+h2];
    for (int p=b; p<e1; p++){
      int e = csr[p];
      const float* ve = VE_ + (size_t)esr[e]*384;
      const float* ea = EA + (size_t)e*4;
      a0 += ea[h0]*i0*ve[d0];
      a1 += ea[h1]*i1*ve[d1];
      a2 += ea[h2]*i2*ve[d2];
    }
  }
  AGG[(size_t)node*384 + d0] = a0;
  AGG[(size_t)node*384 + d1] = a1;
  AGG[(size_t)node*384 + d2] = a2;
}

/* ---------------- row-wise norm kernels ---------------- */

__global__ __launch_bounds__(128) void k_gateln(
    const float* __restrict__ O, float* __restrict__ X,
    const float* __restrict__ skip_l, const float* __restrict__ lng, const float* __restrict__ lnb)
{
  __shared__ float red[2];
  int row = blockIdx.x, tid = threadIdx.x;
  int t = row_type(row);
  float gt = sigm(skip_l[t]);
  const float* o = O + (size_t)row*384;
  float* x = X + (size_t)row*384;
  float v0 = gelu_f(gt*o[tid]     + (1.f-gt)*x[tid]);
  float v1 = gelu_f(gt*o[tid+128] + (1.f-gt)*x[tid+128]);
  float v2 = gelu_f(gt*o[tid+256] + (1.f-gt)*x[tid+256]);
  int lane = tid & 63, wid = tid >> 6;
  float s = wsum64(v0+v1+v2);
  if (lane==0) red[wid] = s;
  __syncthreads();
  float mean = (red[0]+red[1]) * (1.0f/384.0f);
  __syncthreads();
  float d0=v0-mean, d1=v1-mean, d2=v2-mean;
  float q = wsum64(d0*d0+d1*d1+d2*d2);
  if (lane==0) red[wid] = q;
  __syncthreads();
  float var = (red[0]+red[1]) * (1.0f/384.0f);
  float rs = 1.0f/sqrtf(var + 1e-5f);
  const float* g = lng + (size_t)t*384;
  const float* b = lnb + (size_t)t*384;
  x[tid]     = d0*rs*g[tid]     + b[tid];
  x[tid+128] = d1*rs*g[tid+128] + b[tid+128];
  x[tid+256] = d2*rs*g[tid+256] + b[tid+256];
}

__global__ __launch_bounds__(128) void k_lnrow(
    const float* __restrict__ X, float* __restrict__ Y,
    const float* __restrict__ g, const float* __restrict__ b, int act)
{
  __shared__ float red[2];
  int row = blockIdx.x, tid = threadIdx.x;
  const float* x = X + (size_t)row*384;
  float* y = Y + (size_t)row*384;
  float v0 = x[tid], v1 = x[tid+128], v2 = x[tid+256];
  int lane = tid & 63, wid = tid >> 6;
  float s = wsum64(v0+v1+v2);
  if (lane==0) red[wid] = s;
  __syncthreads();
  float mean = (red[0]+red[1]) * (1.0f/384.0f);
  __syncthreads();
  float d0=v0-mean, d1=v1-mean, d2=v2-mean;
  float q = wsum64(d0*d0+d1*d1+d2*d2);
  if (lane==0) red[wid] = q;
  __syncthreads();
  float var = (red[0]+red[1]) * (1.0f/384.0f);
  float rs = 1.0f/sqrtf(var + 1e-5f);
  float u0 = d0*rs*g[tid]     + b[tid];
  float u1 = d1*rs*g[tid+128] + b[tid+128];
  float u2 = d2*rs*g[tid+256] + b[tid+256];
  if (act==1){ u0=fmaxf(u0,0.f); u1=fmaxf(u1,0.f); u2=fmaxf(u2,0.f); }
  else       { u0=gelu_f(u0); u1=gelu_f(u1); u2=gelu_f(u2); }
  y[tid] = u0; y[tid+128] = u1; y[tid+256] = u2;
}

/* ---------------- reductions / misc ---------------- */

__global__ __launch_bounds__(256) void k_sumsq(const float* __restrict__ x, int n, float* out){
  __shared__ float red[4];
  float s = 0.f;
  for (int i = blockIdx.x*256 + threadIdx.x; i < n; i += gridDim.x*256){ float v=x[i]; s += v*v; }
  s = wsum64(s);
  int lane = threadIdx.x & 63, wid = threadIdx.x >> 6;
  if (lane==0) red[wid] = s;
  __syncthreads();
  if (threadIdx.x==0) atomicAdd(out, red[0]+red[1]+red[2]+red[3]);
}

__global__ void k_colsum(const float* __restrict__ A, int R, int C, float scale,
                         float* __restrict__ out){
  int col = blockIdx.x*256 + threadIdx.x;
  if (col >= C) return;
  int nchunk = gridDim.y;
  int chunk = (R + nchunk - 1)/nchunk;
  int r0 = blockIdx.y*chunk, r1 = min(R, r0+chunk);
  float s = 0.f;
  for (int r=r0; r<r1; r++) s += A[(size_t)r*C + col];
  atomicAdd(&out[col], s*scale);
}

__global__ __launch_bounds__(256) void k_dnm(const float* __restrict__ QB,
    const float* __restrict__ KSUM, const float* __restrict__ sqsk, float* __restrict__ DNM){
  int wv = blockIdx.x*4 + (threadIdx.x>>6);
  int n = wv >> 2, h = wv & 3;
  int lane = threadIdx.x & 63;
  const float* q = QB + (size_t)n*1536 + h*384;
  const float* ks = KSUM + h*384;
  float p = 0.f;
  #pragma unroll
  for (int d=lane; d<384; d+=64) p += q[d]*ks[d];
  p = wsum64(p);
  if (lane==0) DNM[n*4+h] = p * (1.0f/sqrtf(sqsk[0]*sqsk[1])) + 2048.0f;
}

__global__ void k_zcomb(const float* __restrict__ ZN, const float* __restrict__ VB_,
                        const float* __restrict__ DNM_, const float* __restrict__ sqsk,
                        float* __restrict__ XG_,
                        const float* __restrict__ bng, const float* __restrict__ bnb){
  int i = blockIdx.x*256 + threadIdx.x;
  if (i >= 2048*384) return;
  int n = i / 384, c = i - n*384;
  float inv_s = 1.0f/sqrtf(sqsk[0]*sqsk[1]);
  float zm = 0.f;
  #pragma unroll
  for (int h=0;h<4;h++){
    float num = ZN[(size_t)n*1536 + h*384 + c]*inv_s + 2048.0f*VB_[(size_t)n*1536 + h*384 + c];
    zm += num / DNM_[n*4+h];
  }
  zm *= 0.25f;
  float y = 0.5f*zm + 0.5f*XG_[i];
  y = y * (bng[c] * BNCONST) + bnb[c];
  XG_[i] = fmaxf(y, 0.f);
}

/* ---------------- parallel small GEMV: partials + finalize ---------------- */

__global__ __launch_bounds__(256) void k_gemv_ks(
    const float* __restrict__ in, int K, const float* __restrict__ W, int ldw,
    float* __restrict__ tmp, int N)
{
  int c = blockIdx.x*64 + (threadIdx.x & 63);
  int w = threadIdx.x >> 6;
  int kch = blockIdx.y, nk = gridDim.y;
  int k0 = (int)(((long long)K * kch) / nk);
  int k1 = (int)(((long long)K * (kch+1)) / nk);
  float s = 0.f;
  if (c < N){
    for (int k = k0 + w; k < k1; k += 4)
      s += in[k] * W[(size_t)k*ldw + c];
  }
  __shared__ float red[4][64];
  red[w][threadIdx.x & 63] = s;
  __syncthreads();
  if (w == 0 && c < N){
    int l = threadIdx.x & 63;
    tmp[(size_t)kch*N + c] = red[0][l] + red[1][l] + red[2][l] + red[3][l];
  }
}

__global__ void k_gemv_fin(const float* __restrict__ tmp, int nk,
                           const float* __restrict__ b, float* __restrict__ out, int N, int act){
  int c = blockIdx.x*256 + threadIdx.x;
  if (c >= N) return;
  float v = 0.f;
  for (int i = 0; i < nk; i++) v += tmp[(size_t)i*N + c];
  v += b[c];
  if (act==1) v = fmaxf(v, 0.f);
  out[c] = v;
}

__global__ __launch_bounds__(256) void k_rowdot(const float* __restrict__ A, int lda, int K,
    const float* __restrict__ w, const float* __restrict__ b, float* __restrict__ out, int M){
  int r = blockIdx.x*4 + (threadIdx.x>>6);
  if (r >= M) return;
  int lane = threadIdx.x & 63;
  const float* a = A + (size_t)r*lda;
  float p = 0.f;
  for (int k = lane; k < K; k += 64) p += a[k]*w[k];
  p = wsum64(p);
  if (lane==0) out[r] = sigm(p + b[0]);
}

__global__ __launch_bounds__(64) void k_final(const float* __restrict__ z2,
    const float* __restrict__ w, const float* __restrict__ b, float* __restrict__ out){
  int lane = threadIdx.x;
  float p = 0.f;
  for (int k = lane; k < 192; k += 64) p += z2[k]*w[k];
  p = wsum64(p);
  if (lane==0){
    float l = p + b[0];
    out[0] = l;
    out[1] = sigm(l);
  }
}

/* ================================================================ */

extern "C" void kernel_launch(void* const* d_in, const int* in_sizes, int n_in,
                              void* d_out, int out_size, void* d_ws, size_t ws_size,
                              hipStream_t stream)
{
  const float* xin[5] = {(const float*)d_in[0], (const float*)d_in[1], (const float*)d_in[2],
                         (const float*)d_in[3], (const float*)d_in[4]};
  const float* Wkqv=(const float*)d_in[5];  const float* bkqv=(const float*)d_in[6];
  const float* Wout=(const float*)d_in[7];  const float* bout=(const float*)d_in[8];
  const float* krel=(const float*)d_in[9];  const float* vrel=(const float*)d_in[10];
  const float* prel=(const float*)d_in[11]; const float* skp =(const float*)d_in[12];
  const float* lng =(const float*)d_in[13]; const float* lnb =(const float*)d_in[14];
  const float* sp_W=(const float*)d_in[15]; const float* sp_b=(const float*)d_in[16];
  const float* sp_lng=(const float*)d_in[17]; const float* sp_lnb=(const float*)d_in[18];
  const float* fc0_W=(const float*)d_in[19]; const float* fc0_b=(const float*)d_in[20];
  const float* bn_g=(const float*)d_in[21]; const float* bn_b=(const float*)d_in[22];
  const float* tq_W=(const float*)d_in[23]; const float* tq_b=(const float*)d_in[24];
  const float* tk_W=(const float*)d_in[25]; const float* tk_b=(const float*)d_in[26];
  const float* tv_W=(const float*)d_in[27]; const float* tv_b=(const float*)d_in[28];
  const float* mWqkv=(const float*)d_in[29]; const float* mbqkv=(const float*)d_in[30];
  const float* mWo=(const float*)d_in[31];  const float* mbo=(const float*)d_in[32];
  const float* c1W=(const float*)d_in[33];  const float* c1b=(const float*)d_in[34];
  const float* c2W=(const float*)d_in[35];  const float* c2b=(const float*)d_in[36];
  const float* opW=(const float*)d_in[37];  const float* opb=(const float*)d_in[38];
  const float* as1W=(const float*)d_in[39]; const float* as1b=(const float*)d_in[40];
  const float* as2W=(const float*)d_in[41]; const float* as2b=(const float*)d_in[42];
  const float* sc1W=(const float*)d_in[43]; const float* sc1b=(const float*)d_in[44];
  const float* sc2W=(const float*)d_in[45]; const float* sc2b=(const float*)d_in[46];
  const float* cl1W=(const float*)d_in[47]; const float* cl1b=(const float*)d_in[48];
  const float* cllng=(const float*)d_in[49]; const float* cllnb=(const float*)d_in[50];
  const float* cl2W=(const float*)d_in[51]; const float* cl2b=(const float*)d_in[52];
  const float* cl3W=(const float*)d_in[53]; const float* cl3b=(const float*)d_in[54];
  const float* tpW=(const float*)d_in[55];  const float* tpb=(const float*)d_in[56];
  const int* e_src=(const int*)d_in[57];  const int* e_dst=(const int*)d_in[58];
  float* out = (float*)d_out;

  /* workspace arena */
  char* ws = (char*)d_ws;
  size_t off_b = 0;
  auto alloc = [&](size_t bytes)->char*{
    char* r = ws + off_b;
    off_b = (off_b + bytes + 255) & ~(size_t)255;
    return r;
  };
  float* X    = (float*)alloc((size_t)8192*384*4);
  float* KQV  = (float*)alloc((size_t)8192*1152*4);
  float* KE   = (float*)alloc((size_t)14336*384*4);
  float* VE   = (float*)alloc((size_t)14336*384*4);
  float* AGG  = (float*)alloc((size_t)8192*384*4);
  float* EA   = (float*)alloc((size_t)NEDGE*4*4);
  int* edg    = (int*)alloc((size_t)NEDGE*4);
  int* esr    = (int*)alloc((size_t)NEDGE*4);
  int* erl    = (int*)alloc((size_t)NEDGE*4);
  int* csr    = (int*)alloc((size_t)NEDGE*4);
  int* cnt    = (int*)alloc(8192*4);
  int* cnt2   = (int*)alloc(8192*4);
  int* coff   = (int*)alloc(8193*4);
  unsigned* EMX = (unsigned*)alloc(8192*4*4);
  float* EDEN = (float*)alloc(8192*4*4);
  float* SM   = (float*)alloc(65536);
  float* GT   = (float*)alloc(20*384*4);
  if (off_b > ws_size) return;

  float* SQSK = SM;
  float* TRAJSUM = SM + 8;
  float* DECAYSUM = SM + 392;
  float* TEMB = SM + 600;
  float* AIPOOL = SM + 984;
  float* BCTXV = SM + 1368;
  float* SDELT = SM + 1752;
  float* SDIN = SM + 2048;
  float* T1   = SM + 2816;
  float* Z1   = SM + 3200;
  float* Zb   = SM + 3584;
  float* Z2   = SM + 3968;
  float* KSUM = SM + 4224;
  float* DNM  = SM + 6144;

  float* QB = KQV;
  float* KB = KQV + (size_t)2048*1536;
  float* VB = KQV + (size_t)2*2048*1536;
  float* MQKV = KQV;
  float* AO = KQV + (size_t)2*2048*1536;
  float* ZNUM = KE;
  float* OWT = KE;
  float* OPART = KE;                       /* flash partials: <= 4*4*2048*96 */
  float* MLBUF = KE + (size_t)3200000;     /* <= 65536 floats */
  float* IMC = KE;                         /* conv im2col 2048x1152 */
  float* WT  = KE + (size_t)2400000;       /* conv weight^T <= 1152*384 */
  float* HS = VE;
  float* XG = VE + (size_t)2048*384;
  float* HM = VE + (size_t)2*2048*384;
  float* C1O = VE + (size_t)3*2048*384;
  float* TRAJ = VE + (size_t)4*2048*384;
  float* AICTX = VE + (size_t)5*2048*384;
  float* C2O = VE + (size_t)6*2048*384;
  float* TMPA = AGG;
  float* CB = AGG;
  float* PT = AGG + (size_t)2048*768;
  float* KVS = AGG + (size_t)2048*1152;

  dim3 B256(256);
  auto gemm = [&](const float* A, int lda, const float* Bw, int ldb, const float* bias,
                  const float* cs, const float* csh, float kmul,
                  float* C, int ldc, int M, int N, int K, int act, int agelu){
    dim3 g((N+63)/64, (M+63)/64);
    gemm_f<<<g, B256, 0, stream>>>(A, lda, Bw, ldb, bias, cs, csh, kmul, C, ldc, M, N, K, act, agelu);
  };
  auto gemv = [&](const float* in, int K, const float* W, int ldw, const float* b,
                  float* o, int N, int act){
    int nk = (K + 79) / 80; if (nk > 20) nk = 20; if (nk < 1) nk = 1;
    k_gemv_ks<<<dim3((N+63)/64, nk), B256, 0, stream>>>(in, K, W, ldw, GT, N);
    k_gemv_fin<<<dim3((N+255)/256), B256, 0, stream>>>(GT, nk, b, o, N, act);
  };

  /* ---- edge CSR ---- */
  hipMemsetAsync(cnt, 0, 8192*4, stream);
  hipMemsetAsync(cnt2, 0, 8192*4, stream);
  k_edge_pre<<<dim3(NEDGE/256), B256, 0, stream>>>(e_src, e_dst, edg, esr, erl, cnt);
  k_scan<<<dim3(1), dim3(1024), 0, stream>>>(cnt, coff);
  k_scatter<<<dim3(NEDGE/256), B256, 0, stream>>>(edg, coff, cnt2, csr);

  /* ---- inputs -> X ---- */
  for (int t=0;t<5;t++)
    hipMemcpyAsync(X + (size_t)h_OFFS[t]*384, xin[t], (size_t)h_NT[t]*384*4,
                   hipMemcpyDeviceToDevice, stream);

  /* ---- HGT layers ---- */
  for (int l=0;l<2;l++){
    for (int t=0;t<5;t++)
      gemm(X + (size_t)h_OFFS[t]*384, 384, Wkqv + (size_t)(l*5+t)*442368, 1152,
           bkqv + (size_t)(l*5+t)*1152, nullptr, nullptr, 1.f,
           KQV + (size_t)h_OFFS[t]*1152, 1152, h_NT[t], 1152, 384, 0, 0);
    gemm_rel<<<dim3(2,32,64), B256, 0, stream>>>(
        KQV, krel + (size_t)l*294912, vrel + (size_t)l*294912, KE, VE);
    k_escore<<<dim3(NEDGE/4), B256, 0, stream>>>(KQV, KE, edg, esr, erl, prel + (size_t)l*32, EA);
    hipMemsetAsync(EMX, 0, 8192*4*4, stream);
    hipMemsetAsync(EDEN, 0, 8192*4*4, stream);
    k_segmax<<<dim3(NEDGE*4/256), B256, 0, stream>>>(EA, edg, EMX);
    k_expsum<<<dim3(NEDGE*4/256), B256, 0, stream>>>(EA, edg, EMX, EDEN);
    k_agg<<<dim3(NTOT), dim3(128), 0, stream>>>(EA, VE, EDEN, csr, coff, esr, AGG);
    for (int t=0;t<5;t++)
      gemm(AGG + (size_t)h_OFFS[t]*384, 384, Wout + (size_t)(l*5+t)*147456, 384,
           bout + (size_t)(l*5+t)*384, nullptr, nullptr, 1.f,
           OWT + (size_t)h_OFFS[t]*384, 384, h_NT[t], 384, 384, 0, 1 /*gelu on A*/);
    k_gateln<<<dim3(NTOT), dim3(128), 0, stream>>>(OWT, X, skp + l*5, lng, lnb);
  }

  const float* user_h   = X;
  const float* ai_h     = X + (size_t)2048*384;
  const float* stance_h = X + (size_t)4096*384;
  const float* belief_h = X + (size_t)7168*384;

  /* ---- hs, xg ---- */
  gemm(stance_h, 384, sp_W, 384, sp_b, nullptr, nullptr, 1.f, TMPA, 384, 2048, 384, 384, 0, 0);
  k_lnrow<<<dim3(2048), dim3(128), 0, stream>>>(TMPA, HS, sp_lng, sp_lnb, 0 /*gelu*/);
  gemm(HS, 384, fc0_W, 384, fc0_b, bn_g, bn_b, BNCONST, XG, 384, 2048, 384, 384, 1 /*relu*/, 0);

  /* ---- linear-attention blocks ---- */
  for (int i=0;i<2;i++){
    gemm(XG, 384, tq_W + (size_t)i*589824, 1536, tq_b + (size_t)i*1536, nullptr, nullptr, 1.f,
         QB, 1536, 2048, 1536, 384, 0, 0);
    gemm(XG, 384, tk_W + (size_t)i*589824, 1536, tk_b + (size_t)i*1536, nullptr, nullptr, 1.f,
         KB, 1536, 2048, 1536, 384, 0, 0);
    gemm(XG, 384, tv_W + (size_t)i*589824, 1536, tv_b + (size_t)i*1536, nullptr, nullptr, 1.f,
         VB, 1536, 2048, 1536, 384, 0, 0);
    hipMemsetAsync(SQSK, 0, 8, stream);
    k_sumsq<<<dim3(512), B256, 0, stream>>>(QB, 2048*1536, SQSK);
    k_sumsq<<<dim3(512), B256, 0, stream>>>(KB, 2048*1536, SQSK+1);
    hipMemsetAsync(KSUM, 0, 1536*4, stream);
    k_colsum<<<dim3(6,8), B256, 0, stream>>>(KB, 2048, 1536, 1.0f, KSUM);
    k_dnm<<<dim3(2048), B256, 0, stream>>>(QB, KSUM, SQSK, DNM);
    hipMemsetAsync(KVS, 0, (size_t)4*147456*4, stream);
    gemm_atb_ks<<<dim3(6,6,32), B256, 0, stream>>>(KB, 1536, VB, 1536, KVS, 384,
        384, 384, 2048, 384, 384, 147456, 8);
    for (int h=0;h<4;h++)
      gemm(QB + h*384, 1536, KVS + (size_t)h*147456, 384, nullptr, nullptr, nullptr, 1.f,
           ZNUM + h*384, 1536, 2048, 384, 384, 0, 0);
    k_zcomb<<<dim3(3072), B256, 0, stream>>>(ZNUM, VB, DNM, SQSK, XG,
        bn_g + (size_t)(i+1)*384, bn_b + (size_t)(i+1)*384);
  }

  /* ---- h_mixed ---- */
  k_mix<<<dim3(3072), B256, 0, stream>>>(HS, XG, HM, 2048*384, 0.7f, 0.3f);

  /* ---- MHA helper (flash) ---- */
  auto run_mha = [&](const float* qin, int nq, const float* kvin, int nkv, int mi, float* OUT){
    const float* Wq = mWqkv + (size_t)mi*442368;
    const float* bq = mbqkv + (size_t)mi*1152;
    gemm(qin, 384, Wq, 1152, bq, nullptr, nullptr, 1.f, MQKV, 1152, nq, 384, 384, 0, 0);
    gemm(kvin, 384, Wq + 384, 1152, bq + 384, nullptr, nullptr, 1.f, MQKV + 384, 1152, nkv, 768, 384, 0, 0);
    int nch = nkv / 512;
    fa_kernel<<<dim3(nq/64, 4, nch), B256, 0, stream>>>(MQKV, nq, OPART, MLBUF);
    k_famerge<<<dim3((4*nq*96 + 255)/256), B256, 0, stream>>>(OPART, MLBUF, AO, nq, nch);
    gemm(AO, 384, mWo + (size_t)mi*147456, 384, mbo + (size_t)mi*384,
         nullptr, nullptr, 1.f, OUT, 384, nq, 384, 384, 0, 0);
  };

  /* ---- traj ---- */
  run_mha(HM, 2048, HM, 2048, 1, TRAJ);
  hipMemsetAsync(TRAJSUM, 0, 576*4, stream);
  k_colsum<<<dim3(2,8), B256, 0, stream>>>(TRAJ, 2048, 384, 1.0f/2048.0f, TRAJSUM);

  /* ---- conv path (im2col + GEMM, gelu epilogue) ---- */
  k_im2col<<<dim3(2048*1152/256), B256, 0, stream>>>(HM, IMC);
  k_wtr<<<dim3((384*1152+255)/256), B256, 0, stream>>>(c1W, WT, 384);
  gemm(IMC, 1152, WT, 384, c1b, nullptr, nullptr, 1.f, C1O, 384, 2048, 384, 1152, 2 /*gelu*/, 0);
  k_im2col<<<dim3(2048*1152/256), B256, 0, stream>>>(C1O, IMC);
  k_wtr<<<dim3((192*1152+255)/256), B256, 0, stream>>>(c2W, WT, 192);
  gemm(IMC, 1152, WT, 192, c2b, nullptr, nullptr, 1.f, C2O, 192, 2048, 192, 1152, 2 /*gelu*/, 0);
  k_colsum<<<dim3(1,8), B256, 0, stream>>>(C2O, 2048, 192, 1.0f/2048.0f, DECAYSUM);

  /* ---- traj_emb ---- */
  gemv(TRAJSUM, 576, opW, 384, opb, TEMB, 384, 0);

  /* ---- ai_ctx ---- */
  run_mha(ai_h, 2048, user_h, 2048, 0, AICTX);
  hipMemsetAsync(AIPOOL, 0, 384*4, stream);
  k_colsum<<<dim3(2,8), B256, 0, stream>>>(AICTX, 2048, 384, 1.0f/2048.0f, AIPOOL);

  /* ---- pscores ---- */
  k_comb<<<dim3(6144), B256, 0, stream>>>(ai_h, user_h, CB);
  gemm(CB, 768, as1W, 384, as1b, nullptr, nullptr, 1.f, PT, 384, 2048, 384, 768, 1, 0);
  k_rowdot<<<dim3(512), B256, 0, stream>>>(PT, 384, 384, as2W, as2b, out + 2 + 2048, 2048);

  /* ---- bctx ---- */
  run_mha(ai_h, 2048, belief_h, 1024, 2, TRAJ);
  hipMemsetAsync(BCTXV, 0, 384*4, stream);
  k_colsum<<<dim3(2,8), B256, 0, stream>>>(TRAJ, 2048, 384, 1.0f/2048.0f, BCTXV);

  /* ---- stance delta ---- */
  hipMemcpyAsync(SDIN, stance_h, 384*4, hipMemcpyDeviceToDevice, stream);
  hipMemcpyAsync(SDIN + 384, stance_h + (size_t)2047*384, 384*4, hipMemcpyDeviceToDevice, stream);
  gemv(SDIN, 768, sc1W, 384, sc1b, T1, 384, 1);
  gemv(T1, 384, sc2W, 192, sc2b, SDELT, 192, 0);

  /* ---- classifier ---- */
  gemv(TEMB, 1344, cl1W, 384, cl1b, Z1, 384, 0);
  k_lnrow<<<dim3(1), dim3(128), 0, stream>>>(Z1, Zb, cllng, cllnb, 1 /*relu*/);
  gemv(Zb, 384, cl2W, 192, cl2b, Z2, 192, 1);
  k_final<<<dim3(1), dim3(64), 0, stream>>>(Z2, cl3W, cl3b, out);

  /* ---- per_turn ---- */
  k_rowdot<<<dim3(512), B256, 0, stream>>>(AICTX, 384, 384, tpW, tpb, out + 2, 2048);
}